// Round 10
// baseline (786.190 us; speedup 1.0000x reference)
//
#include <hip/hip_runtime.h>

#define NBATCH 4
#define NPTS   4096
#define KNNK   32
#define C1D    128
#define CD     256
#define KPAD   160   // conv2 K padded (131 -> 160, 5 mfma K-steps of 32)
#define ASTR   168   // conv2 LDS A row stride in halves
#define ASTR2  264   // kv LDS A row stride in halves (256 cols + 8 pad)

typedef _Float16 v8h __attribute__((ext_vector_type(8)));
typedef float    v4f __attribute__((ext_vector_type(4)));

// ---------------- helpers ----------------

__device__ __forceinline__ float block_sum256(float v, float* red) {
    #pragma unroll
    for (int o = 32; o; o >>= 1) v += __shfl_down(v, o);
    __syncthreads();
    if ((threadIdx.x & 63) == 0) red[threadIdx.x >> 6] = v;
    __syncthreads();
    return red[0] + red[1] + red[2] + red[3];
}

__device__ __forceinline__ unsigned rotl32(unsigned x, unsigned r) {
    return (x << r) | (x >> (32u - r));
}

// XLA f32 erf_inv (Giles polynomial)
__device__ float erfinv_f(float x) {
    float w = -log1pf(-x * x);
    float p;
    if (w < 5.0f) {
        w -= 2.5f;
        p = 2.81022636e-08f;
        p = fmaf(p, w, 3.43273939e-07f);
        p = fmaf(p, w, -3.5233877e-06f);
        p = fmaf(p, w, -4.39150654e-06f);
        p = fmaf(p, w, 0.00021858087f);
        p = fmaf(p, w, -0.00125372503f);
        p = fmaf(p, w, -0.00417768164f);
        p = fmaf(p, w, 0.246640727f);
        p = fmaf(p, w, 1.50140941f);
    } else {
        w = sqrtf(w) - 3.0f;
        p = -0.000200214257f;
        p = fmaf(p, w, 0.000100950558f);
        p = fmaf(p, w, 0.00134934322f);
        p = fmaf(p, w, -0.00367342844f);
        p = fmaf(p, w, 0.00573950773f);
        p = fmaf(p, w, -0.0076224613f);
        p = fmaf(p, w, 0.00943887047f);
        p = fmaf(p, w, 1.00167406f);
        p = fmaf(p, w, 2.83297682f);
    }
    return p * x;
}

__device__ __forceinline__ float bits_to_normal(unsigned bits) {
    unsigned fb = (bits >> 9) | 0x3f800000u;
    float f = __uint_as_float(fb) - 1.0f;
    const float lo = -0.99999994f;           // nextafterf(-1,0)
    float u = fmaf(f, 2.0f, lo);
    u = fmaxf(u, lo);
    return 1.41421356237f * erfinv_f(u);
}

// one level of wave64 lexicographic-min reduce via DPP (VALU-only)
template <int CTRL, int RM>
__device__ __forceinline__ void dpp_lexmin(float& v, int& ix) {
    int tv = __builtin_amdgcn_update_dpp(__float_as_int(v), __float_as_int(v), CTRL, RM, 0xf, false);
    int ti = __builtin_amdgcn_update_dpp(ix, ix, CTRL, RM, 0xf, false);
    float fv = __int_as_float(tv);
    bool take = (fv < v) || (fv == v && ti < ix);
    v  = take ? fv : v;
    ix = take ? ti : ix;
}

// lexicographic max (value desc, index asc on ties) — matches jnp.argmax
template <int CTRL, int RM>
__device__ __forceinline__ void dpp_lexmax(float& v, int& ix) {
    int tv = __builtin_amdgcn_update_dpp(__float_as_int(v), __float_as_int(v), CTRL, RM, 0xf, false);
    int ti = __builtin_amdgcn_update_dpp(ix, ix, CTRL, RM, 0xf, false);
    float fv = __int_as_float(tv);
    bool take = (fv > v) || (fv == v && ti < ix);
    v  = take ? fv : v;
    ix = take ? ti : ix;
}

// ---------------- kernels ----------------

// x [B,3,N] -> xyz [B,N,3], xyzw [B,N] (x,y,z,sq)
__global__ void prep_kernel(const float* __restrict__ x, float* __restrict__ xyz,
                            float4* __restrict__ xyzw) {
    int gid = blockIdx.x * 256 + threadIdx.x;
    if (gid >= NBATCH * NPTS) return;
    int b = gid >> 12, n = gid & (NPTS - 1);
    float a0 = x[(b * 3 + 0) * NPTS + n];
    float a1 = x[(b * 3 + 1) * NPTS + n];
    float a2 = x[(b * 3 + 2) * NPTS + n];
    xyz[gid * 3 + 0] = a0; xyz[gid * 3 + 1] = a1; xyz[gid * 3 + 2] = a2;
    float sq = a0 * a0 + a1 * a1 + a2 * a2;
    xyzw[gid] = make_float4(a0, a1, a2, sq);
}

// JAX threefry2x32, key(42) -> slots = mu + sigma * normal; also zero asum
__global__ void slots_init_kernel(const float* __restrict__ mu, const float* __restrict__ sg,
                                  float* __restrict__ slots, float* __restrict__ asum) {
    int j = blockIdx.x * 256 + threadIdx.x;
    if (j < 16) asum[j] = 0.0f;
    if (j >= 2048) return;
    unsigned ks0 = 0u, ks1 = 42u, ks2 = 0u ^ 42u ^ 0x1BD11BDAu;
    unsigned x0 = (unsigned)j + ks0;
    unsigned x1 = (unsigned)(j + 2048) + ks1;
    #define RND(r) { x0 += x1; x1 = rotl32(x1, r); x1 ^= x0; }
    RND(13u) RND(15u) RND(26u) RND(6u);  x0 += ks1; x1 += ks2 + 1u;
    RND(17u) RND(29u) RND(16u) RND(24u); x0 += ks2; x1 += ks0 + 2u;
    RND(13u) RND(15u) RND(26u) RND(6u);  x0 += ks0; x1 += ks1 + 3u;
    RND(17u) RND(29u) RND(16u) RND(24u); x0 += ks1; x1 += ks2 + 4u;
    RND(13u) RND(15u) RND(26u) RND(6u);  x0 += ks2; x1 += ks0 + 5u;
    #undef RND
    int c0 = j & 255, c1 = (j + 2048) & 255;
    slots[j]        = mu[c0] + sg[c0] * bits_to_normal(x0);
    slots[j + 2048] = mu[c1] + sg[c1] * bits_to_normal(x1);
}

// KNN: one wave per point, no barriers. 8 groups of 8 per lane, incremental
// per-lane (lv,li). Per round: DPP wave argmin + owner-only group rescan +
// owner-only lane-min recombine. Tie-breaks identical to lax.top_k.
__global__ __launch_bounds__(256) void knn_kernel(const float4* __restrict__ xyzw,
                                                  int* __restrict__ knn_idx) {
    int wid = threadIdx.x >> 6, lane = threadIdx.x & 63;
    int pid = blockIdx.x * 4 + wid;
    int b = pid >> 12, n = pid & (NPTS - 1);
    const float4* xb = xyzw + (size_t)b * NPTS;
    float4 p = xb[n];
    float d[64];
    #pragma unroll
    for (int i = 0; i < 64; ++i) {
        float4 c = xb[i * 64 + lane];
        float dot = p.x * c.x + p.y * c.y + p.z * c.z;
        d[i] = p.w + c.w - 2.0f * dot;
    }
    float gv[8]; int gi[8];
    #pragma unroll
    for (int g = 0; g < 8; ++g) {
        float mv = d[g * 8]; int mi = g * 8;
        #pragma unroll
        for (int j = 1; j < 8; ++j)
            if (d[g * 8 + j] < mv) { mv = d[g * 8 + j]; mi = g * 8 + j; }
        gv[g] = mv; gi[g] = mi * 64 + lane;
    }
    // incremental lane-min (smallest index on ties: ascending g, strict <)
    float lv = gv[0]; int li = gi[0];
    #pragma unroll
    for (int g = 1; g < 8; ++g)
        if (gv[g] < lv) { lv = gv[g]; li = gi[g]; }

    int* out = knn_idx + (size_t)pid * KNNK;
    #pragma unroll 1
    for (int s = 0; s < KNNK; ++s) {
        float bv = lv; int bi = li;
        dpp_lexmin<0x111, 0xf>(bv, bi);
        dpp_lexmin<0x112, 0xf>(bv, bi);
        dpp_lexmin<0x114, 0xf>(bv, bi);
        dpp_lexmin<0x118, 0xf>(bv, bi);
        dpp_lexmin<0x142, 0xa>(bv, bi);
        dpp_lexmin<0x143, 0xc>(bv, bi);
        int fm = __builtin_amdgcn_readlane(bi, 63);
        if (lane == 0) out[s] = fm;
        int flane = fm & 63;
        int slot  = fm >> 6;
        if (lane == flane) {
            int g = slot >> 3;
            #pragma unroll
            for (int g2 = 0; g2 < 8; ++g2) {
                if (g2 == g) {
                    #pragma unroll
                    for (int j = 0; j < 8; ++j)
                        if (g2 * 8 + j == slot) d[g2 * 8 + j] = 1e30f;
                    float mv = d[g2 * 8]; int mi = g2 * 8;
                    #pragma unroll
                    for (int j = 1; j < 8; ++j)
                        if (d[g2 * 8 + j] < mv) { mv = d[g2 * 8 + j]; mi = g2 * 8 + j; }
                    gv[g2] = mv; gi[g2] = mi * 64 + lane;
                }
            }
            lv = gv[0]; li = gi[0];
            #pragma unroll
            for (int g2 = 1; g2 < 8; ++g2)
                if (gv[g2] < lv) { lv = gv[g2]; li = gi[g2]; }
        }
    }
}

// conv1 -> fp16 features; neighbor coords preloaded into lanes 0..31, loop
// uses shuffles only (no per-iteration memory dependency chain)
__global__ __launch_bounds__(128) void conv1_kernel(const float* __restrict__ xyz,
                                                    const int* __restrict__ knn_idx,
                                                    const float* __restrict__ W1,
                                                    const float* __restrict__ b1,
                                                    _Float16* __restrict__ f1h) {
    int pid = blockIdx.x;
    int b = pid >> 12, n = pid & (NPTS - 1);
    int d = threadIdx.x, lane = threadIdx.x & 63;
    const float* xb = xyz + (size_t)b * NPTS * 3;
    float w0 = W1[d], wx = W1[C1D + d], wy = W1[2 * C1D + d], wz = W1[3 * C1D + d];
    float bb = b1[d];
    float px = xb[n * 3], py = xb[n * 3 + 1], pz = xb[n * 3 + 2];
    const int* idx = knn_idx + (size_t)pid * KNNK;
    float cx = 0.0f, cy = 0.0f, cz = 0.0f;
    if (lane < 32) {
        int j = idx[lane];
        cx = xb[j * 3]; cy = xb[j * 3 + 1]; cz = xb[j * 3 + 2];
    }
    float m = -1e30f;
    #pragma unroll
    for (int k = 0; k < KNNK; ++k) {
        float jx = __shfl(cx, k), jy = __shfl(cy, k), jz = __shfl(cz, k);
        float v = w0 + bb + (jx - px) * wx + (jy - py) * wy + (jz - pz) * wz;
        m = fmaxf(m, v);
    }
    f1h[(size_t)pid * C1D + d] = (_Float16)fmaxf(m, 0.0f);
}

// W2 [131x256 fp32] -> W2t [256][160] fp16 (transposed, zero-padded)
__global__ void w2t_kernel(const float* __restrict__ W2, _Float16* __restrict__ W2t) {
    int n = blockIdx.x;          // 0..255
    int k = threadIdx.x;         // 0..159
    W2t[n * KPAD + k] = (k < 131) ? (_Float16)W2[k * CD + n] : (_Float16)0.0f;
}

// Wk/Wv [256x256 fp32] -> WkvT [512][256] fp16 (transposed, Wk rows then Wv rows)
__global__ void wkvt_kernel(const float* __restrict__ Wk, const float* __restrict__ Wv,
                            _Float16* __restrict__ WkvT) {
    int n = blockIdx.x;          // 0..511
    int c = threadIdx.x;         // 0..255
    float v = (n < 256) ? Wk[c * CD + n] : Wv[c * CD + (n - 256)];
    WkvT[n * CD + c] = (_Float16)v;
}

// conv2 via MFMA f16 + fused bias/relu/max-over-k/LayerNorm -> inph fp16
__global__ __launch_bounds__(256) void conv2_mfma_kernel(const float* __restrict__ xyz,
                                                         const _Float16* __restrict__ f1h,
                                                         const int* __restrict__ knn_idx,
                                                         const _Float16* __restrict__ W2t,
                                                         const float* __restrict__ b2,
                                                         const float* __restrict__ g_in,
                                                         const float* __restrict__ b_in,
                                                         _Float16* __restrict__ inph) {
    __shared__ _Float16 A[64 * ASTR];
    __shared__ float colmax[2 * CD];
    __shared__ float red[4];
    int pid2 = blockIdx.x;
    int gp0 = pid2 * 2;
    int b = gp0 >> 12, n0 = gp0 & (NPTS - 1);
    int tid = threadIdx.x;
    const int* idx = knn_idx + (size_t)pid2 * 64;   // [2][32]
    const float* xb = xyz + (size_t)b * NPTS * 3;

    {
        int r = tid & 63, seg = tid >> 6;
        int j = idx[r];
        const uint4* s4 = (const uint4*)(f1h + ((size_t)b * NPTS + j) * C1D);
        uint4* d4 = (uint4*)&A[r * ASTR];
        #pragma unroll
        for (int i = 0; i < 4; ++i) d4[seg * 4 + i] = s4[seg * 4 + i];
        unsigned* z = (unsigned*)&A[r * ASTR + 128];
        for (int i = seg; i < 20; i += 4) z[i] = 0u;
        int np_ = (r < 32) ? n0 : (n0 + 1);
        if (seg == 0) {
            A[r * ASTR + 128] = (_Float16)(xb[j * 3 + 0] - xb[np_ * 3 + 0]);
            A[r * ASTR + 129] = (_Float16)(xb[j * 3 + 1] - xb[np_ * 3 + 1]);
        } else if (seg == 1) {
            A[r * ASTR + 130] = (_Float16)(xb[j * 3 + 2] - xb[np_ * 3 + 2]);
        }
    }
    __syncthreads();

    int w = tid >> 6, lane = tid & 63, quad = lane >> 4, lr = lane & 15;
    v4f acc[4][4];
    #pragma unroll
    for (int rt = 0; rt < 4; ++rt)
        #pragma unroll
        for (int ct = 0; ct < 4; ++ct)
            acc[rt][ct] = (v4f){0.0f, 0.0f, 0.0f, 0.0f};

    #pragma unroll
    for (int kk = 0; kk < KPAD; kk += 32) {
        v8h af[4], bf[4];
        #pragma unroll
        for (int rt = 0; rt < 4; ++rt)
            af[rt] = *(const v8h*)&A[(rt * 16 + lr) * ASTR + kk + quad * 8];
        #pragma unroll
        for (int ct = 0; ct < 4; ++ct) {
            int ncol = w * 64 + ct * 16 + lr;
            bf[ct] = *(const v8h*)(W2t + (size_t)ncol * KPAD + kk + quad * 8);
        }
        #pragma unroll
        for (int rt = 0; rt < 4; ++rt)
            #pragma unroll
            for (int ct = 0; ct < 4; ++ct)
                acc[rt][ct] = __builtin_amdgcn_mfma_f32_16x16x32_f16(af[rt], bf[ct], acc[rt][ct], 0, 0, 0);
    }

    #pragma unroll
    for (int ct = 0; ct < 4; ++ct) {
        float tm[4];
        #pragma unroll
        for (int rt = 0; rt < 4; ++rt) {
            v4f a = acc[rt][ct];
            float v = fmaxf(fmaxf(a[0], a[1]), fmaxf(a[2], a[3]));
            v = fmaxf(v, __shfl_xor(v, 16));
            v = fmaxf(v, __shfl_xor(v, 32));
            tm[rt] = v;
        }
        float p0 = fmaxf(tm[0], tm[1]);
        float p1 = fmaxf(tm[2], tm[3]);
        if (quad == 0) {
            colmax[0 * CD + w * 64 + ct * 16 + lr] = p0;
            colmax[1 * CD + w * 64 + ct * 16 + lr] = p1;
        }
    }
    __syncthreads();

    int d = tid;
    #pragma unroll
    for (int p = 0; p < 2; ++p) {
        float v = fmaxf(colmax[p * CD + d] + b2[d], 0.0f);
        float s = block_sum256(v, red);
        float mean = s * (1.0f / 256.0f);
        float s2 = block_sum256(v * v, red);
        float var = s2 * (1.0f / 256.0f) - mean * mean;
        float iv = (v - mean) * rsqrtf(var + 1e-5f) * g_in[d] + b_in[d];
        inph[(size_t)(gp0 + p) * CD + d] = (_Float16)iv;
    }
}

// kv via MFMA fp16: block = 64 points x 256 cols; half 0 -> kk, half 1 -> vv.
__global__ __launch_bounds__(256) void kv_mfma_kernel(const _Float16* __restrict__ inph,
                                                      const _Float16* __restrict__ WkvT,
                                                      float* __restrict__ kk,
                                                      float* __restrict__ vv) {
    __shared__ _Float16 A[64 * ASTR2];
    int rb = blockIdx.x >> 1, half = blockIdx.x & 1;
    int row0 = rb * 64;
    int tid = threadIdx.x;
    {
        const uint4* src4 = (const uint4*)(inph + (size_t)row0 * CD);
        #pragma unroll
        for (int i = 0; i < 8; ++i) {
            int idx = i * 256 + tid;         // uint4 index, 32 per row
            int row = idx >> 5, c8 = idx & 31;
            *(uint4*)&A[row * ASTR2 + c8 * 8] = src4[idx];
        }
    }
    __syncthreads();
    int w = tid >> 6, lane = tid & 63, quad = lane >> 4, lr = lane & 15;
    v4f acc[4][4];
    #pragma unroll
    for (int rt = 0; rt < 4; ++rt)
        #pragma unroll
        for (int ct = 0; ct < 4; ++ct)
            acc[rt][ct] = (v4f){0.0f, 0.0f, 0.0f, 0.0f};
    #pragma unroll
    for (int ks = 0; ks < CD; ks += 32) {
        v8h af[4], bf[4];
        #pragma unroll
        for (int rt = 0; rt < 4; ++rt)
            af[rt] = *(const v8h*)&A[(rt * 16 + lr) * ASTR2 + ks + quad * 8];
        #pragma unroll
        for (int ct = 0; ct < 4; ++ct) {
            int ncol = half * 256 + w * 64 + ct * 16 + lr;
            bf[ct] = *(const v8h*)(WkvT + (size_t)ncol * CD + ks + quad * 8);
        }
        #pragma unroll
        for (int rt = 0; rt < 4; ++rt)
            #pragma unroll
            for (int ct = 0; ct < 4; ++ct)
                acc[rt][ct] = __builtin_amdgcn_mfma_f32_16x16x32_f16(af[rt], bf[ct], acc[rt][ct], 0, 0, 0);
    }
    float* dst = half ? vv : kk;
    #pragma unroll
    for (int rt = 0; rt < 4; ++rt)
        #pragma unroll
        for (int ct = 0; ct < 4; ++ct) {
            int col = w * 64 + ct * 16 + lr;
            #pragma unroll
            for (int r = 0; r < 4; ++r) {
                int row = rt * 16 + quad * 4 + r;
                dst[(size_t)(row0 + row) * CD + col] = acc[rt][ct][r];
            }
        }
}

// FUSED slot-attention iteration: LN(slots)+q (redundant per block, identical
// arithmetic to the old slotq) -> logits/softmax -> asum atomic -> updp
// partials (same order as old updp). One block per (batch, 256-pt chunk).
__global__ __launch_bounds__(256) void slot_attn_kernel(const float* __restrict__ slots,
                                                        const float* __restrict__ g_sl,
                                                        const float* __restrict__ b_sl,
                                                        const float* __restrict__ Wq,
                                                        const float* __restrict__ kk,
                                                        const float* __restrict__ vv,
                                                        float* __restrict__ asum,
                                                        float* __restrict__ updp,
                                                        float* __restrict__ out_attn) {
    int b = blockIdx.x >> 4;
    int chunk = blockIdx.x & 15;
    int t = threadIdx.x;
    __shared__ float sl[4 * CD];
    __shared__ float qs[4 * CD];
    __shared__ float aw[256 * 4];
    __shared__ float red[4];
    __shared__ float redk[16];

    // ---- phase 1: LN per slot row (identical to slotq) ----
    #pragma unroll 1
    for (int r = 0; r < 4; ++r) {
        float v = slots[(b * 4 + r) * CD + t];
        float s = block_sum256(v, red);
        float mean = s * (1.0f / 256.0f);
        float s2 = block_sum256(v * v, red);
        float var = s2 * (1.0f / 256.0f) - mean * mean;
        sl[r * CD + t] = (v - mean) * rsqrtf(var + 1e-5f) * g_sl[t] + b_sl[t];
    }
    __syncthreads();
    // ---- q = LN(slots) @ Wq (same per-row expression as old slotq) ----
    {
        float a0 = 0.0f, a1 = 0.0f, a2 = 0.0f, a3 = 0.0f;
        const float4* s0 = (const float4*)(sl);
        const float4* s1 = (const float4*)(sl + CD);
        const float4* s2p = (const float4*)(sl + 2 * CD);
        const float4* s3 = (const float4*)(sl + 3 * CD);
        for (int c4 = 0; c4 < 64; ++c4) {
            int cb = c4 * 4;
            float w0 = Wq[cb * CD + t], w1 = Wq[(cb + 1) * CD + t];
            float w2 = Wq[(cb + 2) * CD + t], w3 = Wq[(cb + 3) * CD + t];
            float4 x0 = s0[c4], x1 = s1[c4], x2 = s2p[c4], x3 = s3[c4];
            a0 += x0.x * w0 + x0.y * w1 + x0.z * w2 + x0.w * w3;
            a1 += x1.x * w0 + x1.y * w1 + x1.z * w2 + x1.w * w3;
            a2 += x2.x * w0 + x2.y * w1 + x2.z * w2 + x2.w * w3;
            a3 += x3.x * w0 + x3.y * w1 + x3.z * w2 + x3.w * w3;
        }
        qs[0 * CD + t] = a0; qs[1 * CD + t] = a1;
        qs[2 * CD + t] = a2; qs[3 * CD + t] = a3;
    }
    __syncthreads();

    // ---- phase 2: logits -> softmax (identical to old attn) ----
    int n = chunk * 256 + t;
    const float4* kp = (const float4*)(kk + ((size_t)b * NPTS + n) * CD);
    const float4* q0 = (const float4*)(qs);
    const float4* q1 = (const float4*)(qs + CD);
    const float4* q2 = (const float4*)(qs + 2 * CD);
    const float4* q3 = (const float4*)(qs + 3 * CD);
    float a0 = 0, a1 = 0, a2 = 0, a3 = 0;
    for (int c4 = 0; c4 < 64; ++c4) {
        float4 kv = kp[c4];
        float4 x;
        x = q0[c4]; a0 += kv.x * x.x + kv.y * x.y + kv.z * x.z + kv.w * x.w;
        x = q1[c4]; a1 += kv.x * x.x + kv.y * x.y + kv.z * x.z + kv.w * x.w;
        x = q2[c4]; a2 += kv.x * x.x + kv.y * x.y + kv.z * x.z + kv.w * x.w;
        x = q3[c4]; a3 += kv.x * x.x + kv.y * x.y + kv.z * x.z + kv.w * x.w;
    }
    const float scale = 0.0625f;   // 256^-0.5
    float l0 = scale * a0, l1 = scale * a1, l2 = scale * a2, l3 = scale * a3;
    float mx = fmaxf(fmaxf(l0, l1), fmaxf(l2, l3));
    float e0 = expf(l0 - mx), e1 = expf(l1 - mx), e2 = expf(l2 - mx), e3 = expf(l3 - mx);
    float inv = 1.0f / (e0 + e1 + e2 + e3);
    e0 *= inv; e1 *= inv; e2 *= inv; e3 *= inv;
    aw[t * 4 + 0] = e0; aw[t * 4 + 1] = e1; aw[t * 4 + 2] = e2; aw[t * 4 + 3] = e3;
    if (out_attn) {
        float* o = out_attn + ((size_t)b * NPTS + n) * 4;
        o[0] = e0; o[1] = e1; o[2] = e2; o[3] = e3;
    }
    float as[4] = {e0, e1, e2, e3};
    #pragma unroll
    for (int k = 0; k < 4; ++k) {
        float v = as[k];
        #pragma unroll
        for (int o = 32; o; o >>= 1) v += __shfl_down(v, o);
        if ((t & 63) == 0) redk[(t >> 6) * 4 + k] = v;
    }
    __syncthreads();   // also publishes aw
    if (t < 4) {
        float s = redk[t] + redk[4 + t] + redk[8 + t] + redk[12 + t];
        atomicAdd(&asum[b * 4 + t], s);
    }

    // ---- phase 3: updp partials (same order as old updp kernel) ----
    float ac0 = 0.0f, ac1 = 0.0f, ac2 = 0.0f, ac3 = 0.0f;
    const float* vb = vv + ((size_t)b * NPTS + chunk * 256) * CD;
    for (int nn2 = 0; nn2 < 256; ++nn2) {
        float v = vb[(size_t)nn2 * CD + t];
        float4 w4 = *(const float4*)&aw[nn2 * 4];
        ac0 += w4.x * v; ac1 += w4.y * v; ac2 += w4.z * v; ac3 += w4.w * v;
    }
    updp[((size_t)(b * 4 + 0) * 16 + chunk) * CD + t] = ac0;
    updp[((size_t)(b * 4 + 1) * 16 + chunk) * CD + t] = ac1;
    updp[((size_t)(b * 4 + 2) * 16 + chunk) * CD + t] = ac2;
    updp[((size_t)(b * 4 + 3) * 16 + chunk) * CD + t] = ac3;
}

// GRU gates: gi = su@W_ih + b_ih, gh = sp@W_hh + b_hh; one block per (row,gate)
__global__ __launch_bounds__(256) void gru_gates_kernel(const float* __restrict__ updp,
                                                        const float* __restrict__ asum,
                                                        const float* __restrict__ slots,
                                                        const float* __restrict__ W_ih,
                                                        const float* __restrict__ W_hh,
                                                        const float* __restrict__ b_ih,
                                                        const float* __restrict__ b_hh,
                                                        float* __restrict__ gi,
                                                        float* __restrict__ gh) {
    int row = blockIdx.x / 3, gate = blockIdx.x % 3;
    int d = threadIdx.x;
    __shared__ float su[CD], sp[CD];
    float f = 1.0f / (asum[row] + 1e-8f);
    float u = 0.0f;
    for (int p = 0; p < 16; ++p) u += updp[((size_t)row * 16 + p) * CD + d];
    u *= f;
    su[d] = u; sp[d] = slots[row * CD + d];
    __syncthreads();
    float acc_i = b_ih[gate * CD + d];
    float acc_h = b_hh[gate * CD + d];
    const float* wi = W_ih + gate * CD + d;
    const float* wh = W_hh + gate * CD + d;
    for (int c = 0; c < CD; ++c) {
        acc_i += su[c] * wi[c * 3 * CD];
        acc_h += sp[c] * wh[c * 3 * CD];
    }
    gi[row * 3 * CD + gate * CD + d] = acc_i;
    gh[row * 3 * CD + gate * CD + d] = acc_h;
}

// GRU update + LN_ff + MLP residual, one block per row; zeroes asum for next iter
__global__ __launch_bounds__(256) void gru_mlp_kernel(const float* __restrict__ gi,
                                                      const float* __restrict__ gh,
                                                      float* __restrict__ slots,
                                                      const float* __restrict__ g_ff,
                                                      const float* __restrict__ b_ff,
                                                      const float* __restrict__ Wm1,
                                                      const float* __restrict__ bm1,
                                                      const float* __restrict__ Wm2,
                                                      const float* __restrict__ bm2,
                                                      float* __restrict__ asum) {
    int row = blockIdx.x;
    int d = threadIdx.x;
    __shared__ float sh[CD];
    __shared__ float red[4];
    float prev = slots[row * CD + d];
    float gir = gi[row * 3 * CD + d], giz = gi[row * 3 * CD + CD + d], gin = gi[row * 3 * CD + 2 * CD + d];
    float ghr = gh[row * 3 * CD + d], ghz = gh[row * 3 * CD + CD + d], ghn = gh[row * 3 * CD + 2 * CD + d];
    if (d == 0) asum[row] = 0.0f;   // ready for next iteration's atomics
    float r = 1.0f / (1.0f + expf(-(gir + ghr)));
    float z = 1.0f / (1.0f + expf(-(giz + ghz)));
    float nn = tanhf(gin + r * ghn);
    float sNew = (1.0f - z) * nn + z * prev;
    float s = block_sum256(sNew, red);
    float mean = s * (1.0f / 256.0f);
    float s2 = block_sum256(sNew * sNew, red);
    float var = s2 * (1.0f / 256.0f) - mean * mean;
    float h = (sNew - mean) * rsqrtf(var + 1e-5f) * g_ff[d] + b_ff[d];
    __syncthreads();
    sh[d] = h;
    __syncthreads();
    float y = bm1[d];
    {
        const float4* hp = (const float4*)sh;
        for (int c4 = 0; c4 < 64; ++c4) {
            float4 x = hp[c4];
            int cb = c4 * 4;
            y += x.x * Wm1[cb * CD + d] + x.y * Wm1[(cb + 1) * CD + d]
               + x.z * Wm1[(cb + 2) * CD + d] + x.w * Wm1[(cb + 3) * CD + d];
        }
    }
    y = fmaxf(y, 0.0f);
    __syncthreads();
    sh[d] = y;
    __syncthreads();
    float o = bm2[d];
    {
        const float4* hp = (const float4*)sh;
        for (int c4 = 0; c4 < 64; ++c4) {
            float4 x = hp[c4];
            int cb = c4 * 4;
            o += x.x * Wm2[cb * CD + d] + x.y * Wm2[(cb + 1) * CD + d]
               + x.z * Wm2[(cb + 2) * CD + d] + x.w * Wm2[(cb + 3) * CD + d];
        }
    }
    slots[row * CD + d] = sNew + o;
}

// recon head, loop-interchanged: weights read once, 16 rows accumulated inner.
__global__ __launch_bounds__(320) void recon_kernel(const float* __restrict__ slots,
                                                    const float* __restrict__ Wr1, const float* __restrict__ br1,
                                                    const float* __restrict__ g1, const float* __restrict__ be1,
                                                    const float* __restrict__ Wr2, const float* __restrict__ br2,
                                                    const float* __restrict__ g2, const float* __restrict__ be2,
                                                    const float* __restrict__ Wr3, const float* __restrict__ br3,
                                                    float* __restrict__ spts) {
    __shared__ float sl[16 * CD];
    __shared__ float h1[16 * CD];
    __shared__ float h2[16 * CD];
    int d = threadIdx.x;
    if (d < CD) for (int r = 0; r < 16; ++r) sl[r * CD + d] = slots[r * CD + d];
    __syncthreads();
    if (d < CD) {
        float t[16];
        #pragma unroll
        for (int r = 0; r < 16; ++r) t[r] = br1[d];
        for (int c4 = 0; c4 < 64; ++c4) {
            int cb = c4 * 4;
            float w0 = Wr1[cb * CD + d], w1 = Wr1[(cb + 1) * CD + d];
            float w2 = Wr1[(cb + 2) * CD + d], w3 = Wr1[(cb + 3) * CD + d];
            #pragma unroll
            for (int r = 0; r < 16; ++r) {
                float4 x = *(const float4*)(sl + r * CD + cb);
                t[r] += x.x * w0 + x.y * w1 + x.z * w2 + x.w * w3;
            }
        }
        float mean = 0.0f;
        for (int r = 0; r < 16; ++r) mean += t[r];
        mean *= (1.0f / 16.0f);
        float var = 0.0f;
        for (int r = 0; r < 16; ++r) { float dd = t[r] - mean; var += dd * dd; }
        var *= (1.0f / 16.0f);
        float inv = rsqrtf(var + 1e-5f);
        for (int r = 0; r < 16; ++r)
            h1[r * CD + d] = fmaxf(0.0f, (t[r] - mean) * inv * g1[d] + be1[d]);
    }
    __syncthreads();
    if (d < CD) {
        float t[16];
        #pragma unroll
        for (int r = 0; r < 16; ++r) t[r] = br2[d];
        for (int c4 = 0; c4 < 64; ++c4) {
            int cb = c4 * 4;
            float w0 = Wr2[cb * CD + d], w1 = Wr2[(cb + 1) * CD + d];
            float w2 = Wr2[(cb + 2) * CD + d], w3 = Wr2[(cb + 3) * CD + d];
            #pragma unroll
            for (int r = 0; r < 16; ++r) {
                float4 x = *(const float4*)(h1 + r * CD + cb);
                t[r] += x.x * w0 + x.y * w1 + x.z * w2 + x.w * w3;
            }
        }
        float mean = 0.0f;
        for (int r = 0; r < 16; ++r) mean += t[r];
        mean *= (1.0f / 16.0f);
        float var = 0.0f;
        for (int r = 0; r < 16; ++r) { float dd = t[r] - mean; var += dd * dd; }
        var *= (1.0f / 16.0f);
        float inv = rsqrtf(var + 1e-5f);
        for (int r = 0; r < 16; ++r)
            h2[r * CD + d] = fmaxf(0.0f, (t[r] - mean) * inv * g2[d] + be2[d]);
    }
    __syncthreads();
    if (d < 288) {
        float t[16];
        #pragma unroll
        for (int r = 0; r < 16; ++r) t[r] = br3[d];
        for (int c4 = 0; c4 < 64; ++c4) {
            int cb = c4 * 4;
            float w0 = Wr3[cb * 288 + d], w1 = Wr3[(cb + 1) * 288 + d];
            float w2 = Wr3[(cb + 2) * 288 + d], w3 = Wr3[(cb + 3) * 288 + d];
            #pragma unroll
            for (int r = 0; r < 16; ++r) {
                float4 x = *(const float4*)(h2 + r * CD + cb);
                t[r] += x.x * w0 + x.y * w1 + x.z * w2 + x.w * w3;
            }
        }
        for (int r = 0; r < 16; ++r) spts[r * 288 + d] = t[r];
    }
}

// FPS: ONE WAVE per batch, zero barriers.
__global__ __launch_bounds__(64) void fps_kernel(const float* __restrict__ spts,
                                                 int* __restrict__ fidx,
                                                 float* __restrict__ lacc,
                                                 unsigned* __restrict__ mnbuf) {
    int b = blockIdx.x;
    int lane = threadIdx.x;
    const float* pts = spts + (size_t)b * 384 * 3;
    int* out = fidx + b * 128;
    if (lane == 0) out[0] = 0;
    if (b == 0 && lane == 0) lacc[0] = 0.0f;
    mnbuf[b * 128 + lane] = 0x7F800000u;
    mnbuf[b * 128 + 64 + lane] = 0x7F800000u;
    float px[6], py[6], pz[6], dd[6];
    #pragma unroll
    for (int i = 0; i < 6; ++i) {
        int m = i * 64 + lane;
        px[i] = pts[m * 3]; py[i] = pts[m * 3 + 1]; pz[i] = pts[m * 3 + 2];
        dd[i] = 1e10f;
    }
    float lx = pts[0], ly = pts[1], lz = pts[2];
    #pragma unroll 1
    for (int s = 1; s < 128; ++s) {
        #pragma unroll
        for (int i = 0; i < 6; ++i) {
            float dx = px[i] - lx, dy = py[i] - ly, dz = pz[i] - lz;
            dd[i] = fminf(dd[i], dx * dx + dy * dy + dz * dz);
        }
        float bv = dd[0]; int bi = lane;
        #pragma unroll
        for (int i = 1; i < 6; ++i)
            if (dd[i] > bv) { bv = dd[i]; bi = i * 64 + lane; }
        dpp_lexmax<0x111, 0xf>(bv, bi);
        dpp_lexmax<0x112, 0xf>(bv, bi);
        dpp_lexmax<0x114, 0xf>(bv, bi);
        dpp_lexmax<0x118, 0xf>(bv, bi);
        dpp_lexmax<0x142, 0xa>(bv, bi);
        dpp_lexmax<0x143, 0xc>(bv, bi);
        int fm = __builtin_amdgcn_readlane(bi, 63);
        if (lane == 0) out[s] = fm;
        int slot = fm >> 6, sl_lane = fm & 63;
        float sx = px[0], sy = py[0], sz = pz[0];
        #pragma unroll
        for (int i = 1; i < 6; ++i)
            if (slot == i) { sx = px[i]; sy = py[i]; sz = pz[i]; }
        lx = __int_as_float(__builtin_amdgcn_readlane(__float_as_int(sx), sl_lane));
        ly = __int_as_float(__builtin_amdgcn_readlane(__float_as_int(sy), sl_lane));
        lz = __int_as_float(__builtin_amdgcn_readlane(__float_as_int(sz), sl_lane));
    }
}

// chamfer direction 2: per input point n, min over the 128 sampled ds points.
__global__ __launch_bounds__(256) void chamfer_sum2_kernel(const float* __restrict__ spts,
                                                           const int* __restrict__ fidx,
                                                           const float* __restrict__ xyz,
                                                           float* __restrict__ lacc) {
    int b = blockIdx.x >> 4, chunk = blockIdx.x & 15;
    int t = threadIdx.x;
    __shared__ float ds[128 * 3];
    __shared__ float red[4];
    const float* pts = spts + (size_t)b * 384 * 3;
    if (t < 128) {
        int j = fidx[b * 128 + t];
        ds[t * 3] = pts[j * 3]; ds[t * 3 + 1] = pts[j * 3 + 1]; ds[t * 3 + 2] = pts[j * 3 + 2];
    }
    __syncthreads();
    int n = chunk * 256 + t;
    const float* xb = xyz + (size_t)b * NPTS * 3;
    float px = xb[n * 3], py = xb[n * 3 + 1], pz = xb[n * 3 + 2];
    float mn = 1e30f;
    #pragma unroll 4
    for (int jj = 0; jj < 128; ++jj) {
        float dx = ds[jj * 3] - px, dy = ds[jj * 3 + 1] - py, dz = ds[jj * 3 + 2] - pz;
        mn = fminf(mn, dx * dx + dy * dy + dz * dz);
    }
    float total = block_sum256(mn * (1.0f / 4096.0f), red);
    if (t == 0) atomicAdd(lacc, total);
}

// chamfer direction 1: per sampled ds point j, exact min via uint atomicMin.
__global__ __launch_bounds__(128) void chamfer_min1_kernel(const float* __restrict__ spts,
                                                           const int* __restrict__ fidx,
                                                           const float* __restrict__ xyz,
                                                           unsigned* __restrict__ mnbuf) {
    int b = blockIdx.x >> 4, chunk = blockIdx.x & 15;
    int t = threadIdx.x;   // 128
    __shared__ float tile[256 * 3];
    const float* xb = xyz + ((size_t)b * NPTS + chunk * 256) * 3;
    for (int i = t; i < 768; i += 128) tile[i] = xb[i];
    __syncthreads();
    int j = fidx[b * 128 + t];
    const float* pts = spts + (size_t)b * 384 * 3;
    float px = pts[j * 3], py = pts[j * 3 + 1], pz = pts[j * 3 + 2];
    float mn = 1e30f;
    #pragma unroll 4
    for (int i = 0; i < 256; ++i) {
        float dx = tile[i * 3] - px, dy = tile[i * 3 + 1] - py, dz = tile[i * 3 + 2] - pz;
        mn = fminf(mn, dx * dx + dy * dy + dz * dz);
    }
    atomicMin(&mnbuf[b * 128 + t], __float_as_uint(mn));
}

// final: sum the 512 per-ds-point mins (/128 per batch), add lacc, write loss
__global__ __launch_bounds__(512) void chamfer_final_kernel(const unsigned* __restrict__ mnbuf,
                                                            const float* __restrict__ lacc,
                                                            float* __restrict__ out) {
    int t = threadIdx.x;   // 512
    __shared__ float r[8];
    float v = __uint_as_float(mnbuf[t]) * (1.0f / 128.0f);
    #pragma unroll
    for (int o = 32; o; o >>= 1) v += __shfl_down(v, o);
    if ((t & 63) == 0) r[t >> 6] = v;
    __syncthreads();
    if (t == 0) {
        float tot = 0.0f;
        #pragma unroll
        for (int i = 0; i < 8; ++i) tot += r[i];
        out[0] = (lacc[0] + tot) * 0.25f;
    }
}

// ---------------- launch ----------------

extern "C" void kernel_launch(void* const* d_in, const int* in_sizes, int n_in,
                              void* d_out, int out_size, void* d_ws, size_t ws_size,
                              hipStream_t stream) {
    (void)in_sizes; (void)n_in; (void)out_size; (void)ws_size;
    const float* x    = (const float*)d_in[0];
    const float* W1   = (const float*)d_in[2];
    const float* b1   = (const float*)d_in[3];
    const float* W2   = (const float*)d_in[4];
    const float* b2   = (const float*)d_in[5];
    const float* mu   = (const float*)d_in[6];
    const float* sg   = (const float*)d_in[7];
    const float* g_in = (const float*)d_in[8];
    const float* b_in = (const float*)d_in[9];
    const float* g_sl = (const float*)d_in[10];
    const float* b_sl = (const float*)d_in[11];
    const float* g_ff = (const float*)d_in[12];
    const float* b_ff = (const float*)d_in[13];
    const float* Wq   = (const float*)d_in[14];
    const float* Wk   = (const float*)d_in[15];
    const float* Wv   = (const float*)d_in[16];
    const float* W_ih = (const float*)d_in[17];
    const float* W_hh = (const float*)d_in[18];
    const float* b_ih = (const float*)d_in[19];
    const float* b_hh = (const float*)d_in[20];
    const float* Wm1  = (const float*)d_in[21];
    const float* bm1  = (const float*)d_in[22];
    const float* Wm2  = (const float*)d_in[23];
    const float* bm2  = (const float*)d_in[24];
    const float* Wr1  = (const float*)d_in[25];
    const float* br1  = (const float*)d_in[26];
    const float* g1   = (const float*)d_in[27];
    const float* be1  = (const float*)d_in[28];
    const float* Wr2  = (const float*)d_in[29];
    const float* br2  = (const float*)d_in[30];
    const float* g2   = (const float*)d_in[31];
    const float* be2  = (const float*)d_in[32];
    const float* Wr3  = (const float*)d_in[33];
    const float* br3  = (const float*)d_in[34];

    float* ws    = (float*)d_ws;
    float* xyz   = ws;                               // 49152 f
    float* xyzw  = xyz + 49152;                      // 65536 f (float4 [B*N])
    int*   knn   = (int*)(xyzw + 65536);             // 524288 i
    _Float16* f1h = (_Float16*)(knn + 524288);       // 2097152 h = 1048576 f
    _Float16* W2t = (_Float16*)((float*)f1h + 1048576);  // 40960 h -> 20480 f
    _Float16* WkvT = (_Float16*)((float*)W2t + 20480);   // 131072 h -> 65536 f
    _Float16* inph = (_Float16*)((float*)WkvT + 65536);  // 4194304 h -> 2097152 f
    float* kkb   = (float*)inph + 2097152;           // 4194304 f
    float* vvb   = kkb + 4194304;                    // 4194304 f
    float* slots = vvb + 4194304;                    // 4096 f
    float* asum  = slots + 4096;                     // 16 f
    float* updp  = asum + 16;                        // 65536 f
    float* gi    = updp + 65536;                     // 12288 f
    float* gh    = gi + 12288;                       // 12288 f
    float* spts  = gh + 12288;                       // 4608 f
    int*   fidx  = (int*)(spts + 4608);              // 512 i
    float* lacc  = (float*)(fidx + 512);             // 1 f
    unsigned* mnbuf = (unsigned*)(lacc + 1);         // 512 u

    float* out = (float*)d_out;

    prep_kernel<<<64, 256, 0, stream>>>(x, xyz, (float4*)xyzw);
    slots_init_kernel<<<8, 256, 0, stream>>>(mu, sg, slots, asum);
    knn_kernel<<<NBATCH * NPTS / 4, 256, 0, stream>>>((const float4*)xyzw, knn);
    conv1_kernel<<<NBATCH * NPTS, 128, 0, stream>>>(xyz, knn, W1, b1, f1h);
    w2t_kernel<<<256, 160, 0, stream>>>(W2, W2t);
    wkvt_kernel<<<512, 256, 0, stream>>>(Wk, Wv, WkvT);
    conv2_mfma_kernel<<<NBATCH * NPTS / 2, 256, 0, stream>>>(xyz, f1h, knn, W2t, b2, g_in, b_in, inph);
    kv_mfma_kernel<<<NBATCH * NPTS / 64 * 2, 256, 0, stream>>>(inph, WkvT, kkb, vvb);

    for (int it = 0; it < 3; ++it) {
        slot_attn_kernel<<<64, 256, 0, stream>>>(slots, g_sl, b_sl, Wq, kkb, vvb, asum, updp,
                                                 (it == 2) ? (out + 1) : (float*)nullptr);
        gru_gates_kernel<<<48, 256, 0, stream>>>(updp, asum, slots, W_ih, W_hh, b_ih, b_hh, gi, gh);
        gru_mlp_kernel<<<16, 256, 0, stream>>>(gi, gh, slots, g_ff, b_ff, Wm1, bm1, Wm2, bm2, asum);
    }

    recon_kernel<<<1, 320, 0, stream>>>(slots, Wr1, br1, g1, be1, Wr2, br2, g2, be2, Wr3, br3, spts);
    fps_kernel<<<4, 64, 0, stream>>>(spts, fidx, lacc, mnbuf);
    chamfer_sum2_kernel<<<64, 256, 0, stream>>>(spts, fidx, xyz, lacc);
    chamfer_min1_kernel<<<64, 128, 0, stream>>>(spts, fidx, xyz, mnbuf);
    chamfer_final_kernel<<<1, 512, 0, stream>>>(mnbuf, lacc, out);
}

// Round 11
// 741.574 us; speedup vs baseline: 1.0602x; 1.0602x over previous
//
#include <hip/hip_runtime.h>

#define NBATCH 4
#define NPTS   4096
#define KNNK   32
#define C1D    128
#define CD     256
#define KPAD   160   // conv2 K padded (131 -> 160, 5 mfma K-steps of 32)
#define ASTR   168   // conv2 LDS A row stride in halves
#define ASTR2  264   // kv LDS A row stride in halves (256 cols + 8 pad)

typedef _Float16 v8h __attribute__((ext_vector_type(8)));
typedef float    v4f __attribute__((ext_vector_type(4)));
typedef unsigned long long ull;

// ---------------- helpers ----------------

__device__ __forceinline__ float block_sum256(float v, float* red) {
    #pragma unroll
    for (int o = 32; o; o >>= 1) v += __shfl_down(v, o);
    __syncthreads();
    if ((threadIdx.x & 63) == 0) red[threadIdx.x >> 6] = v;
    __syncthreads();
    return red[0] + red[1] + red[2] + red[3];
}

__device__ __forceinline__ unsigned rotl32(unsigned x, unsigned r) {
    return (x << r) | (x >> (32u - r));
}

// XLA f32 erf_inv (Giles polynomial)
__device__ float erfinv_f(float x) {
    float w = -log1pf(-x * x);
    float p;
    if (w < 5.0f) {
        w -= 2.5f;
        p = 2.81022636e-08f;
        p = fmaf(p, w, 3.43273939e-07f);
        p = fmaf(p, w, -3.5233877e-06f);
        p = fmaf(p, w, -4.39150654e-06f);
        p = fmaf(p, w, 0.00021858087f);
        p = fmaf(p, w, -0.00125372503f);
        p = fmaf(p, w, -0.00417768164f);
        p = fmaf(p, w, 0.246640727f);
        p = fmaf(p, w, 1.50140941f);
    } else {
        w = sqrtf(w) - 3.0f;
        p = -0.000200214257f;
        p = fmaf(p, w, 0.000100950558f);
        p = fmaf(p, w, 0.00134934322f);
        p = fmaf(p, w, -0.00367342844f);
        p = fmaf(p, w, 0.00573950773f);
        p = fmaf(p, w, -0.0076224613f);
        p = fmaf(p, w, 0.00943887047f);
        p = fmaf(p, w, 1.00167406f);
        p = fmaf(p, w, 2.83297682f);
    }
    return p * x;
}

__device__ __forceinline__ float bits_to_normal(unsigned bits) {
    unsigned fb = (bits >> 9) | 0x3f800000u;
    float f = __uint_as_float(fb) - 1.0f;
    const float lo = -0.99999994f;           // nextafterf(-1,0)
    float u = fmaf(f, 2.0f, lo);
    u = fmaxf(u, lo);
    return 1.41421356237f * erfinv_f(u);
}

// order-preserving float->uint map (strictly monotonic over non-NaN floats)
__device__ __forceinline__ unsigned fmap(float f) {
    unsigned b = __float_as_uint(f);
    return (b & 0x80000000u) ? ~b : (b | 0x80000000u);
}

// one DPP level of u64-key min (key = mapped_dist:idx) — 2 dpp + cmp_u64 + 2 cndmask
template <int CTRL, int RM>
__device__ __forceinline__ ull dpp_min_u64(ull k) {
    unsigned lo = (unsigned)k, hi = (unsigned)(k >> 32);
    unsigned tlo = (unsigned)__builtin_amdgcn_update_dpp((int)lo, (int)lo, CTRL, RM, 0xf, false);
    unsigned thi = (unsigned)__builtin_amdgcn_update_dpp((int)hi, (int)hi, CTRL, RM, 0xf, false);
    ull t = ((ull)thi << 32) | tlo;
    return t < k ? t : k;
}

// lexicographic max (value desc, index asc on ties) — matches jnp.argmax
template <int CTRL, int RM>
__device__ __forceinline__ void dpp_lexmax(float& v, int& ix) {
    int tv = __builtin_amdgcn_update_dpp(__float_as_int(v), __float_as_int(v), CTRL, RM, 0xf, false);
    int ti = __builtin_amdgcn_update_dpp(ix, ix, CTRL, RM, 0xf, false);
    float fv = __int_as_float(tv);
    bool take = (fv > v) || (fv == v && ti < ix);
    v  = take ? fv : v;
    ix = take ? ti : ix;
}

// ---------------- kernels ----------------

// x [B,3,N] -> xyz [B,N,3], xyzw [B,N] (x,y,z,sq)
__global__ void prep_kernel(const float* __restrict__ x, float* __restrict__ xyz,
                            float4* __restrict__ xyzw) {
    int gid = blockIdx.x * 256 + threadIdx.x;
    if (gid >= NBATCH * NPTS) return;
    int b = gid >> 12, n = gid & (NPTS - 1);
    float a0 = x[(b * 3 + 0) * NPTS + n];
    float a1 = x[(b * 3 + 1) * NPTS + n];
    float a2 = x[(b * 3 + 2) * NPTS + n];
    xyz[gid * 3 + 0] = a0; xyz[gid * 3 + 1] = a1; xyz[gid * 3 + 2] = a2;
    float sq = a0 * a0 + a1 * a1 + a2 * a2;
    xyzw[gid] = make_float4(a0, a1, a2, sq);
}

// JAX threefry2x32, key(42) -> slots = mu + sigma * normal; also zero asum
__global__ void slots_init_kernel(const float* __restrict__ mu, const float* __restrict__ sg,
                                  float* __restrict__ slots, float* __restrict__ asum) {
    int j = blockIdx.x * 256 + threadIdx.x;
    if (j < 16) asum[j] = 0.0f;
    if (j >= 2048) return;
    unsigned ks0 = 0u, ks1 = 42u, ks2 = 0u ^ 42u ^ 0x1BD11BDAu;
    unsigned x0 = (unsigned)j + ks0;
    unsigned x1 = (unsigned)(j + 2048) + ks1;
    #define RND(r) { x0 += x1; x1 = rotl32(x1, r); x1 ^= x0; }
    RND(13u) RND(15u) RND(26u) RND(6u);  x0 += ks1; x1 += ks2 + 1u;
    RND(17u) RND(29u) RND(16u) RND(24u); x0 += ks2; x1 += ks0 + 2u;
    RND(13u) RND(15u) RND(26u) RND(6u);  x0 += ks0; x1 += ks1 + 3u;
    RND(17u) RND(29u) RND(16u) RND(24u); x0 += ks1; x1 += ks2 + 4u;
    RND(13u) RND(15u) RND(26u) RND(6u);  x0 += ks2; x1 += ks0 + 5u;
    #undef RND
    int c0 = j & 255, c1 = (j + 2048) & 255;
    slots[j]        = mu[c0] + sg[c0] * bits_to_normal(x0);
    slots[j + 2048] = mu[c1] + sg[c1] * bits_to_normal(x1);
}

// KNN: one wave per point, no barriers. Dists stored as order-mapped uints in
// 8 groups of 8/lane. Per round: u64-key DPP wave argmin (exact (dist,idx)
// lex order incl. ties) + owner-only rescan. Matches lax.top_k exactly.
__global__ __launch_bounds__(256) void knn_kernel(const float4* __restrict__ xyzw,
                                                  int* __restrict__ knn_idx) {
    int wid = threadIdx.x >> 6, lane = threadIdx.x & 63;
    int pid = blockIdx.x * 4 + wid;
    int b = pid >> 12, n = pid & (NPTS - 1);
    const float4* xb = xyzw + (size_t)b * NPTS;
    float4 p = xb[n];
    unsigned d[64];
    #pragma unroll
    for (int i = 0; i < 64; ++i) {
        float4 c = xb[i * 64 + lane];
        float dot = p.x * c.x + p.y * c.y + p.z * c.z;
        d[i] = fmap(p.w + c.w - 2.0f * dot);
    }
    unsigned gv[8]; int gi[8];
    #pragma unroll
    for (int g = 0; g < 8; ++g) {
        unsigned mv = d[g * 8]; int mi = g * 8;
        #pragma unroll
        for (int j = 1; j < 8; ++j)
            if (d[g * 8 + j] < mv) { mv = d[g * 8 + j]; mi = g * 8 + j; }
        gv[g] = mv; gi[g] = mi * 64 + lane;
    }
    unsigned lv = gv[0]; int li = gi[0];
    #pragma unroll
    for (int g = 1; g < 8; ++g)
        if (gv[g] < lv) { lv = gv[g]; li = gi[g]; }

    int* out = knn_idx + (size_t)pid * KNNK;
    #pragma unroll 1
    for (int s = 0; s < KNNK; ++s) {
        ull k = ((ull)lv << 32) | (unsigned)li;
        k = dpp_min_u64<0x111, 0xf>(k);
        k = dpp_min_u64<0x112, 0xf>(k);
        k = dpp_min_u64<0x114, 0xf>(k);
        k = dpp_min_u64<0x118, 0xf>(k);
        k = dpp_min_u64<0x142, 0xa>(k);
        k = dpp_min_u64<0x143, 0xc>(k);
        int fm = __builtin_amdgcn_readlane((int)(unsigned)k, 63);
        if (lane == 0) out[s] = fm;
        int flane = fm & 63;
        int slot  = fm >> 6;
        if (lane == flane) {
            int g = slot >> 3;
            #pragma unroll
            for (int g2 = 0; g2 < 8; ++g2) {
                if (g2 == g) {
                    #pragma unroll
                    for (int j = 0; j < 8; ++j)
                        if (g2 * 8 + j == slot) d[g2 * 8 + j] = 0xFFFFFFFFu;
                    unsigned mv = d[g2 * 8]; int mi = g2 * 8;
                    #pragma unroll
                    for (int j = 1; j < 8; ++j)
                        if (d[g2 * 8 + j] < mv) { mv = d[g2 * 8 + j]; mi = g2 * 8 + j; }
                    gv[g2] = mv; gi[g2] = mi * 64 + lane;
                }
            }
            lv = gv[0]; li = gi[0];
            #pragma unroll
            for (int g2 = 1; g2 < 8; ++g2)
                if (gv[g2] < lv) { lv = gv[g2]; li = gi[g2]; }
        }
    }
}

// conv1 -> fp16 features; neighbor coords preloaded into lanes 0..31
__global__ __launch_bounds__(128) void conv1_kernel(const float* __restrict__ xyz,
                                                    const int* __restrict__ knn_idx,
                                                    const float* __restrict__ W1,
                                                    const float* __restrict__ b1,
                                                    _Float16* __restrict__ f1h) {
    int pid = blockIdx.x;
    int b = pid >> 12, n = pid & (NPTS - 1);
    int d = threadIdx.x, lane = threadIdx.x & 63;
    const float* xb = xyz + (size_t)b * NPTS * 3;
    float w0 = W1[d], wx = W1[C1D + d], wy = W1[2 * C1D + d], wz = W1[3 * C1D + d];
    float bb = b1[d];
    float px = xb[n * 3], py = xb[n * 3 + 1], pz = xb[n * 3 + 2];
    const int* idx = knn_idx + (size_t)pid * KNNK;
    float cx = 0.0f, cy = 0.0f, cz = 0.0f;
    if (lane < 32) {
        int j = idx[lane];
        cx = xb[j * 3]; cy = xb[j * 3 + 1]; cz = xb[j * 3 + 2];
    }
    float m = -1e30f;
    #pragma unroll
    for (int k = 0; k < KNNK; ++k) {
        float jx = __shfl(cx, k), jy = __shfl(cy, k), jz = __shfl(cz, k);
        float v = w0 + bb + (jx - px) * wx + (jy - py) * wy + (jz - pz) * wz;
        m = fmaxf(m, v);
    }
    f1h[(size_t)pid * C1D + d] = (_Float16)fmaxf(m, 0.0f);
}

// W2 [131x256 fp32] -> W2t [256][160] fp16 (transposed, zero-padded)
__global__ void w2t_kernel(const float* __restrict__ W2, _Float16* __restrict__ W2t) {
    int n = blockIdx.x;          // 0..255
    int k = threadIdx.x;         // 0..159
    W2t[n * KPAD + k] = (k < 131) ? (_Float16)W2[k * CD + n] : (_Float16)0.0f;
}

// Wk/Wv [256x256 fp32] -> WkvT [512][256] fp16 (transposed, Wk rows then Wv rows)
__global__ void wkvt_kernel(const float* __restrict__ Wk, const float* __restrict__ Wv,
                            _Float16* __restrict__ WkvT) {
    int n = blockIdx.x;          // 0..511
    int c = threadIdx.x;         // 0..255
    float v = (n < 256) ? Wk[c * CD + n] : Wv[c * CD + (n - 256)];
    WkvT[n * CD + c] = (_Float16)v;
}

// conv2 via MFMA f16 + fused bias/relu/max-over-k/LayerNorm -> inph fp16
__global__ __launch_bounds__(256) void conv2_mfma_kernel(const float* __restrict__ xyz,
                                                         const _Float16* __restrict__ f1h,
                                                         const int* __restrict__ knn_idx,
                                                         const _Float16* __restrict__ W2t,
                                                         const float* __restrict__ b2,
                                                         const float* __restrict__ g_in,
                                                         const float* __restrict__ b_in,
                                                         _Float16* __restrict__ inph) {
    __shared__ _Float16 A[64 * ASTR];
    __shared__ float colmax[2 * CD];
    __shared__ float red[4];
    int pid2 = blockIdx.x;
    int gp0 = pid2 * 2;
    int b = gp0 >> 12, n0 = gp0 & (NPTS - 1);
    int tid = threadIdx.x;
    const int* idx = knn_idx + (size_t)pid2 * 64;   // [2][32]
    const float* xb = xyz + (size_t)b * NPTS * 3;

    {
        int r = tid & 63, seg = tid >> 6;
        int j = idx[r];
        const uint4* s4 = (const uint4*)(f1h + ((size_t)b * NPTS + j) * C1D);
        uint4* d4 = (uint4*)&A[r * ASTR];
        #pragma unroll
        for (int i = 0; i < 4; ++i) d4[seg * 4 + i] = s4[seg * 4 + i];
        unsigned* z = (unsigned*)&A[r * ASTR + 128];
        for (int i = seg; i < 20; i += 4) z[i] = 0u;
        int np_ = (r < 32) ? n0 : (n0 + 1);
        if (seg == 0) {
            A[r * ASTR + 128] = (_Float16)(xb[j * 3 + 0] - xb[np_ * 3 + 0]);
            A[r * ASTR + 129] = (_Float16)(xb[j * 3 + 1] - xb[np_ * 3 + 1]);
        } else if (seg == 1) {
            A[r * ASTR + 130] = (_Float16)(xb[j * 3 + 2] - xb[np_ * 3 + 2]);
        }
    }
    __syncthreads();

    int w = tid >> 6, lane = tid & 63, quad = lane >> 4, lr = lane & 15;
    v4f acc[4][4];
    #pragma unroll
    for (int rt = 0; rt < 4; ++rt)
        #pragma unroll
        for (int ct = 0; ct < 4; ++ct)
            acc[rt][ct] = (v4f){0.0f, 0.0f, 0.0f, 0.0f};

    #pragma unroll
    for (int kk = 0; kk < KPAD; kk += 32) {
        v8h af[4], bf[4];
        #pragma unroll
        for (int rt = 0; rt < 4; ++rt)
            af[rt] = *(const v8h*)&A[(rt * 16 + lr) * ASTR + kk + quad * 8];
        #pragma unroll
        for (int ct = 0; ct < 4; ++ct) {
            int ncol = w * 64 + ct * 16 + lr;
            bf[ct] = *(const v8h*)(W2t + (size_t)ncol * KPAD + kk + quad * 8);
        }
        #pragma unroll
        for (int rt = 0; rt < 4; ++rt)
            #pragma unroll
            for (int ct = 0; ct < 4; ++ct)
                acc[rt][ct] = __builtin_amdgcn_mfma_f32_16x16x32_f16(af[rt], bf[ct], acc[rt][ct], 0, 0, 0);
    }

    #pragma unroll
    for (int ct = 0; ct < 4; ++ct) {
        float tm[4];
        #pragma unroll
        for (int rt = 0; rt < 4; ++rt) {
            v4f a = acc[rt][ct];
            float v = fmaxf(fmaxf(a[0], a[1]), fmaxf(a[2], a[3]));
            v = fmaxf(v, __shfl_xor(v, 16));
            v = fmaxf(v, __shfl_xor(v, 32));
            tm[rt] = v;
        }
        float p0 = fmaxf(tm[0], tm[1]);
        float p1 = fmaxf(tm[2], tm[3]);
        if (quad == 0) {
            colmax[0 * CD + w * 64 + ct * 16 + lr] = p0;
            colmax[1 * CD + w * 64 + ct * 16 + lr] = p1;
        }
    }
    __syncthreads();

    int d = tid;
    #pragma unroll
    for (int p = 0; p < 2; ++p) {
        float v = fmaxf(colmax[p * CD + d] + b2[d], 0.0f);
        float s = block_sum256(v, red);
        float mean = s * (1.0f / 256.0f);
        float s2 = block_sum256(v * v, red);
        float var = s2 * (1.0f / 256.0f) - mean * mean;
        float iv = (v - mean) * rsqrtf(var + 1e-5f) * g_in[d] + b_in[d];
        inph[(size_t)(gp0 + p) * CD + d] = (_Float16)iv;
    }
}

// kv via MFMA fp16: block = 64 points x 256 cols; half 0 -> kk, half 1 -> vv.
__global__ __launch_bounds__(256) void kv_mfma_kernel(const _Float16* __restrict__ inph,
                                                      const _Float16* __restrict__ WkvT,
                                                      float* __restrict__ kk,
                                                      float* __restrict__ vv) {
    __shared__ _Float16 A[64 * ASTR2];
    int rb = blockIdx.x >> 1, half = blockIdx.x & 1;
    int row0 = rb * 64;
    int tid = threadIdx.x;
    {
        const uint4* src4 = (const uint4*)(inph + (size_t)row0 * CD);
        #pragma unroll
        for (int i = 0; i < 8; ++i) {
            int idx = i * 256 + tid;
            int row = idx >> 5, c8 = idx & 31;
            *(uint4*)&A[row * ASTR2 + c8 * 8] = src4[idx];
        }
    }
    __syncthreads();
    int w = tid >> 6, lane = tid & 63, quad = lane >> 4, lr = lane & 15;
    v4f acc[4][4];
    #pragma unroll
    for (int rt = 0; rt < 4; ++rt)
        #pragma unroll
        for (int ct = 0; ct < 4; ++ct)
            acc[rt][ct] = (v4f){0.0f, 0.0f, 0.0f, 0.0f};
    #pragma unroll
    for (int ks = 0; ks < CD; ks += 32) {
        v8h af[4], bf[4];
        #pragma unroll
        for (int rt = 0; rt < 4; ++rt)
            af[rt] = *(const v8h*)&A[(rt * 16 + lr) * ASTR2 + ks + quad * 8];
        #pragma unroll
        for (int ct = 0; ct < 4; ++ct) {
            int ncol = half * 256 + w * 64 + ct * 16 + lr;
            bf[ct] = *(const v8h*)(WkvT + (size_t)ncol * CD + ks + quad * 8);
        }
        #pragma unroll
        for (int rt = 0; rt < 4; ++rt)
            #pragma unroll
            for (int ct = 0; ct < 4; ++ct)
                acc[rt][ct] = __builtin_amdgcn_mfma_f32_16x16x32_f16(af[rt], bf[ct], acc[rt][ct], 0, 0, 0);
    }
    float* dst = half ? vv : kk;
    #pragma unroll
    for (int rt = 0; rt < 4; ++rt)
        #pragma unroll
        for (int ct = 0; ct < 4; ++ct) {
            int col = w * 64 + ct * 16 + lr;
            #pragma unroll
            for (int r = 0; r < 4; ++r) {
                int row = rt * 16 + quad * 4 + r;
                dst[(size_t)(row0 + row) * CD + col] = acc[rt][ct][r];
            }
        }
}

// q = LN(slots) @ Wq, one block per row (b,k) — identical arithmetic to R9
__global__ __launch_bounds__(256) void slotq_kernel(const float* __restrict__ slots,
                                                    const float* __restrict__ g_sl,
                                                    const float* __restrict__ b_sl,
                                                    const float* __restrict__ Wq,
                                                    float* __restrict__ q) {
    int row = blockIdx.x;
    int d = threadIdx.x;
    __shared__ float sl[CD];
    __shared__ float red[4];
    float v = slots[row * CD + d];
    float s = block_sum256(v, red);
    float mean = s * (1.0f / 256.0f);
    float s2 = block_sum256(v * v, red);
    float var = s2 * (1.0f / 256.0f) - mean * mean;
    float ln = (v - mean) * rsqrtf(var + 1e-5f) * g_sl[d] + b_sl[d];
    sl[d] = ln;
    __syncthreads();
    float acc = 0.0f;
    const float4* sp = (const float4*)sl;
    for (int c4 = 0; c4 < 64; ++c4) {
        float4 x = sp[c4];
        int cb = c4 * 4;
        acc += x.x * Wq[cb * CD + d] + x.y * Wq[(cb + 1) * CD + d]
             + x.z * Wq[(cb + 2) * CD + d] + x.w * Wq[(cb + 3) * CD + d];
    }
    q[row * CD + d] = acc;
}

// FUSED attn+updp: logits -> softmax -> asum atomic -> updp partials, with
// attn kept in LDS. One block per (batch, 256-pt chunk).
__global__ __launch_bounds__(256) void attn_updp_kernel(const float* __restrict__ q,
                                                        const float* __restrict__ kk,
                                                        const float* __restrict__ vv,
                                                        float* __restrict__ asum,
                                                        float* __restrict__ updp,
                                                        float* __restrict__ out_attn) {
    int b = blockIdx.x >> 4;
    int chunk = blockIdx.x & 15;
    int t = threadIdx.x;
    __shared__ float qs[4 * CD];
    __shared__ float aw[256 * 4];
    __shared__ float redk[16];
    for (int i = t; i < 4 * CD; i += 256) qs[i] = q[b * 4 * CD + i];
    __syncthreads();

    int n = chunk * 256 + t;
    const float4* kp = (const float4*)(kk + ((size_t)b * NPTS + n) * CD);
    const float4* q0 = (const float4*)(qs);
    const float4* q1 = (const float4*)(qs + CD);
    const float4* q2 = (const float4*)(qs + 2 * CD);
    const float4* q3 = (const float4*)(qs + 3 * CD);
    float a0 = 0, a1 = 0, a2 = 0, a3 = 0;
    for (int c4 = 0; c4 < 64; ++c4) {
        float4 kv = kp[c4];
        float4 x;
        x = q0[c4]; a0 += kv.x * x.x + kv.y * x.y + kv.z * x.z + kv.w * x.w;
        x = q1[c4]; a1 += kv.x * x.x + kv.y * x.y + kv.z * x.z + kv.w * x.w;
        x = q2[c4]; a2 += kv.x * x.x + kv.y * x.y + kv.z * x.z + kv.w * x.w;
        x = q3[c4]; a3 += kv.x * x.x + kv.y * x.y + kv.z * x.z + kv.w * x.w;
    }
    const float scale = 0.0625f;   // 256^-0.5
    float l0 = scale * a0, l1 = scale * a1, l2 = scale * a2, l3 = scale * a3;
    float mx = fmaxf(fmaxf(l0, l1), fmaxf(l2, l3));
    float e0 = expf(l0 - mx), e1 = expf(l1 - mx), e2 = expf(l2 - mx), e3 = expf(l3 - mx);
    float inv = 1.0f / (e0 + e1 + e2 + e3);
    e0 *= inv; e1 *= inv; e2 *= inv; e3 *= inv;
    aw[t * 4 + 0] = e0; aw[t * 4 + 1] = e1; aw[t * 4 + 2] = e2; aw[t * 4 + 3] = e3;
    if (out_attn) {
        float* o = out_attn + ((size_t)b * NPTS + n) * 4;
        o[0] = e0; o[1] = e1; o[2] = e2; o[3] = e3;
    }
    float as[4] = {e0, e1, e2, e3};
    #pragma unroll
    for (int k = 0; k < 4; ++k) {
        float v = as[k];
        #pragma unroll
        for (int o = 32; o; o >>= 1) v += __shfl_down(v, o);
        if ((t & 63) == 0) redk[(t >> 6) * 4 + k] = v;
    }
    __syncthreads();   // also publishes aw
    if (t < 4) {
        float s = redk[t] + redk[4 + t] + redk[8 + t] + redk[12 + t];
        atomicAdd(&asum[b * 4 + t], s);
    }

    float ac0 = 0.0f, ac1 = 0.0f, ac2 = 0.0f, ac3 = 0.0f;
    const float* vb = vv + ((size_t)b * NPTS + chunk * 256) * CD;
    for (int nn2 = 0; nn2 < 256; ++nn2) {
        float v = vb[(size_t)nn2 * CD + t];
        float4 w4 = *(const float4*)&aw[nn2 * 4];
        ac0 += w4.x * v; ac1 += w4.y * v; ac2 += w4.z * v; ac3 += w4.w * v;
    }
    updp[((size_t)(b * 4 + 0) * 16 + chunk) * CD + t] = ac0;
    updp[((size_t)(b * 4 + 1) * 16 + chunk) * CD + t] = ac1;
    updp[((size_t)(b * 4 + 2) * 16 + chunk) * CD + t] = ac2;
    updp[((size_t)(b * 4 + 3) * 16 + chunk) * CD + t] = ac3;
}

// GRU gates: gi = su@W_ih + b_ih, gh = sp@W_hh + b_hh; one block per (row,gate)
__global__ __launch_bounds__(256) void gru_gates_kernel(const float* __restrict__ updp,
                                                        const float* __restrict__ asum,
                                                        const float* __restrict__ slots,
                                                        const float* __restrict__ W_ih,
                                                        const float* __restrict__ W_hh,
                                                        const float* __restrict__ b_ih,
                                                        const float* __restrict__ b_hh,
                                                        float* __restrict__ gi,
                                                        float* __restrict__ gh) {
    int row = blockIdx.x / 3, gate = blockIdx.x % 3;
    int d = threadIdx.x;
    __shared__ float su[CD], sp[CD];
    float f = 1.0f / (asum[row] + 1e-8f);
    float u = 0.0f;
    for (int p = 0; p < 16; ++p) u += updp[((size_t)row * 16 + p) * CD + d];
    u *= f;
    su[d] = u; sp[d] = slots[row * CD + d];
    __syncthreads();
    float acc_i = b_ih[gate * CD + d];
    float acc_h = b_hh[gate * CD + d];
    const float* wi = W_ih + gate * CD + d;
    const float* wh = W_hh + gate * CD + d;
    for (int c = 0; c < CD; ++c) {
        acc_i += su[c] * wi[c * 3 * CD];
        acc_h += sp[c] * wh[c * 3 * CD];
    }
    gi[row * 3 * CD + gate * CD + d] = acc_i;
    gh[row * 3 * CD + gate * CD + d] = acc_h;
}

// GRU update + LN_ff + MLP residual, one block per row; zeroes asum for next iter
__global__ __launch_bounds__(256) void gru_mlp_kernel(const float* __restrict__ gi,
                                                      const float* __restrict__ gh,
                                                      float* __restrict__ slots,
                                                      const float* __restrict__ g_ff,
                                                      const float* __restrict__ b_ff,
                                                      const float* __restrict__ Wm1,
                                                      const float* __restrict__ bm1,
                                                      const float* __restrict__ Wm2,
                                                      const float* __restrict__ bm2,
                                                      float* __restrict__ asum) {
    int row = blockIdx.x;
    int d = threadIdx.x;
    __shared__ float sh[CD];
    __shared__ float red[4];
    float prev = slots[row * CD + d];
    float gir = gi[row * 3 * CD + d], giz = gi[row * 3 * CD + CD + d], gin = gi[row * 3 * CD + 2 * CD + d];
    float ghr = gh[row * 3 * CD + d], ghz = gh[row * 3 * CD + CD + d], ghn = gh[row * 3 * CD + 2 * CD + d];
    if (d == 0) asum[row] = 0.0f;
    float r = 1.0f / (1.0f + expf(-(gir + ghr)));
    float z = 1.0f / (1.0f + expf(-(giz + ghz)));
    float nn = tanhf(gin + r * ghn);
    float sNew = (1.0f - z) * nn + z * prev;
    float s = block_sum256(sNew, red);
    float mean = s * (1.0f / 256.0f);
    float s2 = block_sum256(sNew * sNew, red);
    float var = s2 * (1.0f / 256.0f) - mean * mean;
    float h = (sNew - mean) * rsqrtf(var + 1e-5f) * g_ff[d] + b_ff[d];
    __syncthreads();
    sh[d] = h;
    __syncthreads();
    float y = bm1[d];
    {
        const float4* hp = (const float4*)sh;
        for (int c4 = 0; c4 < 64; ++c4) {
            float4 x = hp[c4];
            int cb = c4 * 4;
            y += x.x * Wm1[cb * CD + d] + x.y * Wm1[(cb + 1) * CD + d]
               + x.z * Wm1[(cb + 2) * CD + d] + x.w * Wm1[(cb + 3) * CD + d];
        }
    }
    y = fmaxf(y, 0.0f);
    __syncthreads();
    sh[d] = y;
    __syncthreads();
    float o = bm2[d];
    {
        const float4* hp = (const float4*)sh;
        for (int c4 = 0; c4 < 64; ++c4) {
            float4 x = hp[c4];
            int cb = c4 * 4;
            o += x.x * Wm2[cb * CD + d] + x.y * Wm2[(cb + 1) * CD + d]
               + x.z * Wm2[(cb + 2) * CD + d] + x.w * Wm2[(cb + 3) * CD + d];
        }
    }
    slots[row * CD + d] = sNew + o;
}

// recon head, loop-interchanged: weights read once, 16 rows accumulated inner.
__global__ __launch_bounds__(320) void recon_kernel(const float* __restrict__ slots,
                                                    const float* __restrict__ Wr1, const float* __restrict__ br1,
                                                    const float* __restrict__ g1, const float* __restrict__ be1,
                                                    const float* __restrict__ Wr2, const float* __restrict__ br2,
                                                    const float* __restrict__ g2, const float* __restrict__ be2,
                                                    const float* __restrict__ Wr3, const float* __restrict__ br3,
                                                    float* __restrict__ spts) {
    __shared__ float sl[16 * CD];
    __shared__ float h1[16 * CD];
    __shared__ float h2[16 * CD];
    int d = threadIdx.x;
    if (d < CD) for (int r = 0; r < 16; ++r) sl[r * CD + d] = slots[r * CD + d];
    __syncthreads();
    if (d < CD) {
        float t[16];
        #pragma unroll
        for (int r = 0; r < 16; ++r) t[r] = br1[d];
        for (int c4 = 0; c4 < 64; ++c4) {
            int cb = c4 * 4;
            float w0 = Wr1[cb * CD + d], w1 = Wr1[(cb + 1) * CD + d];
            float w2 = Wr1[(cb + 2) * CD + d], w3 = Wr1[(cb + 3) * CD + d];
            #pragma unroll
            for (int r = 0; r < 16; ++r) {
                float4 x = *(const float4*)(sl + r * CD + cb);
                t[r] += x.x * w0 + x.y * w1 + x.z * w2 + x.w * w3;
            }
        }
        float mean = 0.0f;
        for (int r = 0; r < 16; ++r) mean += t[r];
        mean *= (1.0f / 16.0f);
        float var = 0.0f;
        for (int r = 0; r < 16; ++r) { float dd = t[r] - mean; var += dd * dd; }
        var *= (1.0f / 16.0f);
        float inv = rsqrtf(var + 1e-5f);
        for (int r = 0; r < 16; ++r)
            h1[r * CD + d] = fmaxf(0.0f, (t[r] - mean) * inv * g1[d] + be1[d]);
    }
    __syncthreads();
    if (d < CD) {
        float t[16];
        #pragma unroll
        for (int r = 0; r < 16; ++r) t[r] = br2[d];
        for (int c4 = 0; c4 < 64; ++c4) {
            int cb = c4 * 4;
            float w0 = Wr2[cb * CD + d], w1 = Wr2[(cb + 1) * CD + d];
            float w2 = Wr2[(cb + 2) * CD + d], w3 = Wr2[(cb + 3) * CD + d];
            #pragma unroll
            for (int r = 0; r < 16; ++r) {
                float4 x = *(const float4*)(h1 + r * CD + cb);
                t[r] += x.x * w0 + x.y * w1 + x.z * w2 + x.w * w3;
            }
        }
        float mean = 0.0f;
        for (int r = 0; r < 16; ++r) mean += t[r];
        mean *= (1.0f / 16.0f);
        float var = 0.0f;
        for (int r = 0; r < 16; ++r) { float dd = t[r] - mean; var += dd * dd; }
        var *= (1.0f / 16.0f);
        float inv = rsqrtf(var + 1e-5f);
        for (int r = 0; r < 16; ++r)
            h2[r * CD + d] = fmaxf(0.0f, (t[r] - mean) * inv * g2[d] + be2[d]);
    }
    __syncthreads();
    if (d < 288) {
        float t[16];
        #pragma unroll
        for (int r = 0; r < 16; ++r) t[r] = br3[d];
        for (int c4 = 0; c4 < 64; ++c4) {
            int cb = c4 * 4;
            float w0 = Wr3[cb * 288 + d], w1 = Wr3[(cb + 1) * 288 + d];
            float w2 = Wr3[(cb + 2) * 288 + d], w3 = Wr3[(cb + 3) * 288 + d];
            #pragma unroll
            for (int r = 0; r < 16; ++r) {
                float4 x = *(const float4*)(h2 + r * CD + cb);
                t[r] += x.x * w0 + x.y * w1 + x.z * w2 + x.w * w3;
            }
        }
        for (int r = 0; r < 16; ++r) spts[r * 288 + d] = t[r];
    }
}

// FPS: ONE WAVE per batch, zero barriers.
__global__ __launch_bounds__(64) void fps_kernel(const float* __restrict__ spts,
                                                 int* __restrict__ fidx,
                                                 float* __restrict__ lacc,
                                                 unsigned* __restrict__ mnbuf) {
    int b = blockIdx.x;
    int lane = threadIdx.x;
    const float* pts = spts + (size_t)b * 384 * 3;
    int* out = fidx + b * 128;
    if (lane == 0) out[0] = 0;
    if (b == 0 && lane == 0) lacc[0] = 0.0f;
    mnbuf[b * 128 + lane] = 0x7F800000u;
    mnbuf[b * 128 + 64 + lane] = 0x7F800000u;
    float px[6], py[6], pz[6], dd[6];
    #pragma unroll
    for (int i = 0; i < 6; ++i) {
        int m = i * 64 + lane;
        px[i] = pts[m * 3]; py[i] = pts[m * 3 + 1]; pz[i] = pts[m * 3 + 2];
        dd[i] = 1e10f;
    }
    float lx = pts[0], ly = pts[1], lz = pts[2];
    #pragma unroll 1
    for (int s = 1; s < 128; ++s) {
        #pragma unroll
        for (int i = 0; i < 6; ++i) {
            float dx = px[i] - lx, dy = py[i] - ly, dz = pz[i] - lz;
            dd[i] = fminf(dd[i], dx * dx + dy * dy + dz * dz);
        }
        float bv = dd[0]; int bi = lane;
        #pragma unroll
        for (int i = 1; i < 6; ++i)
            if (dd[i] > bv) { bv = dd[i]; bi = i * 64 + lane; }
        dpp_lexmax<0x111, 0xf>(bv, bi);
        dpp_lexmax<0x112, 0xf>(bv, bi);
        dpp_lexmax<0x114, 0xf>(bv, bi);
        dpp_lexmax<0x118, 0xf>(bv, bi);
        dpp_lexmax<0x142, 0xa>(bv, bi);
        dpp_lexmax<0x143, 0xc>(bv, bi);
        int fm = __builtin_amdgcn_readlane(bi, 63);
        if (lane == 0) out[s] = fm;
        int slot = fm >> 6, sl_lane = fm & 63;
        float sx = px[0], sy = py[0], sz = pz[0];
        #pragma unroll
        for (int i = 1; i < 6; ++i)
            if (slot == i) { sx = px[i]; sy = py[i]; sz = pz[i]; }
        lx = __int_as_float(__builtin_amdgcn_readlane(__float_as_int(sx), sl_lane));
        ly = __int_as_float(__builtin_amdgcn_readlane(__float_as_int(sy), sl_lane));
        lz = __int_as_float(__builtin_amdgcn_readlane(__float_as_int(sz), sl_lane));
    }
}

// chamfer direction 2: per input point n, min over the 128 sampled ds points.
__global__ __launch_bounds__(256) void chamfer_sum2_kernel(const float* __restrict__ spts,
                                                           const int* __restrict__ fidx,
                                                           const float* __restrict__ xyz,
                                                           float* __restrict__ lacc) {
    int b = blockIdx.x >> 4, chunk = blockIdx.x & 15;
    int t = threadIdx.x;
    __shared__ float ds[128 * 3];
    __shared__ float red[4];
    const float* pts = spts + (size_t)b * 384 * 3;
    if (t < 128) {
        int j = fidx[b * 128 + t];
        ds[t * 3] = pts[j * 3]; ds[t * 3 + 1] = pts[j * 3 + 1]; ds[t * 3 + 2] = pts[j * 3 + 2];
    }
    __syncthreads();
    int n = chunk * 256 + t;
    const float* xb = xyz + (size_t)b * NPTS * 3;
    float px = xb[n * 3], py = xb[n * 3 + 1], pz = xb[n * 3 + 2];
    float mn = 1e30f;
    #pragma unroll 4
    for (int jj = 0; jj < 128; ++jj) {
        float dx = ds[jj * 3] - px, dy = ds[jj * 3 + 1] - py, dz = ds[jj * 3 + 2] - pz;
        mn = fminf(mn, dx * dx + dy * dy + dz * dz);
    }
    float total = block_sum256(mn * (1.0f / 4096.0f), red);
    if (t == 0) atomicAdd(lacc, total);
}

// chamfer direction 1: per sampled ds point j, exact min via uint atomicMin.
__global__ __launch_bounds__(128) void chamfer_min1_kernel(const float* __restrict__ spts,
                                                           const int* __restrict__ fidx,
                                                           const float* __restrict__ xyz,
                                                           unsigned* __restrict__ mnbuf) {
    int b = blockIdx.x >> 4, chunk = blockIdx.x & 15;
    int t = threadIdx.x;   // 128
    __shared__ float tile[256 * 3];
    const float* xb = xyz + ((size_t)b * NPTS + chunk * 256) * 3;
    for (int i = t; i < 768; i += 128) tile[i] = xb[i];
    __syncthreads();
    int j = fidx[b * 128 + t];
    const float* pts = spts + (size_t)b * 384 * 3;
    float px = pts[j * 3], py = pts[j * 3 + 1], pz = pts[j * 3 + 2];
    float mn = 1e30f;
    #pragma unroll 4
    for (int i = 0; i < 256; ++i) {
        float dx = tile[i * 3] - px, dy = tile[i * 3 + 1] - py, dz = tile[i * 3 + 2] - pz;
        mn = fminf(mn, dx * dx + dy * dy + dz * dz);
    }
    atomicMin(&mnbuf[b * 128 + t], __float_as_uint(mn));
}

// final: sum the 512 per-ds-point mins (/128 per batch), add lacc, write loss
__global__ __launch_bounds__(512) void chamfer_final_kernel(const unsigned* __restrict__ mnbuf,
                                                            const float* __restrict__ lacc,
                                                            float* __restrict__ out) {
    int t = threadIdx.x;   // 512
    __shared__ float r[8];
    float v = __uint_as_float(mnbuf[t]) * (1.0f / 128.0f);
    #pragma unroll
    for (int o = 32; o; o >>= 1) v += __shfl_down(v, o);
    if ((t & 63) == 0) r[t >> 6] = v;
    __syncthreads();
    if (t == 0) {
        float tot = 0.0f;
        #pragma unroll
        for (int i = 0; i < 8; ++i) tot += r[i];
        out[0] = (lacc[0] + tot) * 0.25f;
    }
}

// ---------------- launch ----------------

extern "C" void kernel_launch(void* const* d_in, const int* in_sizes, int n_in,
                              void* d_out, int out_size, void* d_ws, size_t ws_size,
                              hipStream_t stream) {
    (void)in_sizes; (void)n_in; (void)out_size; (void)ws_size;
    const float* x    = (const float*)d_in[0];
    const float* W1   = (const float*)d_in[2];
    const float* b1   = (const float*)d_in[3];
    const float* W2   = (const float*)d_in[4];
    const float* b2   = (const float*)d_in[5];
    const float* mu   = (const float*)d_in[6];
    const float* sg   = (const float*)d_in[7];
    const float* g_in = (const float*)d_in[8];
    const float* b_in = (const float*)d_in[9];
    const float* g_sl = (const float*)d_in[10];
    const float* b_sl = (const float*)d_in[11];
    const float* g_ff = (const float*)d_in[12];
    const float* b_ff = (const float*)d_in[13];
    const float* Wq   = (const float*)d_in[14];
    const float* Wk   = (const float*)d_in[15];
    const float* Wv   = (const float*)d_in[16];
    const float* W_ih = (const float*)d_in[17];
    const float* W_hh = (const float*)d_in[18];
    const float* b_ih = (const float*)d_in[19];
    const float* b_hh = (const float*)d_in[20];
    const float* Wm1  = (const float*)d_in[21];
    const float* bm1  = (const float*)d_in[22];
    const float* Wm2  = (const float*)d_in[23];
    const float* bm2  = (const float*)d_in[24];
    const float* Wr1  = (const float*)d_in[25];
    const float* br1  = (const float*)d_in[26];
    const float* g1   = (const float*)d_in[27];
    const float* be1  = (const float*)d_in[28];
    const float* Wr2  = (const float*)d_in[29];
    const float* br2  = (const float*)d_in[30];
    const float* g2   = (const float*)d_in[31];
    const float* be2  = (const float*)d_in[32];
    const float* Wr3  = (const float*)d_in[33];
    const float* br3  = (const float*)d_in[34];

    float* ws    = (float*)d_ws;
    float* xyz   = ws;                               // 49152 f
    float* xyzw  = xyz + 49152;                      // 65536 f (float4 [B*N])
    int*   knn   = (int*)(xyzw + 65536);             // 524288 i
    _Float16* f1h = (_Float16*)(knn + 524288);       // 2097152 h = 1048576 f
    _Float16* W2t = (_Float16*)((float*)f1h + 1048576);  // -> 20480 f
    _Float16* WkvT = (_Float16*)((float*)W2t + 20480);   // -> 65536 f
    _Float16* inph = (_Float16*)((float*)WkvT + 65536);  // -> 2097152 f
    float* kkb   = (float*)inph + 2097152;           // 4194304 f
    float* vvb   = kkb + 4194304;                    // 4194304 f
    float* slots = vvb + 4194304;                    // 4096 f
    float* qb    = slots + 4096;                     // 4096 f
    float* asum  = qb + 4096;                        // 16 f
    float* updp  = asum + 16;                        // 65536 f
    float* gi    = updp + 65536;                     // 12288 f
    float* gh    = gi + 12288;                       // 12288 f
    float* spts  = gh + 12288;                       // 4608 f
    int*   fidx  = (int*)(spts + 4608);              // 512 i
    float* lacc  = (float*)(fidx + 512);             // 1 f
    unsigned* mnbuf = (unsigned*)(lacc + 1);         // 512 u

    float* out = (float*)d_out;

    prep_kernel<<<64, 256, 0, stream>>>(x, xyz, (float4*)xyzw);
    slots_init_kernel<<<8, 256, 0, stream>>>(mu, sg, slots, asum);
    knn_kernel<<<NBATCH * NPTS / 4, 256, 0, stream>>>((const float4*)xyzw, knn);
    conv1_kernel<<<NBATCH * NPTS, 128, 0, stream>>>(xyz, knn, W1, b1, f1h);
    w2t_kernel<<<256, 160, 0, stream>>>(W2, W2t);
    wkvt_kernel<<<512, 256, 0, stream>>>(Wk, Wv, WkvT);
    conv2_mfma_kernel<<<NBATCH * NPTS / 2, 256, 0, stream>>>(xyz, f1h, knn, W2t, b2, g_in, b_in, inph);
    kv_mfma_kernel<<<NBATCH * NPTS / 64 * 2, 256, 0, stream>>>(inph, WkvT, kkb, vvb);

    for (int it = 0; it < 3; ++it) {
        slotq_kernel<<<16, 256, 0, stream>>>(slots, g_sl, b_sl, Wq, qb);
        attn_updp_kernel<<<64, 256, 0, stream>>>(qb, kkb, vvb, asum, updp,
                                                 (it == 2) ? (out + 1) : (float*)nullptr);
        gru_gates_kernel<<<48, 256, 0, stream>>>(updp, asum, slots, W_ih, W_hh, b_ih, b_hh, gi, gh);
        gru_mlp_kernel<<<16, 256, 0, stream>>>(gi, gh, slots, g_ff, b_ff, Wm1, bm1, Wm2, bm2, asum);
    }

    recon_kernel<<<1, 320, 0, stream>>>(slots, Wr1, br1, g1, be1, Wr2, br2, g2, be2, Wr3, br3, spts);
    fps_kernel<<<4, 64, 0, stream>>>(spts, fidx, lacc, mnbuf);
    chamfer_sum2_kernel<<<64, 256, 0, stream>>>(spts, fidx, xyz, lacc);
    chamfer_min1_kernel<<<64, 128, 0, stream>>>(spts, fidx, xyz, mnbuf);
    chamfer_final_kernel<<<1, 512, 0, stream>>>(mnbuf, lacc, out);
}

// Round 12
// 714.956 us; speedup vs baseline: 1.0996x; 1.0372x over previous
//
#include <hip/hip_runtime.h>

#define NBATCH 4
#define NPTS   4096
#define KNNK   32
#define C1D    128
#define CD     256
#define KPAD   160   // conv2 K padded (131 -> 160, 5 mfma K-steps of 32)
#define ASTR   168   // conv2 LDS A row stride in halves
#define ASTR2  264   // kv LDS A row stride in halves (256 cols + 8 pad)

typedef _Float16 v8h __attribute__((ext_vector_type(8)));
typedef float    v4f __attribute__((ext_vector_type(4)));
typedef unsigned long long ull;

// ---------------- helpers ----------------

__device__ __forceinline__ float block_sum256(float v, float* red) {
    #pragma unroll
    for (int o = 32; o; o >>= 1) v += __shfl_down(v, o);
    __syncthreads();
    if ((threadIdx.x & 63) == 0) red[threadIdx.x >> 6] = v;
    __syncthreads();
    return red[0] + red[1] + red[2] + red[3];
}

__device__ __forceinline__ unsigned rotl32(unsigned x, unsigned r) {
    return (x << r) | (x >> (32u - r));
}

// XLA f32 erf_inv (Giles polynomial)
__device__ float erfinv_f(float x) {
    float w = -log1pf(-x * x);
    float p;
    if (w < 5.0f) {
        w -= 2.5f;
        p = 2.81022636e-08f;
        p = fmaf(p, w, 3.43273939e-07f);
        p = fmaf(p, w, -3.5233877e-06f);
        p = fmaf(p, w, -4.39150654e-06f);
        p = fmaf(p, w, 0.00021858087f);
        p = fmaf(p, w, -0.00125372503f);
        p = fmaf(p, w, -0.00417768164f);
        p = fmaf(p, w, 0.246640727f);
        p = fmaf(p, w, 1.50140941f);
    } else {
        w = sqrtf(w) - 3.0f;
        p = -0.000200214257f;
        p = fmaf(p, w, 0.000100950558f);
        p = fmaf(p, w, 0.00134934322f);
        p = fmaf(p, w, -0.00367342844f);
        p = fmaf(p, w, 0.00573950773f);
        p = fmaf(p, w, -0.0076224613f);
        p = fmaf(p, w, 0.00943887047f);
        p = fmaf(p, w, 1.00167406f);
        p = fmaf(p, w, 2.83297682f);
    }
    return p * x;
}

__device__ __forceinline__ float bits_to_normal(unsigned bits) {
    unsigned fb = (bits >> 9) | 0x3f800000u;
    float f = __uint_as_float(fb) - 1.0f;
    const float lo = -0.99999994f;           // nextafterf(-1,0)
    float u = fmaf(f, 2.0f, lo);
    u = fmaxf(u, lo);
    return 1.41421356237f * erfinv_f(u);
}

// order-preserving float->uint map
__device__ __forceinline__ unsigned fmap(float f) {
    unsigned b = __float_as_uint(f);
    return (b & 0x80000000u) ? ~b : (b | 0x80000000u);
}

// one DPP level of u64-key min
template <int CTRL, int RM>
__device__ __forceinline__ ull dpp_min_u64(ull k) {
    unsigned lo = (unsigned)k, hi = (unsigned)(k >> 32);
    unsigned tlo = (unsigned)__builtin_amdgcn_update_dpp((int)lo, (int)lo, CTRL, RM, 0xf, false);
    unsigned thi = (unsigned)__builtin_amdgcn_update_dpp((int)hi, (int)hi, CTRL, RM, 0xf, false);
    ull t = ((ull)thi << 32) | tlo;
    return t < k ? t : k;
}

// lexicographic max (value desc, index asc on ties) — matches jnp.argmax
template <int CTRL, int RM>
__device__ __forceinline__ void dpp_lexmax(float& v, int& ix) {
    int tv = __builtin_amdgcn_update_dpp(__float_as_int(v), __float_as_int(v), CTRL, RM, 0xf, false);
    int ti = __builtin_amdgcn_update_dpp(ix, ix, CTRL, RM, 0xf, false);
    float fv = __int_as_float(tv);
    bool take = (fv > v) || (fv == v && ti < ix);
    v  = take ? fv : v;
    ix = take ? ti : ix;
}

// ---------------- kernels ----------------

// x [B,3,N] -> xyz [B,N,3], xyzw (x,y,z,sq); also threefry slots + asum zero
__global__ void prep_kernel(const float* __restrict__ x, float* __restrict__ xyz,
                            float4* __restrict__ xyzw,
                            const float* __restrict__ mu, const float* __restrict__ sg,
                            float* __restrict__ slots, float* __restrict__ asum) {
    int gid = blockIdx.x * 256 + threadIdx.x;
    if (gid >= NBATCH * NPTS) return;
    int b = gid >> 12, n = gid & (NPTS - 1);
    float a0 = x[(b * 3 + 0) * NPTS + n];
    float a1 = x[(b * 3 + 1) * NPTS + n];
    float a2 = x[(b * 3 + 2) * NPTS + n];
    xyz[gid * 3 + 0] = a0; xyz[gid * 3 + 1] = a1; xyz[gid * 3 + 2] = a2;
    float sq = a0 * a0 + a1 * a1 + a2 * a2;
    xyzw[gid] = make_float4(a0, a1, a2, sq);
    if (gid < 16) asum[gid] = 0.0f;
    if (gid < 2048) {
        int j = gid;
        unsigned ks0 = 0u, ks1 = 42u, ks2 = 0u ^ 42u ^ 0x1BD11BDAu;
        unsigned x0 = (unsigned)j + ks0;
        unsigned x1 = (unsigned)(j + 2048) + ks1;
        #define RND(r) { x0 += x1; x1 = rotl32(x1, r); x1 ^= x0; }
        RND(13u) RND(15u) RND(26u) RND(6u);  x0 += ks1; x1 += ks2 + 1u;
        RND(17u) RND(29u) RND(16u) RND(24u); x0 += ks2; x1 += ks0 + 2u;
        RND(13u) RND(15u) RND(26u) RND(6u);  x0 += ks0; x1 += ks1 + 3u;
        RND(17u) RND(29u) RND(16u) RND(24u); x0 += ks1; x1 += ks2 + 4u;
        RND(13u) RND(15u) RND(26u) RND(6u);  x0 += ks2; x1 += ks0 + 5u;
        #undef RND
        int c0 = j & 255, c1 = (j + 2048) & 255;
        slots[j]        = mu[c0] + sg[c0] * bits_to_normal(x0);
        slots[j + 2048] = mu[c1] + sg[c1] * bits_to_normal(x1);
    }
}

// KNN: one wave per point, u64-key DPP argmin; matches lax.top_k exactly.
__global__ __launch_bounds__(256) void knn_kernel(const float4* __restrict__ xyzw,
                                                  int* __restrict__ knn_idx) {
    int wid = threadIdx.x >> 6, lane = threadIdx.x & 63;
    int pid = blockIdx.x * 4 + wid;
    int b = pid >> 12, n = pid & (NPTS - 1);
    const float4* xb = xyzw + (size_t)b * NPTS;
    float4 p = xb[n];
    unsigned d[64];
    #pragma unroll
    for (int i = 0; i < 64; ++i) {
        float4 c = xb[i * 64 + lane];
        float dot = p.x * c.x + p.y * c.y + p.z * c.z;
        d[i] = fmap(p.w + c.w - 2.0f * dot);
    }
    unsigned gv[8]; int gi[8];
    #pragma unroll
    for (int g = 0; g < 8; ++g) {
        unsigned mv = d[g * 8]; int mi = g * 8;
        #pragma unroll
        for (int j = 1; j < 8; ++j)
            if (d[g * 8 + j] < mv) { mv = d[g * 8 + j]; mi = g * 8 + j; }
        gv[g] = mv; gi[g] = mi * 64 + lane;
    }
    unsigned lv = gv[0]; int li = gi[0];
    #pragma unroll
    for (int g = 1; g < 8; ++g)
        if (gv[g] < lv) { lv = gv[g]; li = gi[g]; }

    int* out = knn_idx + (size_t)pid * KNNK;
    #pragma unroll 1
    for (int s = 0; s < KNNK; ++s) {
        ull k = ((ull)lv << 32) | (unsigned)li;
        k = dpp_min_u64<0x111, 0xf>(k);
        k = dpp_min_u64<0x112, 0xf>(k);
        k = dpp_min_u64<0x114, 0xf>(k);
        k = dpp_min_u64<0x118, 0xf>(k);
        k = dpp_min_u64<0x142, 0xa>(k);
        k = dpp_min_u64<0x143, 0xc>(k);
        int fm = __builtin_amdgcn_readlane((int)(unsigned)k, 63);
        if (lane == 0) out[s] = fm;
        int flane = fm & 63;
        int slot  = fm >> 6;
        if (lane == flane) {
            int g = slot >> 3;
            #pragma unroll
            for (int g2 = 0; g2 < 8; ++g2) {
                if (g2 == g) {
                    #pragma unroll
                    for (int j = 0; j < 8; ++j)
                        if (g2 * 8 + j == slot) d[g2 * 8 + j] = 0xFFFFFFFFu;
                    unsigned mv = d[g2 * 8]; int mi = g2 * 8;
                    #pragma unroll
                    for (int j = 1; j < 8; ++j)
                        if (d[g2 * 8 + j] < mv) { mv = d[g2 * 8 + j]; mi = g2 * 8 + j; }
                    gv[g2] = mv; gi[g2] = mi * 64 + lane;
                }
            }
            lv = gv[0]; li = gi[0];
            #pragma unroll
            for (int g2 = 1; g2 < 8; ++g2)
                if (gv[g2] < lv) { lv = gv[g2]; li = gi[g2]; }
        }
    }
}

// conv1 -> fp16 features; neighbor coords preloaded into lanes 0..31
__global__ __launch_bounds__(128) void conv1_kernel(const float* __restrict__ xyz,
                                                    const int* __restrict__ knn_idx,
                                                    const float* __restrict__ W1,
                                                    const float* __restrict__ b1,
                                                    _Float16* __restrict__ f1h) {
    int pid = blockIdx.x;
    int b = pid >> 12, n = pid & (NPTS - 1);
    int d = threadIdx.x, lane = threadIdx.x & 63;
    const float* xb = xyz + (size_t)b * NPTS * 3;
    float w0 = W1[d], wx = W1[C1D + d], wy = W1[2 * C1D + d], wz = W1[3 * C1D + d];
    float bb = b1[d];
    float px = xb[n * 3], py = xb[n * 3 + 1], pz = xb[n * 3 + 2];
    const int* idx = knn_idx + (size_t)pid * KNNK;
    float cx = 0.0f, cy = 0.0f, cz = 0.0f;
    if (lane < 32) {
        int j = idx[lane];
        cx = xb[j * 3]; cy = xb[j * 3 + 1]; cz = xb[j * 3 + 2];
    }
    float m = -1e30f;
    #pragma unroll
    for (int k = 0; k < KNNK; ++k) {
        float jx = __shfl(cx, k), jy = __shfl(cy, k), jz = __shfl(cz, k);
        float v = w0 + bb + (jx - px) * wx + (jy - py) * wy + (jz - pz) * wz;
        m = fmaxf(m, v);
    }
    f1h[(size_t)pid * C1D + d] = (_Float16)fmaxf(m, 0.0f);
}

// merged weight transposes: blocks 0..255 -> W2t, 256..767 -> WkvT
__global__ __launch_bounds__(256) void wtrans_kernel(const float* __restrict__ W2,
                                                     const float* __restrict__ Wk,
                                                     const float* __restrict__ Wv,
                                                     _Float16* __restrict__ W2t,
                                                     _Float16* __restrict__ WkvT) {
    int nb = blockIdx.x, t = threadIdx.x;
    if (nb < 256) {
        if (t < KPAD) W2t[nb * KPAD + t] = (t < 131) ? (_Float16)W2[t * CD + nb] : (_Float16)0.0f;
    } else {
        int n = nb - 256;
        float v = (n < 256) ? Wk[t * CD + n] : Wv[t * CD + (n - 256)];
        WkvT[n * CD + t] = (_Float16)v;
    }
}

// conv2 via MFMA f16 + fused bias/relu/max-over-k/LayerNorm -> inph fp16
__global__ __launch_bounds__(256) void conv2_mfma_kernel(const float* __restrict__ xyz,
                                                         const _Float16* __restrict__ f1h,
                                                         const int* __restrict__ knn_idx,
                                                         const _Float16* __restrict__ W2t,
                                                         const float* __restrict__ b2,
                                                         const float* __restrict__ g_in,
                                                         const float* __restrict__ b_in,
                                                         _Float16* __restrict__ inph) {
    __shared__ _Float16 A[64 * ASTR];
    __shared__ float colmax[2 * CD];
    __shared__ float red[4];
    int pid2 = blockIdx.x;
    int gp0 = pid2 * 2;
    int b = gp0 >> 12, n0 = gp0 & (NPTS - 1);
    int tid = threadIdx.x;
    const int* idx = knn_idx + (size_t)pid2 * 64;   // [2][32]
    const float* xb = xyz + (size_t)b * NPTS * 3;

    {
        int r = tid & 63, seg = tid >> 6;
        int j = idx[r];
        const uint4* s4 = (const uint4*)(f1h + ((size_t)b * NPTS + j) * C1D);
        uint4* d4 = (uint4*)&A[r * ASTR];
        #pragma unroll
        for (int i = 0; i < 4; ++i) d4[seg * 4 + i] = s4[seg * 4 + i];
        unsigned* z = (unsigned*)&A[r * ASTR + 128];
        for (int i = seg; i < 20; i += 4) z[i] = 0u;
        int np_ = (r < 32) ? n0 : (n0 + 1);
        if (seg == 0) {
            A[r * ASTR + 128] = (_Float16)(xb[j * 3 + 0] - xb[np_ * 3 + 0]);
            A[r * ASTR + 129] = (_Float16)(xb[j * 3 + 1] - xb[np_ * 3 + 1]);
        } else if (seg == 1) {
            A[r * ASTR + 130] = (_Float16)(xb[j * 3 + 2] - xb[np_ * 3 + 2]);
        }
    }
    __syncthreads();

    int w = tid >> 6, lane = tid & 63, quad = lane >> 4, lr = lane & 15;
    v4f acc[4][4];
    #pragma unroll
    for (int rt = 0; rt < 4; ++rt)
        #pragma unroll
        for (int ct = 0; ct < 4; ++ct)
            acc[rt][ct] = (v4f){0.0f, 0.0f, 0.0f, 0.0f};

    #pragma unroll
    for (int kk = 0; kk < KPAD; kk += 32) {
        v8h af[4], bf[4];
        #pragma unroll
        for (int rt = 0; rt < 4; ++rt)
            af[rt] = *(const v8h*)&A[(rt * 16 + lr) * ASTR + kk + quad * 8];
        #pragma unroll
        for (int ct = 0; ct < 4; ++ct) {
            int ncol = w * 64 + ct * 16 + lr;
            bf[ct] = *(const v8h*)(W2t + (size_t)ncol * KPAD + kk + quad * 8);
        }
        #pragma unroll
        for (int rt = 0; rt < 4; ++rt)
            #pragma unroll
            for (int ct = 0; ct < 4; ++ct)
                acc[rt][ct] = __builtin_amdgcn_mfma_f32_16x16x32_f16(af[rt], bf[ct], acc[rt][ct], 0, 0, 0);
    }

    #pragma unroll
    for (int ct = 0; ct < 4; ++ct) {
        float tm[4];
        #pragma unroll
        for (int rt = 0; rt < 4; ++rt) {
            v4f a = acc[rt][ct];
            float v = fmaxf(fmaxf(a[0], a[1]), fmaxf(a[2], a[3]));
            v = fmaxf(v, __shfl_xor(v, 16));
            v = fmaxf(v, __shfl_xor(v, 32));
            tm[rt] = v;
        }
        float p0 = fmaxf(tm[0], tm[1]);
        float p1 = fmaxf(tm[2], tm[3]);
        if (quad == 0) {
            colmax[0 * CD + w * 64 + ct * 16 + lr] = p0;
            colmax[1 * CD + w * 64 + ct * 16 + lr] = p1;
        }
    }
    __syncthreads();

    int d = tid;
    #pragma unroll
    for (int p = 0; p < 2; ++p) {
        float v = fmaxf(colmax[p * CD + d] + b2[d], 0.0f);
        float s = block_sum256(v, red);
        float mean = s * (1.0f / 256.0f);
        float s2 = block_sum256(v * v, red);
        float var = s2 * (1.0f / 256.0f) - mean * mean;
        float iv = (v - mean) * rsqrtf(var + 1e-5f) * g_in[d] + b_in[d];
        inph[(size_t)(gp0 + p) * CD + d] = (_Float16)iv;
    }
}

// kv via MFMA fp16: block = 64 points x 256 cols; half 0 -> kk, half 1 -> vv.
__global__ __launch_bounds__(256) void kv_mfma_kernel(const _Float16* __restrict__ inph,
                                                      const _Float16* __restrict__ WkvT,
                                                      float* __restrict__ kk,
                                                      float* __restrict__ vv) {
    __shared__ _Float16 A[64 * ASTR2];
    int rb = blockIdx.x >> 1, half = blockIdx.x & 1;
    int row0 = rb * 64;
    int tid = threadIdx.x;
    {
        const uint4* src4 = (const uint4*)(inph + (size_t)row0 * CD);
        #pragma unroll
        for (int i = 0; i < 8; ++i) {
            int idx = i * 256 + tid;
            int row = idx >> 5, c8 = idx & 31;
            *(uint4*)&A[row * ASTR2 + c8 * 8] = src4[idx];
        }
    }
    __syncthreads();
    int w = tid >> 6, lane = tid & 63, quad = lane >> 4, lr = lane & 15;
    v4f acc[4][4];
    #pragma unroll
    for (int rt = 0; rt < 4; ++rt)
        #pragma unroll
        for (int ct = 0; ct < 4; ++ct)
            acc[rt][ct] = (v4f){0.0f, 0.0f, 0.0f, 0.0f};
    #pragma unroll
    for (int ks = 0; ks < CD; ks += 32) {
        v8h af[4], bf[4];
        #pragma unroll
        for (int rt = 0; rt < 4; ++rt)
            af[rt] = *(const v8h*)&A[(rt * 16 + lr) * ASTR2 + ks + quad * 8];
        #pragma unroll
        for (int ct = 0; ct < 4; ++ct) {
            int ncol = half * 256 + w * 64 + ct * 16 + lr;
            bf[ct] = *(const v8h*)(WkvT + (size_t)ncol * CD + ks + quad * 8);
        }
        #pragma unroll
        for (int rt = 0; rt < 4; ++rt)
            #pragma unroll
            for (int ct = 0; ct < 4; ++ct)
                acc[rt][ct] = __builtin_amdgcn_mfma_f32_16x16x32_f16(af[rt], bf[ct], acc[rt][ct], 0, 0, 0);
    }
    float* dst = half ? vv : kk;
    #pragma unroll
    for (int rt = 0; rt < 4; ++rt)
        #pragma unroll
        for (int ct = 0; ct < 4; ++ct) {
            int col = w * 64 + ct * 16 + lr;
            #pragma unroll
            for (int r = 0; r < 4; ++r) {
                int row = rt * 16 + quad * 4 + r;
                dst[(size_t)(row0 + row) * CD + col] = acc[rt][ct][r];
            }
        }
}

// q = LN(slots) @ Wq, one block per row (b,k) — identical arithmetic to R9
__global__ __launch_bounds__(256) void slotq_kernel(const float* __restrict__ slots,
                                                    const float* __restrict__ g_sl,
                                                    const float* __restrict__ b_sl,
                                                    const float* __restrict__ Wq,
                                                    float* __restrict__ q) {
    int row = blockIdx.x;
    int d = threadIdx.x;
    __shared__ float sl[CD];
    __shared__ float red[4];
    float v = slots[row * CD + d];
    float s = block_sum256(v, red);
    float mean = s * (1.0f / 256.0f);
    float s2 = block_sum256(v * v, red);
    float var = s2 * (1.0f / 256.0f) - mean * mean;
    float ln = (v - mean) * rsqrtf(var + 1e-5f) * g_sl[d] + b_sl[d];
    sl[d] = ln;
    __syncthreads();
    float acc = 0.0f;
    const float4* sp = (const float4*)sl;
    for (int c4 = 0; c4 < 64; ++c4) {
        float4 x = sp[c4];
        int cb = c4 * 4;
        acc += x.x * Wq[cb * CD + d] + x.y * Wq[(cb + 1) * CD + d]
             + x.z * Wq[(cb + 2) * CD + d] + x.w * Wq[(cb + 3) * CD + d];
    }
    q[row * CD + d] = acc;
}

// FUSED attn+updp, 256 blocks: block = (batch, 64-pt chunk); thread = (point,slot)
// for the logit dot (identical expression per (point,slot) -> bit-identical
// logits); softmax by threads t<64; updp partials over 64 chunks/row.
__global__ __launch_bounds__(256) void attn_updp_kernel(const float* __restrict__ q,
                                                        const float* __restrict__ kk,
                                                        const float* __restrict__ vv,
                                                        float* __restrict__ asum,
                                                        float* __restrict__ updp,
                                                        float* __restrict__ out_attn) {
    int b = blockIdx.x >> 6;
    int chunk = blockIdx.x & 63;
    int t = threadIdx.x;
    __shared__ float qs[4 * CD];
    __shared__ float logit[64 * 4];
    __shared__ float aw[64 * 4];
    for (int i = t; i < 4 * CD; i += 256) qs[i] = q[b * 4 * CD + i];
    __syncthreads();

    int p = t & 63, r = t >> 6;
    int n = chunk * 64 + p;
    {
        const float4* kp = (const float4*)(kk + ((size_t)b * NPTS + n) * CD);
        const float4* qr = (const float4*)(qs + r * CD);
        float a = 0.0f;
        for (int c4 = 0; c4 < 64; ++c4) {
            float4 kv = kp[c4];
            float4 x = qr[c4];
            a += kv.x * x.x + kv.y * x.y + kv.z * x.z + kv.w * x.w;
        }
        logit[p * 4 + r] = 0.0625f * a;   // 256^-0.5
    }
    __syncthreads();
    if (t < 64) {
        float l0 = logit[t * 4 + 0], l1 = logit[t * 4 + 1];
        float l2 = logit[t * 4 + 2], l3 = logit[t * 4 + 3];
        float mx = fmaxf(fmaxf(l0, l1), fmaxf(l2, l3));
        float e0 = expf(l0 - mx), e1 = expf(l1 - mx), e2 = expf(l2 - mx), e3 = expf(l3 - mx);
        float inv = 1.0f / (e0 + e1 + e2 + e3);
        e0 *= inv; e1 *= inv; e2 *= inv; e3 *= inv;
        aw[t * 4 + 0] = e0; aw[t * 4 + 1] = e1; aw[t * 4 + 2] = e2; aw[t * 4 + 3] = e3;
        if (out_attn) {
            float* o = out_attn + ((size_t)b * NPTS + chunk * 64 + t) * 4;
            o[0] = e0; o[1] = e1; o[2] = e2; o[3] = e3;
        }
        // asum: single-wave reduce over the 64 points
        float s0 = e0, s1 = e1, s2 = e2, s3 = e3;
        #pragma unroll
        for (int o = 32; o; o >>= 1) {
            s0 += __shfl_down(s0, o); s1 += __shfl_down(s1, o);
            s2 += __shfl_down(s2, o); s3 += __shfl_down(s3, o);
        }
        if (t == 0) {
            atomicAdd(&asum[b * 4 + 0], s0);
            atomicAdd(&asum[b * 4 + 1], s1);
            atomicAdd(&asum[b * 4 + 2], s2);
            atomicAdd(&asum[b * 4 + 3], s3);
        }
    }
    __syncthreads();

    float ac0 = 0.0f, ac1 = 0.0f, ac2 = 0.0f, ac3 = 0.0f;
    const float* vb = vv + ((size_t)b * NPTS + chunk * 64) * CD;
    for (int nn2 = 0; nn2 < 64; ++nn2) {
        float v = vb[(size_t)nn2 * CD + t];
        float4 w4 = *(const float4*)&aw[nn2 * 4];
        ac0 += w4.x * v; ac1 += w4.y * v; ac2 += w4.z * v; ac3 += w4.w * v;
    }
    updp[((size_t)(b * 4 + 0) * 64 + chunk) * CD + t] = ac0;
    updp[((size_t)(b * 4 + 1) * 64 + chunk) * CD + t] = ac1;
    updp[((size_t)(b * 4 + 2) * 64 + chunk) * CD + t] = ac2;
    updp[((size_t)(b * 4 + 3) * 64 + chunk) * CD + t] = ac3;
}

// GRU gates, 96 blocks: (row, gate, c-half). Partial sums combined in gru_mlp.
__global__ __launch_bounds__(256) void gru_gates_kernel(const float* __restrict__ updp,
                                                        const float* __restrict__ asum,
                                                        const float* __restrict__ slots,
                                                        const float* __restrict__ W_ih,
                                                        const float* __restrict__ W_hh,
                                                        const float* __restrict__ b_ih,
                                                        const float* __restrict__ b_hh,
                                                        float* __restrict__ gi,
                                                        float* __restrict__ gh) {
    int idx = blockIdx.x;
    int row = idx / 6, rem = idx % 6;
    int gate = rem >> 1, half = rem & 1;
    int d = threadIdx.x;
    __shared__ float su[CD], sp[CD];
    float f = 1.0f / (asum[row] + 1e-8f);
    float u = 0.0f;
    for (int p = 0; p < 64; ++p) u += updp[((size_t)row * 64 + p) * CD + d];
    u *= f;
    su[d] = u; sp[d] = slots[row * CD + d];
    __syncthreads();
    float acc_i = half ? 0.0f : b_ih[gate * CD + d];
    float acc_h = half ? 0.0f : b_hh[gate * CD + d];
    const float* wi = W_ih + gate * CD + d;
    const float* wh = W_hh + gate * CD + d;
    int c0 = half * 128;
    for (int c = c0; c < c0 + 128; ++c) {
        acc_i += su[c] * wi[c * 3 * CD];
        acc_h += sp[c] * wh[c * 3 * CD];
    }
    gi[((size_t)(row * 3 + gate) * 2 + half) * CD + d] = acc_i;
    gh[((size_t)(row * 3 + gate) * 2 + half) * CD + d] = acc_h;
}

// GRU update + LN_ff + MLP residual; combines gate halves; zeroes asum
__global__ __launch_bounds__(256) void gru_mlp_kernel(const float* __restrict__ gi,
                                                      const float* __restrict__ gh,
                                                      float* __restrict__ slots,
                                                      const float* __restrict__ g_ff,
                                                      const float* __restrict__ b_ff,
                                                      const float* __restrict__ Wm1,
                                                      const float* __restrict__ bm1,
                                                      const float* __restrict__ Wm2,
                                                      const float* __restrict__ bm2,
                                                      float* __restrict__ asum) {
    int row = blockIdx.x;
    int d = threadIdx.x;
    __shared__ float sh[CD];
    __shared__ float red[4];
    float prev = slots[row * CD + d];
    float gir = gi[((size_t)(row * 3 + 0) * 2 + 0) * CD + d] + gi[((size_t)(row * 3 + 0) * 2 + 1) * CD + d];
    float giz = gi[((size_t)(row * 3 + 1) * 2 + 0) * CD + d] + gi[((size_t)(row * 3 + 1) * 2 + 1) * CD + d];
    float gin = gi[((size_t)(row * 3 + 2) * 2 + 0) * CD + d] + gi[((size_t)(row * 3 + 2) * 2 + 1) * CD + d];
    float ghr = gh[((size_t)(row * 3 + 0) * 2 + 0) * CD + d] + gh[((size_t)(row * 3 + 0) * 2 + 1) * CD + d];
    float ghz = gh[((size_t)(row * 3 + 1) * 2 + 0) * CD + d] + gh[((size_t)(row * 3 + 1) * 2 + 1) * CD + d];
    float ghn = gh[((size_t)(row * 3 + 2) * 2 + 0) * CD + d] + gh[((size_t)(row * 3 + 2) * 2 + 1) * CD + d];
    if (d == 0) asum[row] = 0.0f;
    float r = 1.0f / (1.0f + expf(-(gir + ghr)));
    float z = 1.0f / (1.0f + expf(-(giz + ghz)));
    float nn = tanhf(gin + r * ghn);
    float sNew = (1.0f - z) * nn + z * prev;
    float s = block_sum256(sNew, red);
    float mean = s * (1.0f / 256.0f);
    float s2 = block_sum256(sNew * sNew, red);
    float var = s2 * (1.0f / 256.0f) - mean * mean;
    float h = (sNew - mean) * rsqrtf(var + 1e-5f) * g_ff[d] + b_ff[d];
    __syncthreads();
    sh[d] = h;
    __syncthreads();
    float y = bm1[d];
    {
        const float4* hp = (const float4*)sh;
        for (int c4 = 0; c4 < 64; ++c4) {
            float4 x = hp[c4];
            int cb = c4 * 4;
            y += x.x * Wm1[cb * CD + d] + x.y * Wm1[(cb + 1) * CD + d]
               + x.z * Wm1[(cb + 2) * CD + d] + x.w * Wm1[(cb + 3) * CD + d];
        }
    }
    y = fmaxf(y, 0.0f);
    __syncthreads();
    sh[d] = y;
    __syncthreads();
    float o = bm2[d];
    {
        const float4* hp = (const float4*)sh;
        for (int c4 = 0; c4 < 64; ++c4) {
            float4 x = hp[c4];
            int cb = c4 * 4;
            o += x.x * Wm2[cb * CD + d] + x.y * Wm2[(cb + 1) * CD + d]
               + x.z * Wm2[(cb + 2) * CD + d] + x.w * Wm2[(cb + 3) * CD + d];
        }
    }
    slots[row * CD + d] = sNew + o;
}

// recon head, loop-interchanged
__global__ __launch_bounds__(320) void recon_kernel(const float* __restrict__ slots,
                                                    const float* __restrict__ Wr1, const float* __restrict__ br1,
                                                    const float* __restrict__ g1, const float* __restrict__ be1,
                                                    const float* __restrict__ Wr2, const float* __restrict__ br2,
                                                    const float* __restrict__ g2, const float* __restrict__ be2,
                                                    const float* __restrict__ Wr3, const float* __restrict__ br3,
                                                    float* __restrict__ spts) {
    __shared__ float sl[16 * CD];
    __shared__ float h1[16 * CD];
    __shared__ float h2[16 * CD];
    int d = threadIdx.x;
    if (d < CD) for (int r = 0; r < 16; ++r) sl[r * CD + d] = slots[r * CD + d];
    __syncthreads();
    if (d < CD) {
        float t[16];
        #pragma unroll
        for (int r = 0; r < 16; ++r) t[r] = br1[d];
        for (int c4 = 0; c4 < 64; ++c4) {
            int cb = c4 * 4;
            float w0 = Wr1[cb * CD + d], w1 = Wr1[(cb + 1) * CD + d];
            float w2 = Wr1[(cb + 2) * CD + d], w3 = Wr1[(cb + 3) * CD + d];
            #pragma unroll
            for (int r = 0; r < 16; ++r) {
                float4 x = *(const float4*)(sl + r * CD + cb);
                t[r] += x.x * w0 + x.y * w1 + x.z * w2 + x.w * w3;
            }
        }
        float mean = 0.0f;
        for (int r = 0; r < 16; ++r) mean += t[r];
        mean *= (1.0f / 16.0f);
        float var = 0.0f;
        for (int r = 0; r < 16; ++r) { float dd = t[r] - mean; var += dd * dd; }
        var *= (1.0f / 16.0f);
        float inv = rsqrtf(var + 1e-5f);
        for (int r = 0; r < 16; ++r)
            h1[r * CD + d] = fmaxf(0.0f, (t[r] - mean) * inv * g1[d] + be1[d]);
    }
    __syncthreads();
    if (d < CD) {
        float t[16];
        #pragma unroll
        for (int r = 0; r < 16; ++r) t[r] = br2[d];
        for (int c4 = 0; c4 < 64; ++c4) {
            int cb = c4 * 4;
            float w0 = Wr2[cb * CD + d], w1 = Wr2[(cb + 1) * CD + d];
            float w2 = Wr2[(cb + 2) * CD + d], w3 = Wr2[(cb + 3) * CD + d];
            #pragma unroll
            for (int r = 0; r < 16; ++r) {
                float4 x = *(const float4*)(h1 + r * CD + cb);
                t[r] += x.x * w0 + x.y * w1 + x.z * w2 + x.w * w3;
            }
        }
        float mean = 0.0f;
        for (int r = 0; r < 16; ++r) mean += t[r];
        mean *= (1.0f / 16.0f);
        float var = 0.0f;
        for (int r = 0; r < 16; ++r) { float dd = t[r] - mean; var += dd * dd; }
        var *= (1.0f / 16.0f);
        float inv = rsqrtf(var + 1e-5f);
        for (int r = 0; r < 16; ++r)
            h2[r * CD + d] = fmaxf(0.0f, (t[r] - mean) * inv * g2[d] + be2[d]);
    }
    __syncthreads();
    if (d < 288) {
        float t[16];
        #pragma unroll
        for (int r = 0; r < 16; ++r) t[r] = br3[d];
        for (int c4 = 0; c4 < 64; ++c4) {
            int cb = c4 * 4;
            float w0 = Wr3[cb * 288 + d], w1 = Wr3[(cb + 1) * 288 + d];
            float w2 = Wr3[(cb + 2) * 288 + d], w3 = Wr3[(cb + 3) * 288 + d];
            #pragma unroll
            for (int r = 0; r < 16; ++r) {
                float4 x = *(const float4*)(h2 + r * CD + cb);
                t[r] += x.x * w0 + x.y * w1 + x.z * w2 + x.w * w3;
            }
        }
        for (int r = 0; r < 16; ++r) spts[r * 288 + d] = t[r];
    }
}

// FPS: ONE WAVE per batch, zero barriers.
__global__ __launch_bounds__(64) void fps_kernel(const float* __restrict__ spts,
                                                 int* __restrict__ fidx,
                                                 float* __restrict__ lacc,
                                                 unsigned* __restrict__ mnbuf) {
    int b = blockIdx.x;
    int lane = threadIdx.x;
    const float* pts = spts + (size_t)b * 384 * 3;
    int* out = fidx + b * 128;
    if (lane == 0) out[0] = 0;
    if (b == 0 && lane == 0) lacc[0] = 0.0f;
    mnbuf[b * 128 + lane] = 0x7F800000u;
    mnbuf[b * 128 + 64 + lane] = 0x7F800000u;
    float px[6], py[6], pz[6], dd[6];
    #pragma unroll
    for (int i = 0; i < 6; ++i) {
        int m = i * 64 + lane;
        px[i] = pts[m * 3]; py[i] = pts[m * 3 + 1]; pz[i] = pts[m * 3 + 2];
        dd[i] = 1e10f;
    }
    float lx = pts[0], ly = pts[1], lz = pts[2];
    #pragma unroll 1
    for (int s = 1; s < 128; ++s) {
        #pragma unroll
        for (int i = 0; i < 6; ++i) {
            float dx = px[i] - lx, dy = py[i] - ly, dz = pz[i] - lz;
            dd[i] = fminf(dd[i], dx * dx + dy * dy + dz * dz);
        }
        float bv = dd[0]; int bi = lane;
        #pragma unroll
        for (int i = 1; i < 6; ++i)
            if (dd[i] > bv) { bv = dd[i]; bi = i * 64 + lane; }
        dpp_lexmax<0x111, 0xf>(bv, bi);
        dpp_lexmax<0x112, 0xf>(bv, bi);
        dpp_lexmax<0x114, 0xf>(bv, bi);
        dpp_lexmax<0x118, 0xf>(bv, bi);
        dpp_lexmax<0x142, 0xa>(bv, bi);
        dpp_lexmax<0x143, 0xc>(bv, bi);
        int fm = __builtin_amdgcn_readlane(bi, 63);
        if (lane == 0) out[s] = fm;
        int slot = fm >> 6, sl_lane = fm & 63;
        float sx = px[0], sy = py[0], sz = pz[0];
        #pragma unroll
        for (int i = 1; i < 6; ++i)
            if (slot == i) { sx = px[i]; sy = py[i]; sz = pz[i]; }
        lx = __int_as_float(__builtin_amdgcn_readlane(__float_as_int(sx), sl_lane));
        ly = __int_as_float(__builtin_amdgcn_readlane(__float_as_int(sy), sl_lane));
        lz = __int_as_float(__builtin_amdgcn_readlane(__float_as_int(sz), sl_lane));
    }
}

// merged chamfer: blocks 0..63 = sum2 direction, 64..127 = min1 direction
__global__ __launch_bounds__(256) void chamfer_kernel(const float* __restrict__ spts,
                                                      const int* __restrict__ fidx,
                                                      const float* __restrict__ xyz,
                                                      float* __restrict__ lacc,
                                                      unsigned* __restrict__ mnbuf) {
    int t = threadIdx.x;
    if (blockIdx.x < 64) {
        int b = blockIdx.x >> 4, chunk = blockIdx.x & 15;
        __shared__ float ds[128 * 3];
        __shared__ float red[4];
        const float* pts = spts + (size_t)b * 384 * 3;
        if (t < 128) {
            int j = fidx[b * 128 + t];
            ds[t * 3] = pts[j * 3]; ds[t * 3 + 1] = pts[j * 3 + 1]; ds[t * 3 + 2] = pts[j * 3 + 2];
        }
        __syncthreads();
        int n = chunk * 256 + t;
        const float* xb = xyz + (size_t)b * NPTS * 3;
        float px = xb[n * 3], py = xb[n * 3 + 1], pz = xb[n * 3 + 2];
        float mn = 1e30f;
        #pragma unroll 4
        for (int jj = 0; jj < 128; ++jj) {
            float dx = ds[jj * 3] - px, dy = ds[jj * 3 + 1] - py, dz = ds[jj * 3 + 2] - pz;
            mn = fminf(mn, dx * dx + dy * dy + dz * dz);
        }
        float total = block_sum256(mn * (1.0f / 4096.0f), red);
        if (t == 0) atomicAdd(lacc, total);
    } else {
        int bid = blockIdx.x - 64;
        int b = bid >> 4, chunk = bid & 15;
        __shared__ float tile[256 * 3];
        const float* xb = xyz + ((size_t)b * NPTS + chunk * 256) * 3;
        for (int i = t; i < 768; i += 256) tile[i] = xb[i];
        __syncthreads();
        if (t < 128) {
            int j = fidx[b * 128 + t];
            const float* pts = spts + (size_t)b * 384 * 3;
            float px = pts[j * 3], py = pts[j * 3 + 1], pz = pts[j * 3 + 2];
            float mn = 1e30f;
            #pragma unroll 4
            for (int i = 0; i < 256; ++i) {
                float dx = tile[i * 3] - px, dy = tile[i * 3 + 1] - py, dz = tile[i * 3 + 2] - pz;
                mn = fminf(mn, dx * dx + dy * dy + dz * dz);
            }
            atomicMin(&mnbuf[b * 128 + t], __float_as_uint(mn));
        }
    }
}

// final: sum the 512 per-ds-point mins (/128 per batch), add lacc, write loss
__global__ __launch_bounds__(512) void chamfer_final_kernel(const unsigned* __restrict__ mnbuf,
                                                            const float* __restrict__ lacc,
                                                            float* __restrict__ out) {
    int t = threadIdx.x;   // 512
    __shared__ float r[8];
    float v = __uint_as_float(mnbuf[t]) * (1.0f / 128.0f);
    #pragma unroll
    for (int o = 32; o; o >>= 1) v += __shfl_down(v, o);
    if ((t & 63) == 0) r[t >> 6] = v;
    __syncthreads();
    if (t == 0) {
        float tot = 0.0f;
        #pragma unroll
        for (int i = 0; i < 8; ++i) tot += r[i];
        out[0] = (lacc[0] + tot) * 0.25f;
    }
}

// ---------------- launch ----------------

extern "C" void kernel_launch(void* const* d_in, const int* in_sizes, int n_in,
                              void* d_out, int out_size, void* d_ws, size_t ws_size,
                              hipStream_t stream) {
    (void)in_sizes; (void)n_in; (void)out_size; (void)ws_size;
    const float* x    = (const float*)d_in[0];
    const float* W1   = (const float*)d_in[2];
    const float* b1   = (const float*)d_in[3];
    const float* W2   = (const float*)d_in[4];
    const float* b2   = (const float*)d_in[5];
    const float* mu   = (const float*)d_in[6];
    const float* sg   = (const float*)d_in[7];
    const float* g_in = (const float*)d_in[8];
    const float* b_in = (const float*)d_in[9];
    const float* g_sl = (const float*)d_in[10];
    const float* b_sl = (const float*)d_in[11];
    const float* g_ff = (const float*)d_in[12];
    const float* b_ff = (const float*)d_in[13];
    const float* Wq   = (const float*)d_in[14];
    const float* Wk   = (const float*)d_in[15];
    const float* Wv   = (const float*)d_in[16];
    const float* W_ih = (const float*)d_in[17];
    const float* W_hh = (const float*)d_in[18];
    const float* b_ih = (const float*)d_in[19];
    const float* b_hh = (const float*)d_in[20];
    const float* Wm1  = (const float*)d_in[21];
    const float* bm1  = (const float*)d_in[22];
    const float* Wm2  = (const float*)d_in[23];
    const float* bm2  = (const float*)d_in[24];
    const float* Wr1  = (const float*)d_in[25];
    const float* br1  = (const float*)d_in[26];
    const float* g1   = (const float*)d_in[27];
    const float* be1  = (const float*)d_in[28];
    const float* Wr2  = (const float*)d_in[29];
    const float* br2  = (const float*)d_in[30];
    const float* g2   = (const float*)d_in[31];
    const float* be2  = (const float*)d_in[32];
    const float* Wr3  = (const float*)d_in[33];
    const float* br3  = (const float*)d_in[34];

    float* ws    = (float*)d_ws;
    float* xyz   = ws;                               // 49152 f
    float* xyzw  = xyz + 49152;                      // 65536 f
    int*   knn   = (int*)(xyzw + 65536);             // 524288 i
    _Float16* f1h = (_Float16*)(knn + 524288);       // -> 1048576 f
    _Float16* W2t = (_Float16*)((float*)f1h + 1048576);  // -> 20480 f
    _Float16* WkvT = (_Float16*)((float*)W2t + 20480);   // -> 65536 f
    _Float16* inph = (_Float16*)((float*)WkvT + 65536);  // -> 2097152 f
    float* kkb   = (float*)inph + 2097152;           // 4194304 f
    float* vvb   = kkb + 4194304;                    // 4194304 f
    float* slots = vvb + 4194304;                    // 4096 f
    float* qb    = slots + 4096;                     // 4096 f
    float* asum  = qb + 4096;                        // 16 f
    float* updp  = asum + 16;                        // 262144 f
    float* gi    = updp + 262144;                    // 24576 f
    float* gh    = gi + 24576;                       // 24576 f
    float* spts  = gh + 24576;                       // 4608 f
    int*   fidx  = (int*)(spts + 4608);              // 512 i
    float* lacc  = (float*)(fidx + 512);             // 1 f
    unsigned* mnbuf = (unsigned*)(lacc + 1);         // 512 u

    float* out = (float*)d_out;

    prep_kernel<<<64, 256, 0, stream>>>(x, xyz, (float4*)xyzw, mu, sg, slots, asum);
    knn_kernel<<<NBATCH * NPTS / 4, 256, 0, stream>>>((const float4*)xyzw, knn);
    conv1_kernel<<<NBATCH * NPTS, 128, 0, stream>>>(xyz, knn, W1, b1, f1h);
    wtrans_kernel<<<768, 256, 0, stream>>>(W2, Wk, Wv, W2t, WkvT);
    conv2_mfma_kernel<<<NBATCH * NPTS / 2, 256, 0, stream>>>(xyz, f1h, knn, W2t, b2, g_in, b_in, inph);
    kv_mfma_kernel<<<NBATCH * NPTS / 64 * 2, 256, 0, stream>>>(inph, WkvT, kkb, vvb);

    for (int it = 0; it < 3; ++it) {
        slotq_kernel<<<16, 256, 0, stream>>>(slots, g_sl, b_sl, Wq, qb);
        attn_updp_kernel<<<256, 256, 0, stream>>>(qb, kkb, vvb, asum, updp,
                                                  (it == 2) ? (out + 1) : (float*)nullptr);
        gru_gates_kernel<<<96, 256, 0, stream>>>(updp, asum, slots, W_ih, W_hh, b_ih, b_hh, gi, gh);
        gru_mlp_kernel<<<16, 256, 0, stream>>>(gi, gh, slots, g_ff, b_ff, Wm1, bm1, Wm2, bm2, asum);
    }

    recon_kernel<<<1, 320, 0, stream>>>(slots, Wr1, br1, g1, be1, Wr2, br2, g2, be2, Wr3, br3, spts);
    fps_kernel<<<4, 64, 0, stream>>>(spts, fidx, lacc, mnbuf);
    chamfer_kernel<<<128, 256, 0, stream>>>(spts, fidx, xyz, lacc, mnbuf);
    chamfer_final_kernel<<<1, 512, 0, stream>>>(mnbuf, lacc, out);
}

// Round 13
// 692.240 us; speedup vs baseline: 1.1357x; 1.0328x over previous
//
#include <hip/hip_runtime.h>

#define NBATCH 4
#define NPTS   4096
#define KNNK   32
#define C1D    128
#define CD     256
#define KPAD   160   // conv2 K padded (131 -> 160, 5 mfma K-steps of 32)
#define ASTR   168   // conv2 LDS A row stride in halves
#define ASTR2  264   // kv LDS A row stride in halves (256 cols + 8 pad)

typedef _Float16 v8h __attribute__((ext_vector_type(8)));
typedef float    v4f __attribute__((ext_vector_type(4)));
typedef unsigned long long ull;

// ---------------- helpers ----------------

__device__ __forceinline__ float block_sum256(float v, float* red) {
    #pragma unroll
    for (int o = 32; o; o >>= 1) v += __shfl_down(v, o);
    __syncthreads();
    if ((threadIdx.x & 63) == 0) red[threadIdx.x >> 6] = v;
    __syncthreads();
    return red[0] + red[1] + red[2] + red[3];
}

__device__ __forceinline__ unsigned rotl32(unsigned x, unsigned r) {
    return (x << r) | (x >> (32u - r));
}

// XLA f32 erf_inv (Giles polynomial)
__device__ float erfinv_f(float x) {
    float w = -log1pf(-x * x);
    float p;
    if (w < 5.0f) {
        w -= 2.5f;
        p = 2.81022636e-08f;
        p = fmaf(p, w, 3.43273939e-07f);
        p = fmaf(p, w, -3.5233877e-06f);
        p = fmaf(p, w, -4.39150654e-06f);
        p = fmaf(p, w, 0.00021858087f);
        p = fmaf(p, w, -0.00125372503f);
        p = fmaf(p, w, -0.00417768164f);
        p = fmaf(p, w, 0.246640727f);
        p = fmaf(p, w, 1.50140941f);
    } else {
        w = sqrtf(w) - 3.0f;
        p = -0.000200214257f;
        p = fmaf(p, w, 0.000100950558f);
        p = fmaf(p, w, 0.00134934322f);
        p = fmaf(p, w, -0.00367342844f);
        p = fmaf(p, w, 0.00573950773f);
        p = fmaf(p, w, -0.0076224613f);
        p = fmaf(p, w, 0.00943887047f);
        p = fmaf(p, w, 1.00167406f);
        p = fmaf(p, w, 2.83297682f);
    }
    return p * x;
}

__device__ __forceinline__ float bits_to_normal(unsigned bits) {
    unsigned fb = (bits >> 9) | 0x3f800000u;
    float f = __uint_as_float(fb) - 1.0f;
    const float lo = -0.99999994f;           // nextafterf(-1,0)
    float u = fmaf(f, 2.0f, lo);
    u = fmaxf(u, lo);
    return 1.41421356237f * erfinv_f(u);
}

// order-preserving float->uint map
__device__ __forceinline__ unsigned fmap(float f) {
    unsigned b = __float_as_uint(f);
    return (b & 0x80000000u) ? ~b : (b | 0x80000000u);
}

// one DPP level of u64-key min
template <int CTRL, int RM>
__device__ __forceinline__ ull dpp_min_u64(ull k) {
    unsigned lo = (unsigned)k, hi = (unsigned)(k >> 32);
    unsigned tlo = (unsigned)__builtin_amdgcn_update_dpp((int)lo, (int)lo, CTRL, RM, 0xf, false);
    unsigned thi = (unsigned)__builtin_amdgcn_update_dpp((int)hi, (int)hi, CTRL, RM, 0xf, false);
    ull t = ((ull)thi << 32) | tlo;
    return t < k ? t : k;
}

// lexicographic max (value desc, index asc on ties) — matches jnp.argmax
template <int CTRL, int RM>
__device__ __forceinline__ void dpp_lexmax(float& v, int& ix) {
    int tv = __builtin_amdgcn_update_dpp(__float_as_int(v), __float_as_int(v), CTRL, RM, 0xf, false);
    int ti = __builtin_amdgcn_update_dpp(ix, ix, CTRL, RM, 0xf, false);
    float fv = __int_as_float(tv);
    bool take = (fv > v) || (fv == v && ti < ix);
    v  = take ? fv : v;
    ix = take ? ti : ix;
}

// ---------------- kernels ----------------

// merged: blocks 0..63 = prep (xyz/xyzw/slots/asum/counter); 64..319 = W2t;
// 320..831 = WkvT
__global__ __launch_bounds__(256) void prep_kernel(const float* __restrict__ x,
                                                   float* __restrict__ xyz,
                                                   float4* __restrict__ xyzw,
                                                   const float* __restrict__ mu,
                                                   const float* __restrict__ sg,
                                                   float* __restrict__ slots,
                                                   float* __restrict__ asum,
                                                   const float* __restrict__ W2,
                                                   const float* __restrict__ Wk,
                                                   const float* __restrict__ Wv,
                                                   _Float16* __restrict__ W2t,
                                                   _Float16* __restrict__ WkvT,
                                                   unsigned* __restrict__ counter) {
    int t = threadIdx.x;
    if (blockIdx.x < 64) {
        int gid = blockIdx.x * 256 + t;
        int b = gid >> 12, n = gid & (NPTS - 1);
        float a0 = x[(b * 3 + 0) * NPTS + n];
        float a1 = x[(b * 3 + 1) * NPTS + n];
        float a2 = x[(b * 3 + 2) * NPTS + n];
        xyz[gid * 3 + 0] = a0; xyz[gid * 3 + 1] = a1; xyz[gid * 3 + 2] = a2;
        float sq = a0 * a0 + a1 * a1 + a2 * a2;
        xyzw[gid] = make_float4(a0, a1, a2, sq);
        if (gid < 16) asum[gid] = 0.0f;
        if (gid == 16) counter[0] = 0u;
        if (gid < 2048) {
            int j = gid;
            unsigned ks0 = 0u, ks1 = 42u, ks2 = 0u ^ 42u ^ 0x1BD11BDAu;
            unsigned x0 = (unsigned)j + ks0;
            unsigned x1 = (unsigned)(j + 2048) + ks1;
            #define RND(r) { x0 += x1; x1 = rotl32(x1, r); x1 ^= x0; }
            RND(13u) RND(15u) RND(26u) RND(6u);  x0 += ks1; x1 += ks2 + 1u;
            RND(17u) RND(29u) RND(16u) RND(24u); x0 += ks2; x1 += ks0 + 2u;
            RND(13u) RND(15u) RND(26u) RND(6u);  x0 += ks0; x1 += ks1 + 3u;
            RND(17u) RND(29u) RND(16u) RND(24u); x0 += ks1; x1 += ks2 + 4u;
            RND(13u) RND(15u) RND(26u) RND(6u);  x0 += ks2; x1 += ks0 + 5u;
            #undef RND
            int c0 = j & 255, c1 = (j + 2048) & 255;
            slots[j]        = mu[c0] + sg[c0] * bits_to_normal(x0);
            slots[j + 2048] = mu[c1] + sg[c1] * bits_to_normal(x1);
        }
    } else if (blockIdx.x < 320) {
        int nb = blockIdx.x - 64;   // 0..255
        if (t < KPAD) W2t[nb * KPAD + t] = (t < 131) ? (_Float16)W2[t * CD + nb] : (_Float16)0.0f;
    } else {
        int n = blockIdx.x - 320;   // 0..511
        float v = (n < 256) ? Wk[t * CD + n] : Wv[t * CD + (n - 256)];
        WkvT[n * CD + t] = (_Float16)v;
    }
}

// KNN: one wave per point, u64-key DPP argmin; matches lax.top_k exactly.
__global__ __launch_bounds__(256) void knn_kernel(const float4* __restrict__ xyzw,
                                                  int* __restrict__ knn_idx) {
    int wid = threadIdx.x >> 6, lane = threadIdx.x & 63;
    int pid = blockIdx.x * 4 + wid;
    int b = pid >> 12, n = pid & (NPTS - 1);
    const float4* xb = xyzw + (size_t)b * NPTS;
    float4 p = xb[n];
    unsigned d[64];
    #pragma unroll
    for (int i = 0; i < 64; ++i) {
        float4 c = xb[i * 64 + lane];
        float dot = p.x * c.x + p.y * c.y + p.z * c.z;
        d[i] = fmap(p.w + c.w - 2.0f * dot);
    }
    unsigned gv[8]; int gi[8];
    #pragma unroll
    for (int g = 0; g < 8; ++g) {
        unsigned mv = d[g * 8]; int mi = g * 8;
        #pragma unroll
        for (int j = 1; j < 8; ++j)
            if (d[g * 8 + j] < mv) { mv = d[g * 8 + j]; mi = g * 8 + j; }
        gv[g] = mv; gi[g] = mi * 64 + lane;
    }
    unsigned lv = gv[0]; int li = gi[0];
    #pragma unroll
    for (int g = 1; g < 8; ++g)
        if (gv[g] < lv) { lv = gv[g]; li = gi[g]; }

    int* out = knn_idx + (size_t)pid * KNNK;
    #pragma unroll 1
    for (int s = 0; s < KNNK; ++s) {
        ull k = ((ull)lv << 32) | (unsigned)li;
        k = dpp_min_u64<0x111, 0xf>(k);
        k = dpp_min_u64<0x112, 0xf>(k);
        k = dpp_min_u64<0x114, 0xf>(k);
        k = dpp_min_u64<0x118, 0xf>(k);
        k = dpp_min_u64<0x142, 0xa>(k);
        k = dpp_min_u64<0x143, 0xc>(k);
        int fm = __builtin_amdgcn_readlane((int)(unsigned)k, 63);
        if (lane == 0) out[s] = fm;
        int flane = fm & 63;
        int slot  = fm >> 6;
        if (lane == flane) {
            int g = slot >> 3;
            #pragma unroll
            for (int g2 = 0; g2 < 8; ++g2) {
                if (g2 == g) {
                    #pragma unroll
                    for (int j = 0; j < 8; ++j)
                        if (g2 * 8 + j == slot) d[g2 * 8 + j] = 0xFFFFFFFFu;
                    unsigned mv = d[g2 * 8]; int mi = g2 * 8;
                    #pragma unroll
                    for (int j = 1; j < 8; ++j)
                        if (d[g2 * 8 + j] < mv) { mv = d[g2 * 8 + j]; mi = g2 * 8 + j; }
                    gv[g2] = mv; gi[g2] = mi * 64 + lane;
                }
            }
            lv = gv[0]; li = gi[0];
            #pragma unroll
            for (int g2 = 1; g2 < 8; ++g2)
                if (gv[g2] < lv) { lv = gv[g2]; li = gi[g2]; }
        }
    }
}

// conv1 -> fp16 features; neighbor coords preloaded into lanes 0..31
__global__ __launch_bounds__(128) void conv1_kernel(const float* __restrict__ xyz,
                                                    const int* __restrict__ knn_idx,
                                                    const float* __restrict__ W1,
                                                    const float* __restrict__ b1,
                                                    _Float16* __restrict__ f1h) {
    int pid = blockIdx.x;
    int b = pid >> 12, n = pid & (NPTS - 1);
    int d = threadIdx.x, lane = threadIdx.x & 63;
    const float* xb = xyz + (size_t)b * NPTS * 3;
    float w0 = W1[d], wx = W1[C1D + d], wy = W1[2 * C1D + d], wz = W1[3 * C1D + d];
    float bb = b1[d];
    float px = xb[n * 3], py = xb[n * 3 + 1], pz = xb[n * 3 + 2];
    const int* idx = knn_idx + (size_t)pid * KNNK;
    float cx = 0.0f, cy = 0.0f, cz = 0.0f;
    if (lane < 32) {
        int j = idx[lane];
        cx = xb[j * 3]; cy = xb[j * 3 + 1]; cz = xb[j * 3 + 2];
    }
    float m = -1e30f;
    #pragma unroll
    for (int k = 0; k < KNNK; ++k) {
        float jx = __shfl(cx, k), jy = __shfl(cy, k), jz = __shfl(cz, k);
        float v = w0 + bb + (jx - px) * wx + (jy - py) * wy + (jz - pz) * wz;
        m = fmaxf(m, v);
    }
    f1h[(size_t)pid * C1D + d] = (_Float16)fmaxf(m, 0.0f);
}

// conv2 via MFMA f16 + fused bias/relu/max-over-k/LayerNorm -> inph fp16
__global__ __launch_bounds__(256) void conv2_mfma_kernel(const float* __restrict__ xyz,
                                                         const _Float16* __restrict__ f1h,
                                                         const int* __restrict__ knn_idx,
                                                         const _Float16* __restrict__ W2t,
                                                         const float* __restrict__ b2,
                                                         const float* __restrict__ g_in,
                                                         const float* __restrict__ b_in,
                                                         _Float16* __restrict__ inph) {
    __shared__ _Float16 A[64 * ASTR];
    __shared__ float colmax[2 * CD];
    __shared__ float red[4];
    int pid2 = blockIdx.x;
    int gp0 = pid2 * 2;
    int b = gp0 >> 12, n0 = gp0 & (NPTS - 1);
    int tid = threadIdx.x;
    const int* idx = knn_idx + (size_t)pid2 * 64;   // [2][32]
    const float* xb = xyz + (size_t)b * NPTS * 3;

    {
        int r = tid & 63, seg = tid >> 6;
        int j = idx[r];
        const uint4* s4 = (const uint4*)(f1h + ((size_t)b * NPTS + j) * C1D);
        uint4* d4 = (uint4*)&A[r * ASTR];
        #pragma unroll
        for (int i = 0; i < 4; ++i) d4[seg * 4 + i] = s4[seg * 4 + i];
        unsigned* z = (unsigned*)&A[r * ASTR + 128];
        for (int i = seg; i < 20; i += 4) z[i] = 0u;
        int np_ = (r < 32) ? n0 : (n0 + 1);
        if (seg == 0) {
            A[r * ASTR + 128] = (_Float16)(xb[j * 3 + 0] - xb[np_ * 3 + 0]);
            A[r * ASTR + 129] = (_Float16)(xb[j * 3 + 1] - xb[np_ * 3 + 1]);
        } else if (seg == 1) {
            A[r * ASTR + 130] = (_Float16)(xb[j * 3 + 2] - xb[np_ * 3 + 2]);
        }
    }
    __syncthreads();

    int w = tid >> 6, lane = tid & 63, quad = lane >> 4, lr = lane & 15;
    v4f acc[4][4];
    #pragma unroll
    for (int rt = 0; rt < 4; ++rt)
        #pragma unroll
        for (int ct = 0; ct < 4; ++ct)
            acc[rt][ct] = (v4f){0.0f, 0.0f, 0.0f, 0.0f};

    #pragma unroll
    for (int kk = 0; kk < KPAD; kk += 32) {
        v8h af[4], bf[4];
        #pragma unroll
        for (int rt = 0; rt < 4; ++rt)
            af[rt] = *(const v8h*)&A[(rt * 16 + lr) * ASTR + kk + quad * 8];
        #pragma unroll
        for (int ct = 0; ct < 4; ++ct) {
            int ncol = w * 64 + ct * 16 + lr;
            bf[ct] = *(const v8h*)(W2t + (size_t)ncol * KPAD + kk + quad * 8);
        }
        #pragma unroll
        for (int rt = 0; rt < 4; ++rt)
            #pragma unroll
            for (int ct = 0; ct < 4; ++ct)
                acc[rt][ct] = __builtin_amdgcn_mfma_f32_16x16x32_f16(af[rt], bf[ct], acc[rt][ct], 0, 0, 0);
    }

    #pragma unroll
    for (int ct = 0; ct < 4; ++ct) {
        float tm[4];
        #pragma unroll
        for (int rt = 0; rt < 4; ++rt) {
            v4f a = acc[rt][ct];
            float v = fmaxf(fmaxf(a[0], a[1]), fmaxf(a[2], a[3]));
            v = fmaxf(v, __shfl_xor(v, 16));
            v = fmaxf(v, __shfl_xor(v, 32));
            tm[rt] = v;
        }
        float p0 = fmaxf(tm[0], tm[1]);
        float p1 = fmaxf(tm[2], tm[3]);
        if (quad == 0) {
            colmax[0 * CD + w * 64 + ct * 16 + lr] = p0;
            colmax[1 * CD + w * 64 + ct * 16 + lr] = p1;
        }
    }
    __syncthreads();

    int d = tid;
    #pragma unroll
    for (int p = 0; p < 2; ++p) {
        float v = fmaxf(colmax[p * CD + d] + b2[d], 0.0f);
        float s = block_sum256(v, red);
        float mean = s * (1.0f / 256.0f);
        float s2 = block_sum256(v * v, red);
        float var = s2 * (1.0f / 256.0f) - mean * mean;
        float iv = (v - mean) * rsqrtf(var + 1e-5f) * g_in[d] + b_in[d];
        inph[(size_t)(gp0 + p) * CD + d] = (_Float16)iv;
    }
}

// kv via MFMA fp16: block = 64 points x 256 cols; half 0 -> kk, half 1 -> vv.
__global__ __launch_bounds__(256) void kv_mfma_kernel(const _Float16* __restrict__ inph,
                                                      const _Float16* __restrict__ WkvT,
                                                      float* __restrict__ kk,
                                                      float* __restrict__ vv) {
    __shared__ _Float16 A[64 * ASTR2];
    int rb = blockIdx.x >> 1, half = blockIdx.x & 1;
    int row0 = rb * 64;
    int tid = threadIdx.x;
    {
        const uint4* src4 = (const uint4*)(inph + (size_t)row0 * CD);
        #pragma unroll
        for (int i = 0; i < 8; ++i) {
            int idx = i * 256 + tid;
            int row = idx >> 5, c8 = idx & 31;
            *(uint4*)&A[row * ASTR2 + c8 * 8] = src4[idx];
        }
    }
    __syncthreads();
    int w = tid >> 6, lane = tid & 63, quad = lane >> 4, lr = lane & 15;
    v4f acc[4][4];
    #pragma unroll
    for (int rt = 0; rt < 4; ++rt)
        #pragma unroll
        for (int ct = 0; ct < 4; ++ct)
            acc[rt][ct] = (v4f){0.0f, 0.0f, 0.0f, 0.0f};
    #pragma unroll
    for (int ks = 0; ks < CD; ks += 32) {
        v8h af[4], bf[4];
        #pragma unroll
        for (int rt = 0; rt < 4; ++rt)
            af[rt] = *(const v8h*)&A[(rt * 16 + lr) * ASTR2 + ks + quad * 8];
        #pragma unroll
        for (int ct = 0; ct < 4; ++ct) {
            int ncol = half * 256 + w * 64 + ct * 16 + lr;
            bf[ct] = *(const v8h*)(WkvT + (size_t)ncol * CD + ks + quad * 8);
        }
        #pragma unroll
        for (int rt = 0; rt < 4; ++rt)
            #pragma unroll
            for (int ct = 0; ct < 4; ++ct)
                acc[rt][ct] = __builtin_amdgcn_mfma_f32_16x16x32_f16(af[rt], bf[ct], acc[rt][ct], 0, 0, 0);
    }
    float* dst = half ? vv : kk;
    #pragma unroll
    for (int rt = 0; rt < 4; ++rt)
        #pragma unroll
        for (int ct = 0; ct < 4; ++ct) {
            int col = w * 64 + ct * 16 + lr;
            #pragma unroll
            for (int r = 0; r < 4; ++r) {
                int row = rt * 16 + quad * 4 + r;
                dst[(size_t)(row0 + row) * CD + col] = acc[rt][ct][r];
            }
        }
}

// q = LN(slots) @ Wq, one block per row (b,k) — iter 0 only
__global__ __launch_bounds__(256) void slotq_kernel(const float* __restrict__ slots,
                                                    const float* __restrict__ g_sl,
                                                    const float* __restrict__ b_sl,
                                                    const float* __restrict__ Wq,
                                                    float* __restrict__ q) {
    int row = blockIdx.x;
    int d = threadIdx.x;
    __shared__ float sl[CD];
    __shared__ float red[4];
    float v = slots[row * CD + d];
    float s = block_sum256(v, red);
    float mean = s * (1.0f / 256.0f);
    float s2 = block_sum256(v * v, red);
    float var = s2 * (1.0f / 256.0f) - mean * mean;
    float ln = (v - mean) * rsqrtf(var + 1e-5f) * g_sl[d] + b_sl[d];
    sl[d] = ln;
    __syncthreads();
    float acc = 0.0f;
    const float4* sp = (const float4*)sl;
    for (int c4 = 0; c4 < 64; ++c4) {
        float4 x = sp[c4];
        int cb = c4 * 4;
        acc += x.x * Wq[cb * CD + d] + x.y * Wq[(cb + 1) * CD + d]
             + x.z * Wq[(cb + 2) * CD + d] + x.w * Wq[(cb + 3) * CD + d];
    }
    q[row * CD + d] = acc;
}

// FUSED attn+updp, 256 blocks
__global__ __launch_bounds__(256) void attn_updp_kernel(const float* __restrict__ q,
                                                        const float* __restrict__ kk,
                                                        const float* __restrict__ vv,
                                                        float* __restrict__ asum,
                                                        float* __restrict__ updp,
                                                        float* __restrict__ out_attn) {
    int b = blockIdx.x >> 6;
    int chunk = blockIdx.x & 63;
    int t = threadIdx.x;
    __shared__ float qs[4 * CD];
    __shared__ float logit[64 * 4];
    __shared__ float aw[64 * 4];
    for (int i = t; i < 4 * CD; i += 256) qs[i] = q[b * 4 * CD + i];
    __syncthreads();

    int p = t & 63, r = t >> 6;
    int n = chunk * 64 + p;
    {
        const float4* kp = (const float4*)(kk + ((size_t)b * NPTS + n) * CD);
        const float4* qr = (const float4*)(qs + r * CD);
        float a = 0.0f;
        for (int c4 = 0; c4 < 64; ++c4) {
            float4 kv = kp[c4];
            float4 x = qr[c4];
            a += kv.x * x.x + kv.y * x.y + kv.z * x.z + kv.w * x.w;
        }
        logit[p * 4 + r] = 0.0625f * a;   // 256^-0.5
    }
    __syncthreads();
    if (t < 64) {
        float l0 = logit[t * 4 + 0], l1 = logit[t * 4 + 1];
        float l2 = logit[t * 4 + 2], l3 = logit[t * 4 + 3];
        float mx = fmaxf(fmaxf(l0, l1), fmaxf(l2, l3));
        float e0 = expf(l0 - mx), e1 = expf(l1 - mx), e2 = expf(l2 - mx), e3 = expf(l3 - mx);
        float inv = 1.0f / (e0 + e1 + e2 + e3);
        e0 *= inv; e1 *= inv; e2 *= inv; e3 *= inv;
        aw[t * 4 + 0] = e0; aw[t * 4 + 1] = e1; aw[t * 4 + 2] = e2; aw[t * 4 + 3] = e3;
        if (out_attn) {
            float* o = out_attn + ((size_t)b * NPTS + chunk * 64 + t) * 4;
            o[0] = e0; o[1] = e1; o[2] = e2; o[3] = e3;
        }
        float s0 = e0, s1 = e1, s2 = e2, s3 = e3;
        #pragma unroll
        for (int o = 32; o; o >>= 1) {
            s0 += __shfl_down(s0, o); s1 += __shfl_down(s1, o);
            s2 += __shfl_down(s2, o); s3 += __shfl_down(s3, o);
        }
        if (t == 0) {
            atomicAdd(&asum[b * 4 + 0], s0);
            atomicAdd(&asum[b * 4 + 1], s1);
            atomicAdd(&asum[b * 4 + 2], s2);
            atomicAdd(&asum[b * 4 + 3], s3);
        }
    }
    __syncthreads();

    float ac0 = 0.0f, ac1 = 0.0f, ac2 = 0.0f, ac3 = 0.0f;
    const float* vb = vv + ((size_t)b * NPTS + chunk * 64) * CD;
    for (int nn2 = 0; nn2 < 64; ++nn2) {
        float v = vb[(size_t)nn2 * CD + t];
        float4 w4 = *(const float4*)&aw[nn2 * 4];
        ac0 += w4.x * v; ac1 += w4.y * v; ac2 += w4.z * v; ac3 += w4.w * v;
    }
    updp[((size_t)(b * 4 + 0) * 64 + chunk) * CD + t] = ac0;
    updp[((size_t)(b * 4 + 1) * 64 + chunk) * CD + t] = ac1;
    updp[((size_t)(b * 4 + 2) * 64 + chunk) * CD + t] = ac2;
    updp[((size_t)(b * 4 + 3) * 64 + chunk) * CD + t] = ac3;
}

// GRU gates, 96 blocks: (row, gate, c-half).
__global__ __launch_bounds__(256) void gru_gates_kernel(const float* __restrict__ updp,
                                                        const float* __restrict__ asum,
                                                        const float* __restrict__ slots,
                                                        const float* __restrict__ W_ih,
                                                        const float* __restrict__ W_hh,
                                                        const float* __restrict__ b_ih,
                                                        const float* __restrict__ b_hh,
                                                        float* __restrict__ gi,
                                                        float* __restrict__ gh) {
    int idx = blockIdx.x;
    int row = idx / 6, rem = idx % 6;
    int gate = rem >> 1, half = rem & 1;
    int d = threadIdx.x;
    __shared__ float su[CD], sp[CD];
    float f = 1.0f / (asum[row] + 1e-8f);
    float u = 0.0f;
    for (int p = 0; p < 64; ++p) u += updp[((size_t)row * 64 + p) * CD + d];
    u *= f;
    su[d] = u; sp[d] = slots[row * CD + d];
    __syncthreads();
    float acc_i = half ? 0.0f : b_ih[gate * CD + d];
    float acc_h = half ? 0.0f : b_hh[gate * CD + d];
    const float* wi = W_ih + gate * CD + d;
    const float* wh = W_hh + gate * CD + d;
    int c0 = half * 128;
    for (int c = c0; c < c0 + 128; ++c) {
        acc_i += su[c] * wi[c * 3 * CD];
        acc_h += sp[c] * wh[c * 3 * CD];
    }
    gi[((size_t)(row * 3 + gate) * 2 + half) * CD + d] = acc_i;
    gh[((size_t)(row * 3 + gate) * 2 + half) * CD + d] = acc_h;
}

// GRU update + LN_ff + MLP residual + (optional) NEXT-ITER slotq, one block/row
__global__ __launch_bounds__(256) void gru_mlp_kernel(const float* __restrict__ gi,
                                                      const float* __restrict__ gh,
                                                      float* __restrict__ slots,
                                                      const float* __restrict__ g_ff,
                                                      const float* __restrict__ b_ff,
                                                      const float* __restrict__ Wm1,
                                                      const float* __restrict__ bm1,
                                                      const float* __restrict__ Wm2,
                                                      const float* __restrict__ bm2,
                                                      float* __restrict__ asum,
                                                      const float* __restrict__ g_sl,
                                                      const float* __restrict__ b_sl,
                                                      const float* __restrict__ Wq,
                                                      float* __restrict__ qv) {
    int row = blockIdx.x;
    int d = threadIdx.x;
    __shared__ float sh[CD];
    __shared__ float red[4];
    float prev = slots[row * CD + d];
    float gir = gi[((size_t)(row * 3 + 0) * 2 + 0) * CD + d] + gi[((size_t)(row * 3 + 0) * 2 + 1) * CD + d];
    float giz = gi[((size_t)(row * 3 + 1) * 2 + 0) * CD + d] + gi[((size_t)(row * 3 + 1) * 2 + 1) * CD + d];
    float gin = gi[((size_t)(row * 3 + 2) * 2 + 0) * CD + d] + gi[((size_t)(row * 3 + 2) * 2 + 1) * CD + d];
    float ghr = gh[((size_t)(row * 3 + 0) * 2 + 0) * CD + d] + gh[((size_t)(row * 3 + 0) * 2 + 1) * CD + d];
    float ghz = gh[((size_t)(row * 3 + 1) * 2 + 0) * CD + d] + gh[((size_t)(row * 3 + 1) * 2 + 1) * CD + d];
    float ghn = gh[((size_t)(row * 3 + 2) * 2 + 0) * CD + d] + gh[((size_t)(row * 3 + 2) * 2 + 1) * CD + d];
    if (d == 0) asum[row] = 0.0f;
    float r = 1.0f / (1.0f + expf(-(gir + ghr)));
    float z = 1.0f / (1.0f + expf(-(giz + ghz)));
    float nn = tanhf(gin + r * ghn);
    float sNew = (1.0f - z) * nn + z * prev;
    float s = block_sum256(sNew, red);
    float mean = s * (1.0f / 256.0f);
    float s2 = block_sum256(sNew * sNew, red);
    float var = s2 * (1.0f / 256.0f) - mean * mean;
    float h = (sNew - mean) * rsqrtf(var + 1e-5f) * g_ff[d] + b_ff[d];
    __syncthreads();
    sh[d] = h;
    __syncthreads();
    float y = bm1[d];
    {
        const float4* hp = (const float4*)sh;
        for (int c4 = 0; c4 < 64; ++c4) {
            float4 x = hp[c4];
            int cb = c4 * 4;
            y += x.x * Wm1[cb * CD + d] + x.y * Wm1[(cb + 1) * CD + d]
               + x.z * Wm1[(cb + 2) * CD + d] + x.w * Wm1[(cb + 3) * CD + d];
        }
    }
    y = fmaxf(y, 0.0f);
    __syncthreads();
    sh[d] = y;
    __syncthreads();
    float o = bm2[d];
    {
        const float4* hp = (const float4*)sh;
        for (int c4 = 0; c4 < 64; ++c4) {
            float4 x = hp[c4];
            int cb = c4 * 4;
            o += x.x * Wm2[cb * CD + d] + x.y * Wm2[(cb + 1) * CD + d]
               + x.z * Wm2[(cb + 2) * CD + d] + x.w * Wm2[(cb + 3) * CD + d];
        }
    }
    float fin = sNew + o;
    slots[row * CD + d] = fin;
    if (qv) {
        // identical arithmetic to slotq, with v = fin
        float v = fin;
        float s3 = block_sum256(v, red);
        float mean2 = s3 * (1.0f / 256.0f);
        float s4 = block_sum256(v * v, red);
        float var2 = s4 * (1.0f / 256.0f) - mean2 * mean2;
        float ln = (v - mean2) * rsqrtf(var2 + 1e-5f) * g_sl[d] + b_sl[d];
        __syncthreads();
        sh[d] = ln;
        __syncthreads();
        float acc = 0.0f;
        const float4* sp = (const float4*)sh;
        for (int c4 = 0; c4 < 64; ++c4) {
            float4 x = sp[c4];
            int cb = c4 * 4;
            acc += x.x * Wq[cb * CD + d] + x.y * Wq[(cb + 1) * CD + d]
                 + x.z * Wq[(cb + 2) * CD + d] + x.w * Wq[(cb + 3) * CD + d];
        }
        qv[row * CD + d] = acc;
    }
}

// recon head + in-kernel FPS, 4 blocks (one per batch); BN stack redundantly
// computed per block (identical arithmetic -> identical spts).
__global__ __launch_bounds__(320) void recon_fps_kernel(const float* __restrict__ slots,
                                                        const float* __restrict__ Wr1, const float* __restrict__ br1,
                                                        const float* __restrict__ g1, const float* __restrict__ be1,
                                                        const float* __restrict__ Wr2, const float* __restrict__ br2,
                                                        const float* __restrict__ g2, const float* __restrict__ be2,
                                                        const float* __restrict__ Wr3, const float* __restrict__ br3,
                                                        float* __restrict__ spts,
                                                        int* __restrict__ fidx,
                                                        float* __restrict__ lacc,
                                                        unsigned* __restrict__ mnbuf) {
    __shared__ float sl[16 * CD];
    __shared__ float h1[16 * CD];
    __shared__ float h2[16 * CD];
    __shared__ float sp[384 * 3];
    int b = blockIdx.x;
    int d = threadIdx.x;
    if (d < CD) for (int r = 0; r < 16; ++r) sl[r * CD + d] = slots[r * CD + d];
    __syncthreads();
    if (d < CD) {
        float t[16];
        #pragma unroll
        for (int r = 0; r < 16; ++r) t[r] = br1[d];
        for (int c4 = 0; c4 < 64; ++c4) {
            int cb = c4 * 4;
            float w0 = Wr1[cb * CD + d], w1 = Wr1[(cb + 1) * CD + d];
            float w2 = Wr1[(cb + 2) * CD + d], w3 = Wr1[(cb + 3) * CD + d];
            #pragma unroll
            for (int r = 0; r < 16; ++r) {
                float4 x = *(const float4*)(sl + r * CD + cb);
                t[r] += x.x * w0 + x.y * w1 + x.z * w2 + x.w * w3;
            }
        }
        float mean = 0.0f;
        for (int r = 0; r < 16; ++r) mean += t[r];
        mean *= (1.0f / 16.0f);
        float var = 0.0f;
        for (int r = 0; r < 16; ++r) { float dd = t[r] - mean; var += dd * dd; }
        var *= (1.0f / 16.0f);
        float inv = rsqrtf(var + 1e-5f);
        for (int r = 0; r < 16; ++r)
            h1[r * CD + d] = fmaxf(0.0f, (t[r] - mean) * inv * g1[d] + be1[d]);
    }
    __syncthreads();
    if (d < CD) {
        float t[16];
        #pragma unroll
        for (int r = 0; r < 16; ++r) t[r] = br2[d];
        for (int c4 = 0; c4 < 64; ++c4) {
            int cb = c4 * 4;
            float w0 = Wr2[cb * CD + d], w1 = Wr2[(cb + 1) * CD + d];
            float w2 = Wr2[(cb + 2) * CD + d], w3 = Wr2[(cb + 3) * CD + d];
            #pragma unroll
            for (int r = 0; r < 16; ++r) {
                float4 x = *(const float4*)(h1 + r * CD + cb);
                t[r] += x.x * w0 + x.y * w1 + x.z * w2 + x.w * w3;
            }
        }
        float mean = 0.0f;
        for (int r = 0; r < 16; ++r) mean += t[r];
        mean *= (1.0f / 16.0f);
        float var = 0.0f;
        for (int r = 0; r < 16; ++r) { float dd = t[r] - mean; var += dd * dd; }
        var *= (1.0f / 16.0f);
        float inv = rsqrtf(var + 1e-5f);
        for (int r = 0; r < 16; ++r)
            h2[r * CD + d] = fmaxf(0.0f, (t[r] - mean) * inv * g2[d] + be2[d]);
    }
    __syncthreads();
    if (d < 288) {
        #pragma unroll
        for (int rl = 0; rl < 4; ++rl) {
            int r = b * 4 + rl;
            float t = br3[d];
            for (int c4 = 0; c4 < 64; ++c4) {
                int cb = c4 * 4;
                float w0 = Wr3[cb * 288 + d], w1 = Wr3[(cb + 1) * 288 + d];
                float w2 = Wr3[(cb + 2) * 288 + d], w3 = Wr3[(cb + 3) * 288 + d];
                float4 x = *(const float4*)(h2 + r * CD + cb);
                t += x.x * w0 + x.y * w1 + x.z * w2 + x.w * w3;
            }
            spts[r * 288 + d] = t;
            sp[rl * 288 + d] = t;
        }
    }
    __syncthreads();

    // ---- FPS on LDS points (identical selection semantics) ----
    if (d < 64) {
        int lane = d;
        int* out = fidx + b * 128;
        if (lane == 0) out[0] = 0;
        if (b == 0 && lane == 0) lacc[0] = 0.0f;
        mnbuf[b * 128 + lane] = 0x7F800000u;
        mnbuf[b * 128 + 64 + lane] = 0x7F800000u;
        float px[6], py[6], pz[6], dd[6];
        #pragma unroll
        for (int i = 0; i < 6; ++i) {
            int m = i * 64 + lane;
            px[i] = sp[m * 3]; py[i] = sp[m * 3 + 1]; pz[i] = sp[m * 3 + 2];
            dd[i] = 1e10f;
        }
        float lx = sp[0], ly = sp[1], lz = sp[2];
        #pragma unroll 1
        for (int s = 1; s < 128; ++s) {
            #pragma unroll
            for (int i = 0; i < 6; ++i) {
                float dx = px[i] - lx, dy = py[i] - ly, dz = pz[i] - lz;
                dd[i] = fminf(dd[i], dx * dx + dy * dy + dz * dz);
            }
            float bv = dd[0]; int bi = lane;
            #pragma unroll
            for (int i = 1; i < 6; ++i)
                if (dd[i] > bv) { bv = dd[i]; bi = i * 64 + lane; }
            dpp_lexmax<0x111, 0xf>(bv, bi);
            dpp_lexmax<0x112, 0xf>(bv, bi);
            dpp_lexmax<0x114, 0xf>(bv, bi);
            dpp_lexmax<0x118, 0xf>(bv, bi);
            dpp_lexmax<0x142, 0xa>(bv, bi);
            dpp_lexmax<0x143, 0xc>(bv, bi);
            int fm = __builtin_amdgcn_readlane(bi, 63);
            if (lane == 0) out[s] = fm;
            int slot = fm >> 6, sl_lane = fm & 63;
            float sx = px[0], sy = py[0], sz = pz[0];
            #pragma unroll
            for (int i = 1; i < 6; ++i)
                if (slot == i) { sx = px[i]; sy = py[i]; sz = pz[i]; }
            lx = __int_as_float(__builtin_amdgcn_readlane(__float_as_int(sx), sl_lane));
            ly = __int_as_float(__builtin_amdgcn_readlane(__float_as_int(sy), sl_lane));
            lz = __int_as_float(__builtin_amdgcn_readlane(__float_as_int(sz), sl_lane));
        }
    }
}

// merged chamfer: blocks 0..63 = sum2, 64..127 = min1; last block writes loss
__global__ __launch_bounds__(256) void chamfer_kernel(const float* __restrict__ spts,
                                                      const int* __restrict__ fidx,
                                                      const float* __restrict__ xyz,
                                                      float* __restrict__ lacc,
                                                      unsigned* __restrict__ mnbuf,
                                                      unsigned* __restrict__ counter,
                                                      float* __restrict__ out) {
    int t = threadIdx.x;
    __shared__ float ds[128 * 3];
    __shared__ float tile[256 * 3];
    __shared__ float red[4];
    __shared__ unsigned done;
    if (blockIdx.x < 64) {
        int b = blockIdx.x >> 4, chunk = blockIdx.x & 15;
        const float* pts = spts + (size_t)b * 384 * 3;
        if (t < 128) {
            int j = fidx[b * 128 + t];
            ds[t * 3] = pts[j * 3]; ds[t * 3 + 1] = pts[j * 3 + 1]; ds[t * 3 + 2] = pts[j * 3 + 2];
        }
        __syncthreads();
        int n = chunk * 256 + t;
        const float* xb = xyz + (size_t)b * NPTS * 3;
        float px = xb[n * 3], py = xb[n * 3 + 1], pz = xb[n * 3 + 2];
        float mn = 1e30f;
        #pragma unroll 4
        for (int jj = 0; jj < 128; ++jj) {
            float dx = ds[jj * 3] - px, dy = ds[jj * 3 + 1] - py, dz = ds[jj * 3 + 2] - pz;
            mn = fminf(mn, dx * dx + dy * dy + dz * dz);
        }
        float total = block_sum256(mn * (1.0f / 4096.0f), red);
        if (t == 0) atomicAdd(lacc, total);
    } else {
        int bid = blockIdx.x - 64;
        int b = bid >> 4, chunk = bid & 15;
        const float* xb = xyz + ((size_t)b * NPTS + chunk * 256) * 3;
        for (int i = t; i < 768; i += 256) tile[i] = xb[i];
        __syncthreads();
        if (t < 128) {
            int j = fidx[b * 128 + t];
            const float* pts = spts + (size_t)b * 384 * 3;
            float px = pts[j * 3], py = pts[j * 3 + 1], pz = pts[j * 3 + 2];
            float mn = 1e30f;
            #pragma unroll 4
            for (int i = 0; i < 256; ++i) {
                float dx = tile[i * 3] - px, dy = tile[i * 3 + 1] - py, dz = tile[i * 3 + 2] - pz;
                mn = fminf(mn, dx * dx + dy * dy + dz * dz);
            }
            atomicMin(&mnbuf[b * 128 + t], __float_as_uint(mn));
        }
    }
    // last-block loss finalize
    __threadfence();
    __syncthreads();
    if (t == 0) done = atomicAdd(counter, 1u);
    __syncthreads();
    if (done == 127u) {
        unsigned a0 = atomicAdd(&mnbuf[t], 0u);
        unsigned a1 = atomicAdd(&mnbuf[t + 256], 0u);
        float v = (__uint_as_float(a0) + __uint_as_float(a1)) * (1.0f / 128.0f);
        __syncthreads();
        float tot = block_sum256(v, red);
        if (t == 0) {
            float l = atomicAdd(lacc, 0.0f);
            out[0] = (l + tot) * 0.25f;
        }
    }
}

// ---------------- launch ----------------

extern "C" void kernel_launch(void* const* d_in, const int* in_sizes, int n_in,
                              void* d_out, int out_size, void* d_ws, size_t ws_size,
                              hipStream_t stream) {
    (void)in_sizes; (void)n_in; (void)out_size; (void)ws_size;
    const float* x    = (const float*)d_in[0];
    const float* W1   = (const float*)d_in[2];
    const float* b1   = (const float*)d_in[3];
    const float* W2   = (const float*)d_in[4];
    const float* b2   = (const float*)d_in[5];
    const float* mu   = (const float*)d_in[6];
    const float* sg   = (const float*)d_in[7];
    const float* g_in = (const float*)d_in[8];
    const float* b_in = (const float*)d_in[9];
    const float* g_sl = (const float*)d_in[10];
    const float* b_sl = (const float*)d_in[11];
    const float* g_ff = (const float*)d_in[12];
    const float* b_ff = (const float*)d_in[13];
    const float* Wq   = (const float*)d_in[14];
    const float* Wk   = (const float*)d_in[15];
    const float* Wv   = (const float*)d_in[16];
    const float* W_ih = (const float*)d_in[17];
    const float* W_hh = (const float*)d_in[18];
    const float* b_ih = (const float*)d_in[19];
    const float* b_hh = (const float*)d_in[20];
    const float* Wm1  = (const float*)d_in[21];
    const float* bm1  = (const float*)d_in[22];
    const float* Wm2  = (const float*)d_in[23];
    const float* bm2  = (const float*)d_in[24];
    const float* Wr1  = (const float*)d_in[25];
    const float* br1  = (const float*)d_in[26];
    const float* g1   = (const float*)d_in[27];
    const float* be1  = (const float*)d_in[28];
    const float* Wr2  = (const float*)d_in[29];
    const float* br2  = (const float*)d_in[30];
    const float* g2   = (const float*)d_in[31];
    const float* be2  = (const float*)d_in[32];
    const float* Wr3  = (const float*)d_in[33];
    const float* br3  = (const float*)d_in[34];

    float* ws    = (float*)d_ws;
    float* xyz   = ws;                               // 49152 f
    float* xyzw  = xyz + 49152;                      // 65536 f
    int*   knn   = (int*)(xyzw + 65536);             // 524288 i
    _Float16* f1h = (_Float16*)(knn + 524288);       // -> 1048576 f
    _Float16* W2t = (_Float16*)((float*)f1h + 1048576);  // -> 20480 f
    _Float16* WkvT = (_Float16*)((float*)W2t + 20480);   // -> 65536 f
    _Float16* inph = (_Float16*)((float*)WkvT + 65536);  // -> 2097152 f
    float* kkb   = (float*)inph + 2097152;           // 4194304 f
    float* vvb   = kkb + 4194304;                    // 4194304 f
    float* slots = vvb + 4194304;                    // 4096 f
    float* qb    = slots + 4096;                     // 4096 f
    float* asum  = qb + 4096;                        // 16 f
    float* updp  = asum + 16;                        // 262144 f
    float* gi    = updp + 262144;                    // 24576 f
    float* gh    = gi + 24576;                       // 24576 f
    float* spts  = gh + 24576;                       // 4608 f
    int*   fidx  = (int*)(spts + 4608);              // 512 i
    float* lacc  = (float*)(fidx + 512);             // 1 f
    unsigned* mnbuf = (unsigned*)(lacc + 1);         // 512 u
    unsigned* counter = mnbuf + 512;                 // 1 u

    float* out = (float*)d_out;

    prep_kernel<<<832, 256, 0, stream>>>(x, xyz, (float4*)xyzw, mu, sg, slots, asum,
                                         W2, Wk, Wv, W2t, WkvT, counter);
    knn_kernel<<<NBATCH * NPTS / 4, 256, 0, stream>>>((const float4*)xyzw, knn);
    conv1_kernel<<<NBATCH * NPTS, 128, 0, stream>>>(xyz, knn, W1, b1, f1h);
    conv2_mfma_kernel<<<NBATCH * NPTS / 2, 256, 0, stream>>>(xyz, f1h, knn, W2t, b2, g_in, b_in, inph);
    kv_mfma_kernel<<<NBATCH * NPTS / 64 * 2, 256, 0, stream>>>(inph, WkvT, kkb, vvb);

    slotq_kernel<<<16, 256, 0, stream>>>(slots, g_sl, b_sl, Wq, qb);
    for (int it = 0; it < 3; ++it) {
        attn_updp_kernel<<<256, 256, 0, stream>>>(qb, kkb, vvb, asum, updp,
                                                  (it == 2) ? (out + 1) : (float*)nullptr);
        gru_gates_kernel<<<96, 256, 0, stream>>>(updp, asum, slots, W_ih, W_hh, b_ih, b_hh, gi, gh);
        gru_mlp_kernel<<<16, 256, 0, stream>>>(gi, gh, slots, g_ff, b_ff, Wm1, bm1, Wm2, bm2, asum,
                                               g_sl, b_sl, Wq, (it < 2) ? qb : (float*)nullptr);
    }

    recon_fps_kernel<<<4, 320, 0, stream>>>(slots, Wr1, br1, g1, be1, Wr2, br2, g2, be2,
                                            Wr3, br3, spts, fidx, lacc, mnbuf);
    chamfer_kernel<<<128, 256, 0, stream>>>(spts, fidx, xyz, lacc, mnbuf, counter, out);
}

// Round 14
// 678.497 us; speedup vs baseline: 1.1587x; 1.0203x over previous
//
#include <hip/hip_runtime.h>

#define NBATCH 4
#define NPTS   4096
#define KNNK   32
#define C1D    128
#define CD     256
#define KPAD   160   // conv2 K padded (131 -> 160, 5 mfma K-steps of 32)
#define ASTR   168   // conv2 LDS A row stride in halves
#define ASTR2  264   // kv LDS A row stride in halves (256 cols + 8 pad)

typedef _Float16 v8h __attribute__((ext_vector_type(8)));
typedef float    v4f __attribute__((ext_vector_type(4)));
typedef unsigned long long ull;

// ---------------- helpers ----------------

__device__ __forceinline__ float block_sum256(float v, float* red) {
    #pragma unroll
    for (int o = 32; o; o >>= 1) v += __shfl_down(v, o);
    __syncthreads();
    if ((threadIdx.x & 63) == 0) red[threadIdx.x >> 6] = v;
    __syncthreads();
    return red[0] + red[1] + red[2] + red[3];
}

__device__ __forceinline__ unsigned rotl32(unsigned x, unsigned r) {
    return (x << r) | (x >> (32u - r));
}

// XLA f32 erf_inv (Giles polynomial)
__device__ float erfinv_f(float x) {
    float w = -log1pf(-x * x);
    float p;
    if (w < 5.0f) {
        w -= 2.5f;
        p = 2.81022636e-08f;
        p = fmaf(p, w, 3.43273939e-07f);
        p = fmaf(p, w, -3.5233877e-06f);
        p = fmaf(p, w, -4.39150654e-06f);
        p = fmaf(p, w, 0.00021858087f);
        p = fmaf(p, w, -0.00125372503f);
        p = fmaf(p, w, -0.00417768164f);
        p = fmaf(p, w, 0.246640727f);
        p = fmaf(p, w, 1.50140941f);
    } else {
        w = sqrtf(w) - 3.0f;
        p = -0.000200214257f;
        p = fmaf(p, w, 0.000100950558f);
        p = fmaf(p, w, 0.00134934322f);
        p = fmaf(p, w, -0.00367342844f);
        p = fmaf(p, w, 0.00573950773f);
        p = fmaf(p, w, -0.0076224613f);
        p = fmaf(p, w, 0.00943887047f);
        p = fmaf(p, w, 1.00167406f);
        p = fmaf(p, w, 2.83297682f);
    }
    return p * x;
}

__device__ __forceinline__ float bits_to_normal(unsigned bits) {
    unsigned fb = (bits >> 9) | 0x3f800000u;
    float f = __uint_as_float(fb) - 1.0f;
    const float lo = -0.99999994f;           // nextafterf(-1,0)
    float u = fmaf(f, 2.0f, lo);
    u = fmaxf(u, lo);
    return 1.41421356237f * erfinv_f(u);
}

// order-preserving float->uint map
__device__ __forceinline__ unsigned fmap(float f) {
    unsigned b = __float_as_uint(f);
    return (b & 0x80000000u) ? ~b : (b | 0x80000000u);
}

// one DPP level of u64-key min
template <int CTRL, int RM>
__device__ __forceinline__ ull dpp_min_u64(ull k) {
    unsigned lo = (unsigned)k, hi = (unsigned)(k >> 32);
    unsigned tlo = (unsigned)__builtin_amdgcn_update_dpp((int)lo, (int)lo, CTRL, RM, 0xf, false);
    unsigned thi = (unsigned)__builtin_amdgcn_update_dpp((int)hi, (int)hi, CTRL, RM, 0xf, false);
    ull t = ((ull)thi << 32) | tlo;
    return t < k ? t : k;
}

// lexicographic max (value desc, index asc on ties) — matches jnp.argmax
template <int CTRL, int RM>
__device__ __forceinline__ void dpp_lexmax(float& v, int& ix) {
    int tv = __builtin_amdgcn_update_dpp(__float_as_int(v), __float_as_int(v), CTRL, RM, 0xf, false);
    int ti = __builtin_amdgcn_update_dpp(ix, ix, CTRL, RM, 0xf, false);
    float fv = __int_as_float(tv);
    bool take = (fv > v) || (fv == v && ti < ix);
    v  = take ? fv : v;
    ix = take ? ti : ix;
}

// ---------------- kernels ----------------

// merged: blocks 0..63 = prep; 64..319 = W2t; 320..831 = WkvT
__global__ __launch_bounds__(256) void prep_kernel(const float* __restrict__ x,
                                                   float* __restrict__ xyz,
                                                   float4* __restrict__ xyzw,
                                                   const float* __restrict__ mu,
                                                   const float* __restrict__ sg,
                                                   float* __restrict__ slots,
                                                   float* __restrict__ asum,
                                                   const float* __restrict__ W2,
                                                   const float* __restrict__ Wk,
                                                   const float* __restrict__ Wv,
                                                   _Float16* __restrict__ W2t,
                                                   _Float16* __restrict__ WkvT,
                                                   unsigned* __restrict__ counter) {
    int t = threadIdx.x;
    if (blockIdx.x < 64) {
        int gid = blockIdx.x * 256 + t;
        int b = gid >> 12, n = gid & (NPTS - 1);
        float a0 = x[(b * 3 + 0) * NPTS + n];
        float a1 = x[(b * 3 + 1) * NPTS + n];
        float a2 = x[(b * 3 + 2) * NPTS + n];
        xyz[gid * 3 + 0] = a0; xyz[gid * 3 + 1] = a1; xyz[gid * 3 + 2] = a2;
        float sq = a0 * a0 + a1 * a1 + a2 * a2;
        xyzw[gid] = make_float4(a0, a1, a2, sq);
        if (gid < 16) asum[gid] = 0.0f;
        if (gid == 16) counter[0] = 0u;
        if (gid < 2048) {
            int j = gid;
            unsigned ks0 = 0u, ks1 = 42u, ks2 = 0u ^ 42u ^ 0x1BD11BDAu;
            unsigned x0 = (unsigned)j + ks0;
            unsigned x1 = (unsigned)(j + 2048) + ks1;
            #define RND(r) { x0 += x1; x1 = rotl32(x1, r); x1 ^= x0; }
            RND(13u) RND(15u) RND(26u) RND(6u);  x0 += ks1; x1 += ks2 + 1u;
            RND(17u) RND(29u) RND(16u) RND(24u); x0 += ks2; x1 += ks0 + 2u;
            RND(13u) RND(15u) RND(26u) RND(6u);  x0 += ks0; x1 += ks1 + 3u;
            RND(17u) RND(29u) RND(16u) RND(24u); x0 += ks1; x1 += ks2 + 4u;
            RND(13u) RND(15u) RND(26u) RND(6u);  x0 += ks2; x1 += ks0 + 5u;
            #undef RND
            int c0 = j & 255, c1 = (j + 2048) & 255;
            slots[j]        = mu[c0] + sg[c0] * bits_to_normal(x0);
            slots[j + 2048] = mu[c1] + sg[c1] * bits_to_normal(x1);
        }
    } else if (blockIdx.x < 320) {
        int nb = blockIdx.x - 64;   // 0..255
        if (t < KPAD) W2t[nb * KPAD + t] = (t < 131) ? (_Float16)W2[t * CD + nb] : (_Float16)0.0f;
    } else {
        int n = blockIdx.x - 320;   // 0..511
        float v = (n < 256) ? Wk[t * CD + n] : Wv[t * CD + (n - 256)];
        WkvT[n * CD + t] = (_Float16)v;
    }
}

// KNN: one wave per point, u64-key DPP argmin; matches lax.top_k exactly.
__global__ __launch_bounds__(256) void knn_kernel(const float4* __restrict__ xyzw,
                                                  int* __restrict__ knn_idx) {
    int wid = threadIdx.x >> 6, lane = threadIdx.x & 63;
    int pid = blockIdx.x * 4 + wid;
    int b = pid >> 12, n = pid & (NPTS - 1);
    const float4* xb = xyzw + (size_t)b * NPTS;
    float4 p = xb[n];
    unsigned d[64];
    #pragma unroll
    for (int i = 0; i < 64; ++i) {
        float4 c = xb[i * 64 + lane];
        float dot = p.x * c.x + p.y * c.y + p.z * c.z;
        d[i] = fmap(p.w + c.w - 2.0f * dot);
    }
    unsigned gv[8]; int gi[8];
    #pragma unroll
    for (int g = 0; g < 8; ++g) {
        unsigned mv = d[g * 8]; int mi = g * 8;
        #pragma unroll
        for (int j = 1; j < 8; ++j)
            if (d[g * 8 + j] < mv) { mv = d[g * 8 + j]; mi = g * 8 + j; }
        gv[g] = mv; gi[g] = mi * 64 + lane;
    }
    unsigned lv = gv[0]; int li = gi[0];
    #pragma unroll
    for (int g = 1; g < 8; ++g)
        if (gv[g] < lv) { lv = gv[g]; li = gi[g]; }

    int* out = knn_idx + (size_t)pid * KNNK;
    #pragma unroll 1
    for (int s = 0; s < KNNK; ++s) {
        ull k = ((ull)lv << 32) | (unsigned)li;
        k = dpp_min_u64<0x111, 0xf>(k);
        k = dpp_min_u64<0x112, 0xf>(k);
        k = dpp_min_u64<0x114, 0xf>(k);
        k = dpp_min_u64<0x118, 0xf>(k);
        k = dpp_min_u64<0x142, 0xa>(k);
        k = dpp_min_u64<0x143, 0xc>(k);
        int fm = __builtin_amdgcn_readlane((int)(unsigned)k, 63);
        if (lane == 0) out[s] = fm;
        int flane = fm & 63;
        int slot  = fm >> 6;
        if (lane == flane) {
            int g = slot >> 3;
            #pragma unroll
            for (int g2 = 0; g2 < 8; ++g2) {
                if (g2 == g) {
                    #pragma unroll
                    for (int j = 0; j < 8; ++j)
                        if (g2 * 8 + j == slot) d[g2 * 8 + j] = 0xFFFFFFFFu;
                    unsigned mv = d[g2 * 8]; int mi = g2 * 8;
                    #pragma unroll
                    for (int j = 1; j < 8; ++j)
                        if (d[g2 * 8 + j] < mv) { mv = d[g2 * 8 + j]; mi = g2 * 8 + j; }
                    gv[g2] = mv; gi[g2] = mi * 64 + lane;
                }
            }
            lv = gv[0]; li = gi[0];
            #pragma unroll
            for (int g2 = 1; g2 < 8; ++g2)
                if (gv[g2] < lv) { lv = gv[g2]; li = gi[g2]; }
        }
    }
}

// conv1 -> fp16 features; neighbor coords preloaded into lanes 0..31
__global__ __launch_bounds__(128) void conv1_kernel(const float* __restrict__ xyz,
                                                    const int* __restrict__ knn_idx,
                                                    const float* __restrict__ W1,
                                                    const float* __restrict__ b1,
                                                    _Float16* __restrict__ f1h) {
    int pid = blockIdx.x;
    int b = pid >> 12, n = pid & (NPTS - 1);
    int d = threadIdx.x, lane = threadIdx.x & 63;
    const float* xb = xyz + (size_t)b * NPTS * 3;
    float w0 = W1[d], wx = W1[C1D + d], wy = W1[2 * C1D + d], wz = W1[3 * C1D + d];
    float bb = b1[d];
    float px = xb[n * 3], py = xb[n * 3 + 1], pz = xb[n * 3 + 2];
    const int* idx = knn_idx + (size_t)pid * KNNK;
    float cx = 0.0f, cy = 0.0f, cz = 0.0f;
    if (lane < 32) {
        int j = idx[lane];
        cx = xb[j * 3]; cy = xb[j * 3 + 1]; cz = xb[j * 3 + 2];
    }
    float m = -1e30f;
    #pragma unroll
    for (int k = 0; k < KNNK; ++k) {
        float jx = __shfl(cx, k), jy = __shfl(cy, k), jz = __shfl(cz, k);
        float v = w0 + bb + (jx - px) * wx + (jy - py) * wy + (jz - pz) * wz;
        m = fmaxf(m, v);
    }
    f1h[(size_t)pid * C1D + d] = (_Float16)fmaxf(m, 0.0f);
}

// conv2 via MFMA f16 + fused bias/relu/max-over-k/LayerNorm -> inph fp16
__global__ __launch_bounds__(256) void conv2_mfma_kernel(const float* __restrict__ xyz,
                                                         const _Float16* __restrict__ f1h,
                                                         const int* __restrict__ knn_idx,
                                                         const _Float16* __restrict__ W2t,
                                                         const float* __restrict__ b2,
                                                         const float* __restrict__ g_in,
                                                         const float* __restrict__ b_in,
                                                         _Float16* __restrict__ inph) {
    __shared__ _Float16 A[64 * ASTR];
    __shared__ float colmax[2 * CD];
    __shared__ float red[4];
    int pid2 = blockIdx.x;
    int gp0 = pid2 * 2;
    int b = gp0 >> 12, n0 = gp0 & (NPTS - 1);
    int tid = threadIdx.x;
    const int* idx = knn_idx + (size_t)pid2 * 64;   // [2][32]
    const float* xb = xyz + (size_t)b * NPTS * 3;

    {
        int r = tid & 63, seg = tid >> 6;
        int j = idx[r];
        const uint4* s4 = (const uint4*)(f1h + ((size_t)b * NPTS + j) * C1D);
        uint4* d4 = (uint4*)&A[r * ASTR];
        #pragma unroll
        for (int i = 0; i < 4; ++i) d4[seg * 4 + i] = s4[seg * 4 + i];
        unsigned* z = (unsigned*)&A[r * ASTR + 128];
        for (int i = seg; i < 20; i += 4) z[i] = 0u;
        int np_ = (r < 32) ? n0 : (n0 + 1);
        if (seg == 0) {
            A[r * ASTR + 128] = (_Float16)(xb[j * 3 + 0] - xb[np_ * 3 + 0]);
            A[r * ASTR + 129] = (_Float16)(xb[j * 3 + 1] - xb[np_ * 3 + 1]);
        } else if (seg == 1) {
            A[r * ASTR + 130] = (_Float16)(xb[j * 3 + 2] - xb[np_ * 3 + 2]);
        }
    }
    __syncthreads();

    int w = tid >> 6, lane = tid & 63, quad = lane >> 4, lr = lane & 15;
    v4f acc[4][4];
    #pragma unroll
    for (int rt = 0; rt < 4; ++rt)
        #pragma unroll
        for (int ct = 0; ct < 4; ++ct)
            acc[rt][ct] = (v4f){0.0f, 0.0f, 0.0f, 0.0f};

    #pragma unroll
    for (int kk = 0; kk < KPAD; kk += 32) {
        v8h af[4], bf[4];
        #pragma unroll
        for (int rt = 0; rt < 4; ++rt)
            af[rt] = *(const v8h*)&A[(rt * 16 + lr) * ASTR + kk + quad * 8];
        #pragma unroll
        for (int ct = 0; ct < 4; ++ct) {
            int ncol = w * 64 + ct * 16 + lr;
            bf[ct] = *(const v8h*)(W2t + (size_t)ncol * KPAD + kk + quad * 8);
        }
        #pragma unroll
        for (int rt = 0; rt < 4; ++rt)
            #pragma unroll
            for (int ct = 0; ct < 4; ++ct)
                acc[rt][ct] = __builtin_amdgcn_mfma_f32_16x16x32_f16(af[rt], bf[ct], acc[rt][ct], 0, 0, 0);
    }

    #pragma unroll
    for (int ct = 0; ct < 4; ++ct) {
        float tm[4];
        #pragma unroll
        for (int rt = 0; rt < 4; ++rt) {
            v4f a = acc[rt][ct];
            float v = fmaxf(fmaxf(a[0], a[1]), fmaxf(a[2], a[3]));
            v = fmaxf(v, __shfl_xor(v, 16));
            v = fmaxf(v, __shfl_xor(v, 32));
            tm[rt] = v;
        }
        float p0 = fmaxf(tm[0], tm[1]);
        float p1 = fmaxf(tm[2], tm[3]);
        if (quad == 0) {
            colmax[0 * CD + w * 64 + ct * 16 + lr] = p0;
            colmax[1 * CD + w * 64 + ct * 16 + lr] = p1;
        }
    }
    __syncthreads();

    int d = tid;
    #pragma unroll
    for (int p = 0; p < 2; ++p) {
        float v = fmaxf(colmax[p * CD + d] + b2[d], 0.0f);
        float s = block_sum256(v, red);
        float mean = s * (1.0f / 256.0f);
        float s2 = block_sum256(v * v, red);
        float var = s2 * (1.0f / 256.0f) - mean * mean;
        float iv = (v - mean) * rsqrtf(var + 1e-5f) * g_in[d] + b_in[d];
        inph[(size_t)(gp0 + p) * CD + d] = (_Float16)iv;
    }
}

// kv via MFMA fp16: block = 64 points x 256 cols; half 0 -> kk, half 1 -> vv.
__global__ __launch_bounds__(256) void kv_mfma_kernel(const _Float16* __restrict__ inph,
                                                      const _Float16* __restrict__ WkvT,
                                                      float* __restrict__ kk,
                                                      float* __restrict__ vv) {
    __shared__ _Float16 A[64 * ASTR2];
    int rb = blockIdx.x >> 1, half = blockIdx.x & 1;
    int row0 = rb * 64;
    int tid = threadIdx.x;
    {
        const uint4* src4 = (const uint4*)(inph + (size_t)row0 * CD);
        #pragma unroll
        for (int i = 0; i < 8; ++i) {
            int idx = i * 256 + tid;
            int row = idx >> 5, c8 = idx & 31;
            *(uint4*)&A[row * ASTR2 + c8 * 8] = src4[idx];
        }
    }
    __syncthreads();
    int w = tid >> 6, lane = tid & 63, quad = lane >> 4, lr = lane & 15;
    v4f acc[4][4];
    #pragma unroll
    for (int rt = 0; rt < 4; ++rt)
        #pragma unroll
        for (int ct = 0; ct < 4; ++ct)
            acc[rt][ct] = (v4f){0.0f, 0.0f, 0.0f, 0.0f};
    #pragma unroll
    for (int ks = 0; ks < CD; ks += 32) {
        v8h af[4], bf[4];
        #pragma unroll
        for (int rt = 0; rt < 4; ++rt)
            af[rt] = *(const v8h*)&A[(rt * 16 + lr) * ASTR2 + ks + quad * 8];
        #pragma unroll
        for (int ct = 0; ct < 4; ++ct) {
            int ncol = half * 256 + w * 64 + ct * 16 + lr;
            bf[ct] = *(const v8h*)(WkvT + (size_t)ncol * CD + ks + quad * 8);
        }
        #pragma unroll
        for (int rt = 0; rt < 4; ++rt)
            #pragma unroll
            for (int ct = 0; ct < 4; ++ct)
                acc[rt][ct] = __builtin_amdgcn_mfma_f32_16x16x32_f16(af[rt], bf[ct], acc[rt][ct], 0, 0, 0);
    }
    float* dst = half ? vv : kk;
    #pragma unroll
    for (int rt = 0; rt < 4; ++rt)
        #pragma unroll
        for (int ct = 0; ct < 4; ++ct) {
            int col = w * 64 + ct * 16 + lr;
            #pragma unroll
            for (int r = 0; r < 4; ++r) {
                int row = rt * 16 + quad * 4 + r;
                dst[(size_t)(row0 + row) * CD + col] = acc[rt][ct][r];
            }
        }
}

// q = LN(slots) @ Wq, one block per row (b,k) — iter 0 only
__global__ __launch_bounds__(256) void slotq_kernel(const float* __restrict__ slots,
                                                    const float* __restrict__ g_sl,
                                                    const float* __restrict__ b_sl,
                                                    const float* __restrict__ Wq,
                                                    float* __restrict__ q) {
    int row = blockIdx.x;
    int d = threadIdx.x;
    __shared__ float sl[CD];
    __shared__ float red[4];
    float v = slots[row * CD + d];
    float s = block_sum256(v, red);
    float mean = s * (1.0f / 256.0f);
    float s2 = block_sum256(v * v, red);
    float var = s2 * (1.0f / 256.0f) - mean * mean;
    float ln = (v - mean) * rsqrtf(var + 1e-5f) * g_sl[d] + b_sl[d];
    sl[d] = ln;
    __syncthreads();
    float acc = 0.0f;
    const float4* sp = (const float4*)sl;
    for (int c4 = 0; c4 < 64; ++c4) {
        float4 x = sp[c4];
        int cb = c4 * 4;
        acc += x.x * Wq[cb * CD + d] + x.y * Wq[(cb + 1) * CD + d]
             + x.z * Wq[(cb + 2) * CD + d] + x.w * Wq[(cb + 3) * CD + d];
    }
    q[row * CD + d] = acc;
}

// FUSED attn+updp, 256 blocks
__global__ __launch_bounds__(256) void attn_updp_kernel(const float* __restrict__ q,
                                                        const float* __restrict__ kk,
                                                        const float* __restrict__ vv,
                                                        float* __restrict__ asum,
                                                        float* __restrict__ updp,
                                                        float* __restrict__ out_attn) {
    int b = blockIdx.x >> 6;
    int chunk = blockIdx.x & 63;
    int t = threadIdx.x;
    __shared__ float qs[4 * CD];
    __shared__ float logit[64 * 4];
    __shared__ float aw[64 * 4];
    for (int i = t; i < 4 * CD; i += 256) qs[i] = q[b * 4 * CD + i];
    __syncthreads();

    int p = t & 63, r = t >> 6;
    int n = chunk * 64 + p;
    {
        const float4* kp = (const float4*)(kk + ((size_t)b * NPTS + n) * CD);
        const float4* qr = (const float4*)(qs + r * CD);
        float a = 0.0f;
        for (int c4 = 0; c4 < 64; ++c4) {
            float4 kv = kp[c4];
            float4 x = qr[c4];
            a += kv.x * x.x + kv.y * x.y + kv.z * x.z + kv.w * x.w;
        }
        logit[p * 4 + r] = 0.0625f * a;   // 256^-0.5
    }
    __syncthreads();
    if (t < 64) {
        float l0 = logit[t * 4 + 0], l1 = logit[t * 4 + 1];
        float l2 = logit[t * 4 + 2], l3 = logit[t * 4 + 3];
        float mx = fmaxf(fmaxf(l0, l1), fmaxf(l2, l3));
        float e0 = expf(l0 - mx), e1 = expf(l1 - mx), e2 = expf(l2 - mx), e3 = expf(l3 - mx);
        float inv = 1.0f / (e0 + e1 + e2 + e3);
        e0 *= inv; e1 *= inv; e2 *= inv; e3 *= inv;
        aw[t * 4 + 0] = e0; aw[t * 4 + 1] = e1; aw[t * 4 + 2] = e2; aw[t * 4 + 3] = e3;
        if (out_attn) {
            float* o = out_attn + ((size_t)b * NPTS + chunk * 64 + t) * 4;
            o[0] = e0; o[1] = e1; o[2] = e2; o[3] = e3;
        }
        float s0 = e0, s1 = e1, s2 = e2, s3 = e3;
        #pragma unroll
        for (int o = 32; o; o >>= 1) {
            s0 += __shfl_down(s0, o); s1 += __shfl_down(s1, o);
            s2 += __shfl_down(s2, o); s3 += __shfl_down(s3, o);
        }
        if (t == 0) {
            atomicAdd(&asum[b * 4 + 0], s0);
            atomicAdd(&asum[b * 4 + 1], s1);
            atomicAdd(&asum[b * 4 + 2], s2);
            atomicAdd(&asum[b * 4 + 3], s3);
        }
    }
    __syncthreads();

    float ac0 = 0.0f, ac1 = 0.0f, ac2 = 0.0f, ac3 = 0.0f;
    const float* vb = vv + ((size_t)b * NPTS + chunk * 64) * CD;
    for (int nn2 = 0; nn2 < 64; ++nn2) {
        float v = vb[(size_t)nn2 * CD + t];
        float4 w4 = *(const float4*)&aw[nn2 * 4];
        ac0 += w4.x * v; ac1 += w4.y * v; ac2 += w4.z * v; ac3 += w4.w * v;
    }
    updp[((size_t)(b * 4 + 0) * 64 + chunk) * CD + t] = ac0;
    updp[((size_t)(b * 4 + 1) * 64 + chunk) * CD + t] = ac1;
    updp[((size_t)(b * 4 + 2) * 64 + chunk) * CD + t] = ac2;
    updp[((size_t)(b * 4 + 3) * 64 + chunk) * CD + t] = ac3;
}

// GRU gates, 96 blocks: (row, gate, c-half).
__global__ __launch_bounds__(256) void gru_gates_kernel(const float* __restrict__ updp,
                                                        const float* __restrict__ asum,
                                                        const float* __restrict__ slots,
                                                        const float* __restrict__ W_ih,
                                                        const float* __restrict__ W_hh,
                                                        const float* __restrict__ b_ih,
                                                        const float* __restrict__ b_hh,
                                                        float* __restrict__ gi,
                                                        float* __restrict__ gh) {
    int idx = blockIdx.x;
    int row = idx / 6, rem = idx % 6;
    int gate = rem >> 1, half = rem & 1;
    int d = threadIdx.x;
    __shared__ float su[CD], sp[CD];
    float f = 1.0f / (asum[row] + 1e-8f);
    float u = 0.0f;
    for (int p = 0; p < 64; ++p) u += updp[((size_t)row * 64 + p) * CD + d];
    u *= f;
    su[d] = u; sp[d] = slots[row * CD + d];
    __syncthreads();
    float acc_i = half ? 0.0f : b_ih[gate * CD + d];
    float acc_h = half ? 0.0f : b_hh[gate * CD + d];
    const float* wi = W_ih + gate * CD + d;
    const float* wh = W_hh + gate * CD + d;
    int c0 = half * 128;
    for (int c = c0; c < c0 + 128; ++c) {
        acc_i += su[c] * wi[c * 3 * CD];
        acc_h += sp[c] * wh[c * 3 * CD];
    }
    gi[((size_t)(row * 3 + gate) * 2 + half) * CD + d] = acc_i;
    gh[((size_t)(row * 3 + gate) * 2 + half) * CD + d] = acc_h;
}

// GRU update + LN_ff + MLP residual + (optional) NEXT-ITER slotq, one block/row
__global__ __launch_bounds__(256) void gru_mlp_kernel(const float* __restrict__ gi,
                                                      const float* __restrict__ gh,
                                                      float* __restrict__ slots,
                                                      const float* __restrict__ g_ff,
                                                      const float* __restrict__ b_ff,
                                                      const float* __restrict__ Wm1,
                                                      const float* __restrict__ bm1,
                                                      const float* __restrict__ Wm2,
                                                      const float* __restrict__ bm2,
                                                      float* __restrict__ asum,
                                                      const float* __restrict__ g_sl,
                                                      const float* __restrict__ b_sl,
                                                      const float* __restrict__ Wq,
                                                      float* __restrict__ qv) {
    int row = blockIdx.x;
    int d = threadIdx.x;
    __shared__ float sh[CD];
    __shared__ float red[4];
    float prev = slots[row * CD + d];
    float gir = gi[((size_t)(row * 3 + 0) * 2 + 0) * CD + d] + gi[((size_t)(row * 3 + 0) * 2 + 1) * CD + d];
    float giz = gi[((size_t)(row * 3 + 1) * 2 + 0) * CD + d] + gi[((size_t)(row * 3 + 1) * 2 + 1) * CD + d];
    float gin = gi[((size_t)(row * 3 + 2) * 2 + 0) * CD + d] + gi[((size_t)(row * 3 + 2) * 2 + 1) * CD + d];
    float ghr = gh[((size_t)(row * 3 + 0) * 2 + 0) * CD + d] + gh[((size_t)(row * 3 + 0) * 2 + 1) * CD + d];
    float ghz = gh[((size_t)(row * 3 + 1) * 2 + 0) * CD + d] + gh[((size_t)(row * 3 + 1) * 2 + 1) * CD + d];
    float ghn = gh[((size_t)(row * 3 + 2) * 2 + 0) * CD + d] + gh[((size_t)(row * 3 + 2) * 2 + 1) * CD + d];
    if (d == 0) asum[row] = 0.0f;
    float r = 1.0f / (1.0f + expf(-(gir + ghr)));
    float z = 1.0f / (1.0f + expf(-(giz + ghz)));
    float nn = tanhf(gin + r * ghn);
    float sNew = (1.0f - z) * nn + z * prev;
    float s = block_sum256(sNew, red);
    float mean = s * (1.0f / 256.0f);
    float s2 = block_sum256(sNew * sNew, red);
    float var = s2 * (1.0f / 256.0f) - mean * mean;
    float h = (sNew - mean) * rsqrtf(var + 1e-5f) * g_ff[d] + b_ff[d];
    __syncthreads();
    sh[d] = h;
    __syncthreads();
    float y = bm1[d];
    {
        const float4* hp = (const float4*)sh;
        for (int c4 = 0; c4 < 64; ++c4) {
            float4 x = hp[c4];
            int cb = c4 * 4;
            y += x.x * Wm1[cb * CD + d] + x.y * Wm1[(cb + 1) * CD + d]
               + x.z * Wm1[(cb + 2) * CD + d] + x.w * Wm1[(cb + 3) * CD + d];
        }
    }
    y = fmaxf(y, 0.0f);
    __syncthreads();
    sh[d] = y;
    __syncthreads();
    float o = bm2[d];
    {
        const float4* hp = (const float4*)sh;
        for (int c4 = 0; c4 < 64; ++c4) {
            float4 x = hp[c4];
            int cb = c4 * 4;
            o += x.x * Wm2[cb * CD + d] + x.y * Wm2[(cb + 1) * CD + d]
               + x.z * Wm2[(cb + 2) * CD + d] + x.w * Wm2[(cb + 3) * CD + d];
        }
    }
    float fin = sNew + o;
    slots[row * CD + d] = fin;
    if (qv) {
        float v = fin;
        float s3 = block_sum256(v, red);
        float mean2 = s3 * (1.0f / 256.0f);
        float s4 = block_sum256(v * v, red);
        float var2 = s4 * (1.0f / 256.0f) - mean2 * mean2;
        float ln = (v - mean2) * rsqrtf(var2 + 1e-5f) * g_sl[d] + b_sl[d];
        __syncthreads();
        sh[d] = ln;
        __syncthreads();
        float acc = 0.0f;
        const float4* sp = (const float4*)sh;
        for (int c4 = 0; c4 < 64; ++c4) {
            float4 x = sp[c4];
            int cb = c4 * 4;
            acc += x.x * Wq[cb * CD + d] + x.y * Wq[(cb + 1) * CD + d]
                 + x.z * Wq[(cb + 2) * CD + d] + x.w * Wq[(cb + 3) * CD + d];
        }
        qv[row * CD + d] = acc;
    }
}

// recon linear+BN+relu layer, column-parallel: 16 blocks x 16 cols.
// Thread = (col in 0..15, row in 0..15). Accumulation order identical to the
// original (c4 ascending, 4-term expression); BN mean/var over rows ascending.
__global__ __launch_bounds__(256) void recon_layer_kernel(const float* __restrict__ in,
                                                          const float* __restrict__ W,
                                                          const float* __restrict__ bias,
                                                          const float* __restrict__ g,
                                                          const float* __restrict__ be,
                                                          float* __restrict__ outb) {
    __shared__ float sin[16 * CD];
    __shared__ float tb[16 * 16];   // tb[row*16+col]
    int t = threadIdx.x;
    for (int i = t; i < 16 * CD; i += 256) sin[i] = in[i];
    __syncthreads();
    int col = t & 15, row = t >> 4;
    int colg = blockIdx.x * 16 + col;
    float acc = bias[colg];
    for (int c4 = 0; c4 < 64; ++c4) {
        int cb = c4 * 4;
        float w0 = W[cb * CD + colg], w1 = W[(cb + 1) * CD + colg];
        float w2 = W[(cb + 2) * CD + colg], w3 = W[(cb + 3) * CD + colg];
        float4 x = *(const float4*)(sin + row * CD + cb);
        acc += x.x * w0 + x.y * w1 + x.z * w2 + x.w * w3;
    }
    tb[row * 16 + col] = acc;
    __syncthreads();
    float mean = 0.0f;
    for (int r = 0; r < 16; ++r) mean += tb[r * 16 + col];
    mean *= (1.0f / 16.0f);
    float var = 0.0f;
    for (int r = 0; r < 16; ++r) { float dd = tb[r * 16 + col] - mean; var += dd * dd; }
    var *= (1.0f / 16.0f);
    float inv = rsqrtf(var + 1e-5f);
    outb[row * CD + colg] = fmaxf(0.0f, (acc - mean) * inv * g[colg] + be[colg]);
}

// final recon layer (no BN) + in-kernel FPS, 4 blocks (one per batch)
__global__ __launch_bounds__(320) void recon3_fps_kernel(const float* __restrict__ h2g,
                                                         const float* __restrict__ Wr3,
                                                         const float* __restrict__ br3,
                                                         float* __restrict__ spts,
                                                         int* __restrict__ fidx,
                                                         float* __restrict__ lacc,
                                                         unsigned* __restrict__ mnbuf) {
    __shared__ float h2[16 * CD];
    __shared__ float sp[384 * 3];
    int b = blockIdx.x;
    int d = threadIdx.x;
    for (int i = d; i < 16 * CD; i += 320) h2[i] = h2g[i];
    __syncthreads();
    if (d < 288) {
        float t4[4];
        #pragma unroll
        for (int rl = 0; rl < 4; ++rl) t4[rl] = br3[d];
        for (int c4 = 0; c4 < 64; ++c4) {
            int cb = c4 * 4;
            float w0 = Wr3[cb * 288 + d], w1 = Wr3[(cb + 1) * 288 + d];
            float w2 = Wr3[(cb + 2) * 288 + d], w3 = Wr3[(cb + 3) * 288 + d];
            #pragma unroll
            for (int rl = 0; rl < 4; ++rl) {
                float4 x = *(const float4*)(h2 + (b * 4 + rl) * CD + cb);
                t4[rl] += x.x * w0 + x.y * w1 + x.z * w2 + x.w * w3;
            }
        }
        #pragma unroll
        for (int rl = 0; rl < 4; ++rl) {
            spts[(b * 4 + rl) * 288 + d] = t4[rl];
            sp[rl * 288 + d] = t4[rl];
        }
    }
    __syncthreads();

    if (d < 64) {
        int lane = d;
        int* out = fidx + b * 128;
        if (lane == 0) out[0] = 0;
        if (b == 0 && lane == 0) lacc[0] = 0.0f;
        mnbuf[b * 128 + lane] = 0x7F800000u;
        mnbuf[b * 128 + 64 + lane] = 0x7F800000u;
        float px[6], py[6], pz[6], dd[6];
        #pragma unroll
        for (int i = 0; i < 6; ++i) {
            int m = i * 64 + lane;
            px[i] = sp[m * 3]; py[i] = sp[m * 3 + 1]; pz[i] = sp[m * 3 + 2];
            dd[i] = 1e10f;
        }
        float lx = sp[0], ly = sp[1], lz = sp[2];
        #pragma unroll 1
        for (int s = 1; s < 128; ++s) {
            #pragma unroll
            for (int i = 0; i < 6; ++i) {
                float dx = px[i] - lx, dy = py[i] - ly, dz = pz[i] - lz;
                dd[i] = fminf(dd[i], dx * dx + dy * dy + dz * dz);
            }
            float bv = dd[0]; int bi = lane;
            #pragma unroll
            for (int i = 1; i < 6; ++i)
                if (dd[i] > bv) { bv = dd[i]; bi = i * 64 + lane; }
            dpp_lexmax<0x111, 0xf>(bv, bi);
            dpp_lexmax<0x112, 0xf>(bv, bi);
            dpp_lexmax<0x114, 0xf>(bv, bi);
            dpp_lexmax<0x118, 0xf>(bv, bi);
            dpp_lexmax<0x142, 0xa>(bv, bi);
            dpp_lexmax<0x143, 0xc>(bv, bi);
            int fm = __builtin_amdgcn_readlane(bi, 63);
            if (lane == 0) out[s] = fm;
            int slot = fm >> 6, sl_lane = fm & 63;
            float sx = px[0], sy = py[0], sz = pz[0];
            #pragma unroll
            for (int i = 1; i < 6; ++i)
                if (slot == i) { sx = px[i]; sy = py[i]; sz = pz[i]; }
            lx = __int_as_float(__builtin_amdgcn_readlane(__float_as_int(sx), sl_lane));
            ly = __int_as_float(__builtin_amdgcn_readlane(__float_as_int(sy), sl_lane));
            lz = __int_as_float(__builtin_amdgcn_readlane(__float_as_int(sz), sl_lane));
        }
    }
}

// merged chamfer: blocks 0..63 = sum2, 64..127 = min1; last block writes loss
__global__ __launch_bounds__(256) void chamfer_kernel(const float* __restrict__ spts,
                                                      const int* __restrict__ fidx,
                                                      const float* __restrict__ xyz,
                                                      float* __restrict__ lacc,
                                                      unsigned* __restrict__ mnbuf,
                                                      unsigned* __restrict__ counter,
                                                      float* __restrict__ out) {
    int t = threadIdx.x;
    __shared__ float ds[128 * 3];
    __shared__ float tile[256 * 3];
    __shared__ float red[4];
    __shared__ unsigned done;
    if (blockIdx.x < 64) {
        int b = blockIdx.x >> 4, chunk = blockIdx.x & 15;
        const float* pts = spts + (size_t)b * 384 * 3;
        if (t < 128) {
            int j = fidx[b * 128 + t];
            ds[t * 3] = pts[j * 3]; ds[t * 3 + 1] = pts[j * 3 + 1]; ds[t * 3 + 2] = pts[j * 3 + 2];
        }
        __syncthreads();
        int n = chunk * 256 + t;
        const float* xb = xyz + (size_t)b * NPTS * 3;
        float px = xb[n * 3], py = xb[n * 3 + 1], pz = xb[n * 3 + 2];
        float mn = 1e30f;
        #pragma unroll 4
        for (int jj = 0; jj < 128; ++jj) {
            float dx = ds[jj * 3] - px, dy = ds[jj * 3 + 1] - py, dz = ds[jj * 3 + 2] - pz;
            mn = fminf(mn, dx * dx + dy * dy + dz * dz);
        }
        float total = block_sum256(mn * (1.0f / 4096.0f), red);
        if (t == 0) atomicAdd(lacc, total);
    } else {
        int bid = blockIdx.x - 64;
        int b = bid >> 4, chunk = bid & 15;
        const float* xb = xyz + ((size_t)b * NPTS + chunk * 256) * 3;
        for (int i = t; i < 768; i += 256) tile[i] = xb[i];
        __syncthreads();
        if (t < 128) {
            int j = fidx[b * 128 + t];
            const float* pts = spts + (size_t)b * 384 * 3;
            float px = pts[j * 3], py = pts[j * 3 + 1], pz = pts[j * 3 + 2];
            float mn = 1e30f;
            #pragma unroll 4
            for (int i = 0; i < 256; ++i) {
                float dx = tile[i * 3] - px, dy = tile[i * 3 + 1] - py, dz = tile[i * 3 + 2] - pz;
                mn = fminf(mn, dx * dx + dy * dy + dz * dz);
            }
            atomicMin(&mnbuf[b * 128 + t], __float_as_uint(mn));
        }
    }
    __threadfence();
    __syncthreads();
    if (t == 0) done = atomicAdd(counter, 1u);
    __syncthreads();
    if (done == 127u) {
        unsigned a0 = atomicAdd(&mnbuf[t], 0u);
        unsigned a1 = atomicAdd(&mnbuf[t + 256], 0u);
        float v = (__uint_as_float(a0) + __uint_as_float(a1)) * (1.0f / 128.0f);
        __syncthreads();
        float tot = block_sum256(v, red);
        if (t == 0) {
            float l = atomicAdd(lacc, 0.0f);
            out[0] = (l + tot) * 0.25f;
        }
    }
}

// ---------------- launch ----------------

extern "C" void kernel_launch(void* const* d_in, const int* in_sizes, int n_in,
                              void* d_out, int out_size, void* d_ws, size_t ws_size,
                              hipStream_t stream) {
    (void)in_sizes; (void)n_in; (void)out_size; (void)ws_size;
    const float* x    = (const float*)d_in[0];
    const float* W1   = (const float*)d_in[2];
    const float* b1   = (const float*)d_in[3];
    const float* W2   = (const float*)d_in[4];
    const float* b2   = (const float*)d_in[5];
    const float* mu   = (const float*)d_in[6];
    const float* sg   = (const float*)d_in[7];
    const float* g_in = (const float*)d_in[8];
    const float* b_in = (const float*)d_in[9];
    const float* g_sl = (const float*)d_in[10];
    const float* b_sl = (const float*)d_in[11];
    const float* g_ff = (const float*)d_in[12];
    const float* b_ff = (const float*)d_in[13];
    const float* Wq   = (const float*)d_in[14];
    const float* Wk   = (const float*)d_in[15];
    const float* Wv   = (const float*)d_in[16];
    const float* W_ih = (const float*)d_in[17];
    const float* W_hh = (const float*)d_in[18];
    const float* b_ih = (const float*)d_in[19];
    const float* b_hh = (const float*)d_in[20];
    const float* Wm1  = (const float*)d_in[21];
    const float* bm1  = (const float*)d_in[22];
    const float* Wm2  = (const float*)d_in[23];
    const float* bm2  = (const float*)d_in[24];
    const float* Wr1  = (const float*)d_in[25];
    const float* br1  = (const float*)d_in[26];
    const float* g1   = (const float*)d_in[27];
    const float* be1  = (const float*)d_in[28];
    const float* Wr2  = (const float*)d_in[29];
    const float* br2  = (const float*)d_in[30];
    const float* g2   = (const float*)d_in[31];
    const float* be2  = (const float*)d_in[32];
    const float* Wr3  = (const float*)d_in[33];
    const float* br3  = (const float*)d_in[34];

    float* ws    = (float*)d_ws;
    float* xyz   = ws;                               // 49152 f
    float* xyzw  = xyz + 49152;                      // 65536 f
    int*   knn   = (int*)(xyzw + 65536);             // 524288 i
    _Float16* f1h = (_Float16*)(knn + 524288);       // -> 1048576 f
    _Float16* W2t = (_Float16*)((float*)f1h + 1048576);  // -> 20480 f
    _Float16* WkvT = (_Float16*)((float*)W2t + 20480);   // -> 65536 f
    _Float16* inph = (_Float16*)((float*)WkvT + 65536);  // -> 2097152 f
    float* kkb   = (float*)inph + 2097152;           // 4194304 f
    float* vvb   = kkb + 4194304;                    // 4194304 f
    float* slots = vvb + 4194304;                    // 4096 f
    float* qb    = slots + 4096;                     // 4096 f
    float* asum  = qb + 4096;                        // 16 f
    float* updp  = asum + 16;                        // 262144 f
    float* gi    = updp + 262144;                    // 24576 f
    float* gh    = gi + 24576;                       // 24576 f
    float* h1g   = gh + 24576;                       // 4096 f
    float* h2g   = h1g + 4096;                       // 4096 f
    float* spts  = h2g + 4096;                       // 4608 f
    int*   fidx  = (int*)(spts + 4608);              // 512 i
    float* lacc  = (float*)(fidx + 512);             // 1 f
    unsigned* mnbuf = (unsigned*)(lacc + 1);         // 512 u
    unsigned* counter = mnbuf + 512;                 // 1 u

    float* out = (float*)d_out;

    prep_kernel<<<832, 256, 0, stream>>>(x, xyz, (float4*)xyzw, mu, sg, slots, asum,
                                         W2, Wk, Wv, W2t, WkvT, counter);
    knn_kernel<<<NBATCH * NPTS / 4, 256, 0, stream>>>((const float4*)xyzw, knn);
    conv1_kernel<<<NBATCH * NPTS, 128, 0, stream>>>(xyz, knn, W1, b1, f1h);
    conv2_mfma_kernel<<<NBATCH * NPTS / 2, 256, 0, stream>>>(xyz, f1h, knn, W2t, b2, g_in, b_in, inph);
    kv_mfma_kernel<<<NBATCH * NPTS / 64 * 2, 256, 0, stream>>>(inph, WkvT, kkb, vvb);

    slotq_kernel<<<16, 256, 0, stream>>>(slots, g_sl, b_sl, Wq, qb);
    for (int it = 0; it < 3; ++it) {
        attn_updp_kernel<<<256, 256, 0, stream>>>(qb, kkb, vvb, asum, updp,
                                                  (it == 2) ? (out + 1) : (float*)nullptr);
        gru_gates_kernel<<<96, 256, 0, stream>>>(updp, asum, slots, W_ih, W_hh, b_ih, b_hh, gi, gh);
        gru_mlp_kernel<<<16, 256, 0, stream>>>(gi, gh, slots, g_ff, b_ff, Wm1, bm1, Wm2, bm2, asum,
                                               g_sl, b_sl, Wq, (it < 2) ? qb : (float*)nullptr);
    }

    recon_layer_kernel<<<16, 256, 0, stream>>>(slots, Wr1, br1, g1, be1, h1g);
    recon_layer_kernel<<<16, 256, 0, stream>>>(h1g, Wr2, br2, g2, be2, h2g);
    recon3_fps_kernel<<<4, 320, 0, stream>>>(h2g, Wr3, br3, spts, fidx, lacc, mnbuf);
    chamfer_kernel<<<128, 256, 0, stream>>>(spts, fidx, xyz, lacc, mnbuf, counter, out);
}

// Round 16
// 669.873 us; speedup vs baseline: 1.1736x; 1.0129x over previous
//
#include <hip/hip_runtime.h>

#define NBATCH 4
#define NPTS   4096
#define KNNK   32
#define C1D    128
#define CD     256
#define KPAD   160   // conv2 K padded (131 -> 160, 5 mfma K-steps of 32)
#define ASTR   168   // conv2 LDS A row stride in halves
#define ASTR2  264   // kv LDS A row stride in halves (256 cols + 8 pad)

typedef _Float16 v8h __attribute__((ext_vector_type(8)));
typedef float    v4f __attribute__((ext_vector_type(4)));
typedef unsigned long long ull;

// ---------------- helpers ----------------

__device__ __forceinline__ float block_sum256(float v, float* red) {
    #pragma unroll
    for (int o = 32; o; o >>= 1) v += __shfl_down(v, o);
    __syncthreads();
    if ((threadIdx.x & 63) == 0) red[threadIdx.x >> 6] = v;
    __syncthreads();
    return red[0] + red[1] + red[2] + red[3];
}

__device__ __forceinline__ unsigned rotl32(unsigned x, unsigned r) {
    return (x << r) | (x >> (32u - r));
}

// XLA f32 erf_inv (Giles polynomial)
__device__ float erfinv_f(float x) {
    float w = -log1pf(-x * x);
    float p;
    if (w < 5.0f) {
        w -= 2.5f;
        p = 2.81022636e-08f;
        p = fmaf(p, w, 3.43273939e-07f);
        p = fmaf(p, w, -3.5233877e-06f);
        p = fmaf(p, w, -4.39150654e-06f);
        p = fmaf(p, w, 0.00021858087f);
        p = fmaf(p, w, -0.00125372503f);
        p = fmaf(p, w, -0.00417768164f);
        p = fmaf(p, w, 0.246640727f);
        p = fmaf(p, w, 1.50140941f);
    } else {
        w = sqrtf(w) - 3.0f;
        p = -0.000200214257f;
        p = fmaf(p, w, 0.000100950558f);
        p = fmaf(p, w, 0.00134934322f);
        p = fmaf(p, w, -0.00367342844f);
        p = fmaf(p, w, 0.00573950773f);
        p = fmaf(p, w, -0.0076224613f);
        p = fmaf(p, w, 0.00943887047f);
        p = fmaf(p, w, 1.00167406f);
        p = fmaf(p, w, 2.83297682f);
    }
    return p * x;
}

__device__ __forceinline__ float bits_to_normal(unsigned bits) {
    unsigned fb = (bits >> 9) | 0x3f800000u;
    float f = __uint_as_float(fb) - 1.0f;
    const float lo = -0.99999994f;           // nextafterf(-1,0)
    float u = fmaf(f, 2.0f, lo);
    u = fmaxf(u, lo);
    return 1.41421356237f * erfinv_f(u);
}

// order-preserving float->uint map
__device__ __forceinline__ unsigned fmap(float f) {
    unsigned b = __float_as_uint(f);
    return (b & 0x80000000u) ? ~b : (b | 0x80000000u);
}

// one DPP level of u64-key min
template <int CTRL, int RM>
__device__ __forceinline__ ull dpp_min_u64(ull k) {
    unsigned lo = (unsigned)k, hi = (unsigned)(k >> 32);
    unsigned tlo = (unsigned)__builtin_amdgcn_update_dpp((int)lo, (int)lo, CTRL, RM, 0xf, false);
    unsigned thi = (unsigned)__builtin_amdgcn_update_dpp((int)hi, (int)hi, CTRL, RM, 0xf, false);
    ull t = ((ull)thi << 32) | tlo;
    return t < k ? t : k;
}

// lexicographic max (value desc, index asc on ties) — matches jnp.argmax
template <int CTRL, int RM>
__device__ __forceinline__ void dpp_lexmax(float& v, int& ix) {
    int tv = __builtin_amdgcn_update_dpp(__float_as_int(v), __float_as_int(v), CTRL, RM, 0xf, false);
    int ti = __builtin_amdgcn_update_dpp(ix, ix, CTRL, RM, 0xf, false);
    float fv = __int_as_float(tv);
    bool take = (fv > v) || (fv == v && ti < ix);
    v  = take ? fv : v;
    ix = take ? ti : ix;
}

// ---------------- kernels ----------------

// merged: blocks 0..63 = prep; 64..319 = W2t; 320..831 = WkvT
__global__ __launch_bounds__(256) void prep_kernel(const float* __restrict__ x,
                                                   float* __restrict__ xyz,
                                                   float4* __restrict__ xyzw,
                                                   const float* __restrict__ mu,
                                                   const float* __restrict__ sg,
                                                   float* __restrict__ slots,
                                                   float* __restrict__ asum,
                                                   const float* __restrict__ W2,
                                                   const float* __restrict__ Wk,
                                                   const float* __restrict__ Wv,
                                                   _Float16* __restrict__ W2t,
                                                   _Float16* __restrict__ WkvT,
                                                   unsigned* __restrict__ counter) {
    int t = threadIdx.x;
    if (blockIdx.x < 64) {
        int gid = blockIdx.x * 256 + t;
        int b = gid >> 12, n = gid & (NPTS - 1);
        float a0 = x[(b * 3 + 0) * NPTS + n];
        float a1 = x[(b * 3 + 1) * NPTS + n];
        float a2 = x[(b * 3 + 2) * NPTS + n];
        xyz[gid * 3 + 0] = a0; xyz[gid * 3 + 1] = a1; xyz[gid * 3 + 2] = a2;
        float sq = a0 * a0 + a1 * a1 + a2 * a2;
        xyzw[gid] = make_float4(a0, a1, a2, sq);
        if (gid < 16) asum[gid] = 0.0f;
        if (gid == 16) counter[0] = 0u;
        if (gid < 2048) {
            int j = gid;
            unsigned ks0 = 0u, ks1 = 42u, ks2 = 0u ^ 42u ^ 0x1BD11BDAu;
            unsigned x0 = (unsigned)j + ks0;
            unsigned x1 = (unsigned)(j + 2048) + ks1;
            #define RND(r) { x0 += x1; x1 = rotl32(x1, r); x1 ^= x0; }
            RND(13u) RND(15u) RND(26u) RND(6u);  x0 += ks1; x1 += ks2 + 1u;
            RND(17u) RND(29u) RND(16u) RND(24u); x0 += ks2; x1 += ks0 + 2u;
            RND(13u) RND(15u) RND(26u) RND(6u);  x0 += ks0; x1 += ks1 + 3u;
            RND(17u) RND(29u) RND(16u) RND(24u); x0 += ks1; x1 += ks2 + 4u;
            RND(13u) RND(15u) RND(26u) RND(6u);  x0 += ks2; x1 += ks0 + 5u;
            #undef RND
            int c0 = j & 255, c1 = (j + 2048) & 255;
            slots[j]        = mu[c0] + sg[c0] * bits_to_normal(x0);
            slots[j + 2048] = mu[c1] + sg[c1] * bits_to_normal(x1);
        }
    } else if (blockIdx.x < 320) {
        int nb = blockIdx.x - 64;   // 0..255
        if (t < KPAD) W2t[nb * KPAD + t] = (t < 131) ? (_Float16)W2[t * CD + nb] : (_Float16)0.0f;
    } else {
        int n = blockIdx.x - 320;   // 0..511
        float v = (n < 256) ? Wk[t * CD + n] : Wv[t * CD + (n - 256)];
        WkvT[n * CD + t] = (_Float16)v;
    }
}

// KNN: one wave per point, u64-key DPP argmin; matches lax.top_k exactly.
__global__ __launch_bounds__(256) void knn_kernel(const float4* __restrict__ xyzw,
                                                  int* __restrict__ knn_idx) {
    int wid = threadIdx.x >> 6, lane = threadIdx.x & 63;
    int pid = blockIdx.x * 4 + wid;
    int b = pid >> 12, n = pid & (NPTS - 1);
    const float4* xb = xyzw + (size_t)b * NPTS;
    float4 p = xb[n];
    unsigned d[64];
    #pragma unroll
    for (int i = 0; i < 64; ++i) {
        float4 c = xb[i * 64 + lane];
        float dot = p.x * c.x + p.y * c.y + p.z * c.z;
        d[i] = fmap(p.w + c.w - 2.0f * dot);
    }
    unsigned gv[8]; int gi[8];
    #pragma unroll
    for (int g = 0; g < 8; ++g) {
        unsigned mv = d[g * 8]; int mi = g * 8;
        #pragma unroll
        for (int j = 1; j < 8; ++j)
            if (d[g * 8 + j] < mv) { mv = d[g * 8 + j]; mi = g * 8 + j; }
        gv[g] = mv; gi[g] = mi * 64 + lane;
    }
    unsigned lv = gv[0]; int li = gi[0];
    #pragma unroll
    for (int g = 1; g < 8; ++g)
        if (gv[g] < lv) { lv = gv[g]; li = gi[g]; }

    int* out = knn_idx + (size_t)pid * KNNK;
    #pragma unroll 1
    for (int s = 0; s < KNNK; ++s) {
        ull k = ((ull)lv << 32) | (unsigned)li;
        k = dpp_min_u64<0x111, 0xf>(k);
        k = dpp_min_u64<0x112, 0xf>(k);
        k = dpp_min_u64<0x114, 0xf>(k);
        k = dpp_min_u64<0x118, 0xf>(k);
        k = dpp_min_u64<0x142, 0xa>(k);
        k = dpp_min_u64<0x143, 0xc>(k);
        int fm = __builtin_amdgcn_readlane((int)(unsigned)k, 63);
        if (lane == 0) out[s] = fm;
        int flane = fm & 63;
        int slot  = fm >> 6;
        if (lane == flane) {
            int g = slot >> 3;
            #pragma unroll
            for (int g2 = 0; g2 < 8; ++g2) {
                if (g2 == g) {
                    #pragma unroll
                    for (int j = 0; j < 8; ++j)
                        if (g2 * 8 + j == slot) d[g2 * 8 + j] = 0xFFFFFFFFu;
                    unsigned mv = d[g2 * 8]; int mi = g2 * 8;
                    #pragma unroll
                    for (int j = 1; j < 8; ++j)
                        if (d[g2 * 8 + j] < mv) { mv = d[g2 * 8 + j]; mi = g2 * 8 + j; }
                    gv[g2] = mv; gi[g2] = mi * 64 + lane;
                }
            }
            lv = gv[0]; li = gi[0];
            #pragma unroll
            for (int g2 = 1; g2 < 8; ++g2)
                if (gv[g2] < lv) { lv = gv[g2]; li = gi[g2]; }
        }
    }
}

// conv1 -> fp16 features; neighbor coords preloaded into lanes 0..31
__global__ __launch_bounds__(128) void conv1_kernel(const float* __restrict__ xyz,
                                                    const int* __restrict__ knn_idx,
                                                    const float* __restrict__ W1,
                                                    const float* __restrict__ b1,
                                                    _Float16* __restrict__ f1h) {
    int pid = blockIdx.x;
    int b = pid >> 12, n = pid & (NPTS - 1);
    int d = threadIdx.x, lane = threadIdx.x & 63;
    const float* xb = xyz + (size_t)b * NPTS * 3;
    float w0 = W1[d], wx = W1[C1D + d], wy = W1[2 * C1D + d], wz = W1[3 * C1D + d];
    float bb = b1[d];
    float px = xb[n * 3], py = xb[n * 3 + 1], pz = xb[n * 3 + 2];
    const int* idx = knn_idx + (size_t)pid * KNNK;
    float cx = 0.0f, cy = 0.0f, cz = 0.0f;
    if (lane < 32) {
        int j = idx[lane];
        cx = xb[j * 3]; cy = xb[j * 3 + 1]; cz = xb[j * 3 + 2];
    }
    float m = -1e30f;
    #pragma unroll
    for (int k = 0; k < KNNK; ++k) {
        float jx = __shfl(cx, k), jy = __shfl(cy, k), jz = __shfl(cz, k);
        float v = w0 + bb + (jx - px) * wx + (jy - py) * wy + (jz - pz) * wz;
        m = fmaxf(m, v);
    }
    f1h[(size_t)pid * C1D + d] = (_Float16)fmaxf(m, 0.0f);
}

// conv2 via MFMA f16 + fused bias/relu/max-over-k/LayerNorm -> inph fp16
__global__ __launch_bounds__(256) void conv2_mfma_kernel(const float* __restrict__ xyz,
                                                         const _Float16* __restrict__ f1h,
                                                         const int* __restrict__ knn_idx,
                                                         const _Float16* __restrict__ W2t,
                                                         const float* __restrict__ b2,
                                                         const float* __restrict__ g_in,
                                                         const float* __restrict__ b_in,
                                                         _Float16* __restrict__ inph) {
    __shared__ _Float16 A[64 * ASTR];
    __shared__ float colmax[2 * CD];
    __shared__ float red[4];
    int pid2 = blockIdx.x;
    int gp0 = pid2 * 2;
    int b = gp0 >> 12, n0 = gp0 & (NPTS - 1);
    int tid = threadIdx.x;
    const int* idx = knn_idx + (size_t)pid2 * 64;   // [2][32]
    const float* xb = xyz + (size_t)b * NPTS * 3;

    {
        int r = tid & 63, seg = tid >> 6;
        int j = idx[r];
        const uint4* s4 = (const uint4*)(f1h + ((size_t)b * NPTS + j) * C1D);
        uint4* d4 = (uint4*)&A[r * ASTR];
        #pragma unroll
        for (int i = 0; i < 4; ++i) d4[seg * 4 + i] = s4[seg * 4 + i];
        unsigned* z = (unsigned*)&A[r * ASTR + 128];
        for (int i = seg; i < 20; i += 4) z[i] = 0u;
        int np_ = (r < 32) ? n0 : (n0 + 1);
        if (seg == 0) {
            A[r * ASTR + 128] = (_Float16)(xb[j * 3 + 0] - xb[np_ * 3 + 0]);
            A[r * ASTR + 129] = (_Float16)(xb[j * 3 + 1] - xb[np_ * 3 + 1]);
        } else if (seg == 1) {
            A[r * ASTR + 130] = (_Float16)(xb[j * 3 + 2] - xb[np_ * 3 + 2]);
        }
    }
    __syncthreads();

    int w = tid >> 6, lane = tid & 63, quad = lane >> 4, lr = lane & 15;
    v4f acc[4][4];
    #pragma unroll
    for (int rt = 0; rt < 4; ++rt)
        #pragma unroll
        for (int ct = 0; ct < 4; ++ct)
            acc[rt][ct] = (v4f){0.0f, 0.0f, 0.0f, 0.0f};

    #pragma unroll
    for (int kk = 0; kk < KPAD; kk += 32) {
        v8h af[4], bf[4];
        #pragma unroll
        for (int rt = 0; rt < 4; ++rt)
            af[rt] = *(const v8h*)&A[(rt * 16 + lr) * ASTR + kk + quad * 8];
        #pragma unroll
        for (int ct = 0; ct < 4; ++ct) {
            int ncol = w * 64 + ct * 16 + lr;
            bf[ct] = *(const v8h*)(W2t + (size_t)ncol * KPAD + kk + quad * 8);
        }
        #pragma unroll
        for (int rt = 0; rt < 4; ++rt)
            #pragma unroll
            for (int ct = 0; ct < 4; ++ct)
                acc[rt][ct] = __builtin_amdgcn_mfma_f32_16x16x32_f16(af[rt], bf[ct], acc[rt][ct], 0, 0, 0);
    }

    #pragma unroll
    for (int ct = 0; ct < 4; ++ct) {
        float tm[4];
        #pragma unroll
        for (int rt = 0; rt < 4; ++rt) {
            v4f a = acc[rt][ct];
            float v = fmaxf(fmaxf(a[0], a[1]), fmaxf(a[2], a[3]));
            v = fmaxf(v, __shfl_xor(v, 16));
            v = fmaxf(v, __shfl_xor(v, 32));
            tm[rt] = v;
        }
        float p0 = fmaxf(tm[0], tm[1]);
        float p1 = fmaxf(tm[2], tm[3]);
        if (quad == 0) {
            colmax[0 * CD + w * 64 + ct * 16 + lr] = p0;
            colmax[1 * CD + w * 64 + ct * 16 + lr] = p1;
        }
    }
    __syncthreads();

    int d = tid;
    #pragma unroll
    for (int p = 0; p < 2; ++p) {
        float v = fmaxf(colmax[p * CD + d] + b2[d], 0.0f);
        float s = block_sum256(v, red);
        float mean = s * (1.0f / 256.0f);
        float s2 = block_sum256(v * v, red);
        float var = s2 * (1.0f / 256.0f) - mean * mean;
        float iv = (v - mean) * rsqrtf(var + 1e-5f) * g_in[d] + b_in[d];
        inph[(size_t)(gp0 + p) * CD + d] = (_Float16)iv;
    }
}

// kv via MFMA fp16 (blocks 0..511) + fused iter-0 slotq (blocks 512..527).
// slotq inputs (slots from prep, Wq) are ready before this launch; the two
// block groups are independent -> no intra-kernel ordering needed.
__global__ __launch_bounds__(256) void kv_mfma_kernel(const _Float16* __restrict__ inph,
                                                      const _Float16* __restrict__ WkvT,
                                                      float* __restrict__ kk,
                                                      float* __restrict__ vv,
                                                      const float* __restrict__ slots,
                                                      const float* __restrict__ g_sl,
                                                      const float* __restrict__ b_sl,
                                                      const float* __restrict__ Wq,
                                                      float* __restrict__ qb) {
    __shared__ _Float16 A[64 * ASTR2];
    __shared__ float sl[CD];
    __shared__ float red[4];
    int tid = threadIdx.x;
    if (blockIdx.x >= 512) {
        // ---- slotq body (identical arithmetic to R14 slotq_kernel) ----
        int row = blockIdx.x - 512;
        int d = tid;
        float v = slots[row * CD + d];
        float s = block_sum256(v, red);
        float mean = s * (1.0f / 256.0f);
        float s2 = block_sum256(v * v, red);
        float var = s2 * (1.0f / 256.0f) - mean * mean;
        float ln = (v - mean) * rsqrtf(var + 1e-5f) * g_sl[d] + b_sl[d];
        sl[d] = ln;
        __syncthreads();
        float acc = 0.0f;
        const float4* sp = (const float4*)sl;
        for (int c4 = 0; c4 < 64; ++c4) {
            float4 x = sp[c4];
            int cb = c4 * 4;
            acc += x.x * Wq[cb * CD + d] + x.y * Wq[(cb + 1) * CD + d]
                 + x.z * Wq[(cb + 2) * CD + d] + x.w * Wq[(cb + 3) * CD + d];
        }
        qb[row * CD + d] = acc;
        return;
    }
    int rb = blockIdx.x >> 1, half = blockIdx.x & 1;
    int row0 = rb * 64;
    {
        const uint4* src4 = (const uint4*)(inph + (size_t)row0 * CD);
        #pragma unroll
        for (int i = 0; i < 8; ++i) {
            int idx = i * 256 + tid;
            int row = idx >> 5, c8 = idx & 31;
            *(uint4*)&A[row * ASTR2 + c8 * 8] = src4[idx];
        }
    }
    __syncthreads();
    int w = tid >> 6, lane = tid & 63, quad = lane >> 4, lr = lane & 15;
    v4f acc[4][4];
    #pragma unroll
    for (int rt = 0; rt < 4; ++rt)
        #pragma unroll
        for (int ct = 0; ct < 4; ++ct)
            acc[rt][ct] = (v4f){0.0f, 0.0f, 0.0f, 0.0f};
    #pragma unroll
    for (int ks = 0; ks < CD; ks += 32) {
        v8h af[4], bf[4];
        #pragma unroll
        for (int rt = 0; rt < 4; ++rt)
            af[rt] = *(const v8h*)&A[(rt * 16 + lr) * ASTR2 + ks + quad * 8];
        #pragma unroll
        for (int ct = 0; ct < 4; ++ct) {
            int ncol = half * 256 + w * 64 + ct * 16 + lr;
            bf[ct] = *(const v8h*)(WkvT + (size_t)ncol * CD + ks + quad * 8);
        }
        #pragma unroll
        for (int rt = 0; rt < 4; ++rt)
            #pragma unroll
            for (int ct = 0; ct < 4; ++ct)
                acc[rt][ct] = __builtin_amdgcn_mfma_f32_16x16x32_f16(af[rt], bf[ct], acc[rt][ct], 0, 0, 0);
    }
    float* dst = half ? vv : kk;
    #pragma unroll
    for (int rt = 0; rt < 4; ++rt)
        #pragma unroll
        for (int ct = 0; ct < 4; ++ct) {
            int col = w * 64 + ct * 16 + lr;
            #pragma unroll
            for (int r = 0; r < 4; ++r) {
                int row = rt * 16 + quad * 4 + r;
                dst[(size_t)(row0 + row) * CD + col] = acc[rt][ct][r];
            }
        }
}

// FUSED attn+updp, 256 blocks
__global__ __launch_bounds__(256) void attn_updp_kernel(const float* __restrict__ q,
                                                        const float* __restrict__ kk,
                                                        const float* __restrict__ vv,
                                                        float* __restrict__ asum,
                                                        float* __restrict__ updp,
                                                        float* __restrict__ out_attn) {
    int b = blockIdx.x >> 6;
    int chunk = blockIdx.x & 63;
    int t = threadIdx.x;
    __shared__ float qs[4 * CD];
    __shared__ float logit[64 * 4];
    __shared__ float aw[64 * 4];
    for (int i = t; i < 4 * CD; i += 256) qs[i] = q[b * 4 * CD + i];
    __syncthreads();

    int p = t & 63, r = t >> 6;
    int n = chunk * 64 + p;
    {
        const float4* kp = (const float4*)(kk + ((size_t)b * NPTS + n) * CD);
        const float4* qr = (const float4*)(qs + r * CD);
        float a = 0.0f;
        for (int c4 = 0; c4 < 64; ++c4) {
            float4 kv = kp[c4];
            float4 x = qr[c4];
            a += kv.x * x.x + kv.y * x.y + kv.z * x.z + kv.w * x.w;
        }
        logit[p * 4 + r] = 0.0625f * a;   // 256^-0.5
    }
    __syncthreads();
    if (t < 64) {
        float l0 = logit[t * 4 + 0], l1 = logit[t * 4 + 1];
        float l2 = logit[t * 4 + 2], l3 = logit[t * 4 + 3];
        float mx = fmaxf(fmaxf(l0, l1), fmaxf(l2, l3));
        float e0 = expf(l0 - mx), e1 = expf(l1 - mx), e2 = expf(l2 - mx), e3 = expf(l3 - mx);
        float inv = 1.0f / (e0 + e1 + e2 + e3);
        e0 *= inv; e1 *= inv; e2 *= inv; e3 *= inv;
        aw[t * 4 + 0] = e0; aw[t * 4 + 1] = e1; aw[t * 4 + 2] = e2; aw[t * 4 + 3] = e3;
        if (out_attn) {
            float* o = out_attn + ((size_t)b * NPTS + chunk * 64 + t) * 4;
            o[0] = e0; o[1] = e1; o[2] = e2; o[3] = e3;
        }
        float s0 = e0, s1 = e1, s2 = e2, s3 = e3;
        #pragma unroll
        for (int o = 32; o; o >>= 1) {
            s0 += __shfl_down(s0, o); s1 += __shfl_down(s1, o);
            s2 += __shfl_down(s2, o); s3 += __shfl_down(s3, o);
        }
        if (t == 0) {
            atomicAdd(&asum[b * 4 + 0], s0);
            atomicAdd(&asum[b * 4 + 1], s1);
            atomicAdd(&asum[b * 4 + 2], s2);
            atomicAdd(&asum[b * 4 + 3], s3);
        }
    }
    __syncthreads();

    float ac0 = 0.0f, ac1 = 0.0f, ac2 = 0.0f, ac3 = 0.0f;
    const float* vb = vv + ((size_t)b * NPTS + chunk * 64) * CD;
    for (int nn2 = 0; nn2 < 64; ++nn2) {
        float v = vb[(size_t)nn2 * CD + t];
        float4 w4 = *(const float4*)&aw[nn2 * 4];
        ac0 += w4.x * v; ac1 += w4.y * v; ac2 += w4.z * v; ac3 += w4.w * v;
    }
    updp[((size_t)(b * 4 + 0) * 64 + chunk) * CD + t] = ac0;
    updp[((size_t)(b * 4 + 1) * 64 + chunk) * CD + t] = ac1;
    updp[((size_t)(b * 4 + 2) * 64 + chunk) * CD + t] = ac2;
    updp[((size_t)(b * 4 + 3) * 64 + chunk) * CD + t] = ac3;
}

// GRU gates, 96 blocks: (row, gate, c-half).
__global__ __launch_bounds__(256) void gru_gates_kernel(const float* __restrict__ updp,
                                                        const float* __restrict__ asum,
                                                        const float* __restrict__ slots,
                                                        const float* __restrict__ W_ih,
                                                        const float* __restrict__ W_hh,
                                                        const float* __restrict__ b_ih,
                                                        const float* __restrict__ b_hh,
                                                        float* __restrict__ gi,
                                                        float* __restrict__ gh) {
    int idx = blockIdx.x;
    int row = idx / 6, rem = idx % 6;
    int gate = rem >> 1, half = rem & 1;
    int d = threadIdx.x;
    __shared__ float su[CD], sp[CD];
    float f = 1.0f / (asum[row] + 1e-8f);
    float u = 0.0f;
    for (int p = 0; p < 64; ++p) u += updp[((size_t)row * 64 + p) * CD + d];
    u *= f;
    su[d] = u; sp[d] = slots[row * CD + d];
    __syncthreads();
    float acc_i = half ? 0.0f : b_ih[gate * CD + d];
    float acc_h = half ? 0.0f : b_hh[gate * CD + d];
    const float* wi = W_ih + gate * CD + d;
    const float* wh = W_hh + gate * CD + d;
    int c0 = half * 128;
    for (int c = c0; c < c0 + 128; ++c) {
        acc_i += su[c] * wi[c * 3 * CD];
        acc_h += sp[c] * wh[c * 3 * CD];
    }
    gi[((size_t)(row * 3 + gate) * 2 + half) * CD + d] = acc_i;
    gh[((size_t)(row * 3 + gate) * 2 + half) * CD + d] = acc_h;
}

// GRU update + LN_ff + MLP residual + (optional) NEXT-ITER slotq, one block/row
__global__ __launch_bounds__(256) void gru_mlp_kernel(const float* __restrict__ gi,
                                                      const float* __restrict__ gh,
                                                      float* __restrict__ slots,
                                                      const float* __restrict__ g_ff,
                                                      const float* __restrict__ b_ff,
                                                      const float* __restrict__ Wm1,
                                                      const float* __restrict__ bm1,
                                                      const float* __restrict__ Wm2,
                                                      const float* __restrict__ bm2,
                                                      float* __restrict__ asum,
                                                      const float* __restrict__ g_sl,
                                                      const float* __restrict__ b_sl,
                                                      const float* __restrict__ Wq,
                                                      float* __restrict__ qv) {
    int row = blockIdx.x;
    int d = threadIdx.x;
    __shared__ float sh[CD];
    __shared__ float red[4];
    float prev = slots[row * CD + d];
    float gir = gi[((size_t)(row * 3 + 0) * 2 + 0) * CD + d] + gi[((size_t)(row * 3 + 0) * 2 + 1) * CD + d];
    float giz = gi[((size_t)(row * 3 + 1) * 2 + 0) * CD + d] + gi[((size_t)(row * 3 + 1) * 2 + 1) * CD + d];
    float gin = gi[((size_t)(row * 3 + 2) * 2 + 0) * CD + d] + gi[((size_t)(row * 3 + 2) * 2 + 1) * CD + d];
    float ghr = gh[((size_t)(row * 3 + 0) * 2 + 0) * CD + d] + gh[((size_t)(row * 3 + 0) * 2 + 1) * CD + d];
    float ghz = gh[((size_t)(row * 3 + 1) * 2 + 0) * CD + d] + gh[((size_t)(row * 3 + 1) * 2 + 1) * CD + d];
    float ghn = gh[((size_t)(row * 3 + 2) * 2 + 0) * CD + d] + gh[((size_t)(row * 3 + 2) * 2 + 1) * CD + d];
    if (d == 0) asum[row] = 0.0f;
    float r = 1.0f / (1.0f + expf(-(gir + ghr)));
    float z = 1.0f / (1.0f + expf(-(giz + ghz)));
    float nn = tanhf(gin + r * ghn);
    float sNew = (1.0f - z) * nn + z * prev;
    float s = block_sum256(sNew, red);
    float mean = s * (1.0f / 256.0f);
    float s2 = block_sum256(sNew * sNew, red);
    float var = s2 * (1.0f / 256.0f) - mean * mean;
    float h = (sNew - mean) * rsqrtf(var + 1e-5f) * g_ff[d] + b_ff[d];
    __syncthreads();
    sh[d] = h;
    __syncthreads();
    float y = bm1[d];
    {
        const float4* hp = (const float4*)sh;
        for (int c4 = 0; c4 < 64; ++c4) {
            float4 x = hp[c4];
            int cb = c4 * 4;
            y += x.x * Wm1[cb * CD + d] + x.y * Wm1[(cb + 1) * CD + d]
               + x.z * Wm1[(cb + 2) * CD + d] + x.w * Wm1[(cb + 3) * CD + d];
        }
    }
    y = fmaxf(y, 0.0f);
    __syncthreads();
    sh[d] = y;
    __syncthreads();
    float o = bm2[d];
    {
        const float4* hp = (const float4*)sh;
        for (int c4 = 0; c4 < 64; ++c4) {
            float4 x = hp[c4];
            int cb = c4 * 4;
            o += x.x * Wm2[cb * CD + d] + x.y * Wm2[(cb + 1) * CD + d]
               + x.z * Wm2[(cb + 2) * CD + d] + x.w * Wm2[(cb + 3) * CD + d];
        }
    }
    float fin = sNew + o;
    slots[row * CD + d] = fin;
    if (qv) {
        float v = fin;
        float s3 = block_sum256(v, red);
        float mean2 = s3 * (1.0f / 256.0f);
        float s4 = block_sum256(v * v, red);
        float var2 = s4 * (1.0f / 256.0f) - mean2 * mean2;
        float ln = (v - mean2) * rsqrtf(var2 + 1e-5f) * g_sl[d] + b_sl[d];
        __syncthreads();
        sh[d] = ln;
        __syncthreads();
        float acc = 0.0f;
        const float4* sp = (const float4*)sh;
        for (int c4 = 0; c4 < 64; ++c4) {
            float4 x = sp[c4];
            int cb = c4 * 4;
            acc += x.x * Wq[cb * CD + d] + x.y * Wq[(cb + 1) * CD + d]
                 + x.z * Wq[(cb + 2) * CD + d] + x.w * Wq[(cb + 3) * CD + d];
        }
        qv[row * CD + d] = acc;
    }
}

// recon linear+BN+relu layer, column-parallel: 16 blocks x 16 cols.
__global__ __launch_bounds__(256) void recon_layer_kernel(const float* __restrict__ in,
                                                          const float* __restrict__ W,
                                                          const float* __restrict__ bias,
                                                          const float* __restrict__ g,
                                                          const float* __restrict__ be,
                                                          float* __restrict__ outb) {
    __shared__ float sin[16 * CD];
    __shared__ float tb[16 * 16];   // tb[row*16+col]
    int t = threadIdx.x;
    for (int i = t; i < 16 * CD; i += 256) sin[i] = in[i];
    __syncthreads();
    int col = t & 15, row = t >> 4;
    int colg = blockIdx.x * 16 + col;
    float acc = bias[colg];
    for (int c4 = 0; c4 < 64; ++c4) {
        int cb = c4 * 4;
        float w0 = W[cb * CD + colg], w1 = W[(cb + 1) * CD + colg];
        float w2 = W[(cb + 2) * CD + colg], w3 = W[(cb + 3) * CD + colg];
        float4 x = *(const float4*)(sin + row * CD + cb);
        acc += x.x * w0 + x.y * w1 + x.z * w2 + x.w * w3;
    }
    tb[row * 16 + col] = acc;
    __syncthreads();
    float mean = 0.0f;
    for (int r = 0; r < 16; ++r) mean += tb[r * 16 + col];
    mean *= (1.0f / 16.0f);
    float var = 0.0f;
    for (int r = 0; r < 16; ++r) { float dd = tb[r * 16 + col] - mean; var += dd * dd; }
    var *= (1.0f / 16.0f);
    float inv = rsqrtf(var + 1e-5f);
    outb[row * CD + colg] = fmaxf(0.0f, (acc - mean) * inv * g[colg] + be[colg]);
}

// final recon layer (no BN) + in-kernel FPS, 4 blocks (one per batch)
__global__ __launch_bounds__(320) void recon3_fps_kernel(const float* __restrict__ h2g,
                                                         const float* __restrict__ Wr3,
                                                         const float* __restrict__ br3,
                                                         float* __restrict__ spts,
                                                         int* __restrict__ fidx,
                                                         float* __restrict__ lacc,
                                                         unsigned* __restrict__ mnbuf) {
    __shared__ float h2[16 * CD];
    __shared__ float sp[384 * 3];
    int b = blockIdx.x;
    int d = threadIdx.x;
    for (int i = d; i < 16 * CD; i += 320) h2[i] = h2g[i];
    __syncthreads();
    if (d < 288) {
        float t4[4];
        #pragma unroll
        for (int rl = 0; rl < 4; ++rl) t4[rl] = br3[d];
        for (int c4 = 0; c4 < 64; ++c4) {
            int cb = c4 * 4;
            float w0 = Wr3[cb * 288 + d], w1 = Wr3[(cb + 1) * 288 + d];
            float w2 = Wr3[(cb + 2) * 288 + d], w3 = Wr3[(cb + 3) * 288 + d];
            #pragma unroll
            for (int rl = 0; rl < 4; ++rl) {
                float4 x = *(const float4*)(h2 + (b * 4 + rl) * CD + cb);
                t4[rl] += x.x * w0 + x.y * w1 + x.z * w2 + x.w * w3;
            }
        }
        #pragma unroll
        for (int rl = 0; rl < 4; ++rl) {
            spts[(b * 4 + rl) * 288 + d] = t4[rl];
            sp[rl * 288 + d] = t4[rl];
        }
    }
    __syncthreads();

    if (d < 64) {
        int lane = d;
        int* out = fidx + b * 128;
        if (lane == 0) out[0] = 0;
        if (b == 0 && lane == 0) lacc[0] = 0.0f;
        mnbuf[b * 128 + lane] = 0x7F800000u;
        mnbuf[b * 128 + 64 + lane] = 0x7F800000u;
        float px[6], py[6], pz[6], dd[6];
        #pragma unroll
        for (int i = 0; i < 6; ++i) {
            int m = i * 64 + lane;
            px[i] = sp[m * 3]; py[i] = sp[m * 3 + 1]; pz[i] = sp[m * 3 + 2];
            dd[i] = 1e10f;
        }
        float lx = sp[0], ly = sp[1], lz = sp[2];
        #pragma unroll 1
        for (int s = 1; s < 128; ++s) {
            #pragma unroll
            for (int i = 0; i < 6; ++i) {
                float dx = px[i] - lx, dy = py[i] - ly, dz = pz[i] - lz;
                dd[i] = fminf(dd[i], dx * dx + dy * dy + dz * dz);
            }
            float bv = dd[0]; int bi = lane;
            #pragma unroll
            for (int i = 1; i < 6; ++i)
                if (dd[i] > bv) { bv = dd[i]; bi = i * 64 + lane; }
            dpp_lexmax<0x111, 0xf>(bv, bi);
            dpp_lexmax<0x112, 0xf>(bv, bi);
            dpp_lexmax<0x114, 0xf>(bv, bi);
            dpp_lexmax<0x118, 0xf>(bv, bi);
            dpp_lexmax<0x142, 0xa>(bv, bi);
            dpp_lexmax<0x143, 0xc>(bv, bi);
            int fm = __builtin_amdgcn_readlane(bi, 63);
            if (lane == 0) out[s] = fm;
            int slot = fm >> 6, sl_lane = fm & 63;
            float sx = px[0], sy = py[0], sz = pz[0];
            #pragma unroll
            for (int i = 1; i < 6; ++i)
                if (slot == i) { sx = px[i]; sy = py[i]; sz = pz[i]; }
            lx = __int_as_float(__builtin_amdgcn_readlane(__float_as_int(sx), sl_lane));
            ly = __int_as_float(__builtin_amdgcn_readlane(__float_as_int(sy), sl_lane));
            lz = __int_as_float(__builtin_amdgcn_readlane(__float_as_int(sz), sl_lane));
        }
    }
}

// merged chamfer: blocks 0..63 = sum2, 64..127 = min1; last block writes loss
__global__ __launch_bounds__(256) void chamfer_kernel(const float* __restrict__ spts,
                                                      const int* __restrict__ fidx,
                                                      const float* __restrict__ xyz,
                                                      float* __restrict__ lacc,
                                                      unsigned* __restrict__ mnbuf,
                                                      unsigned* __restrict__ counter,
                                                      float* __restrict__ out) {
    int t = threadIdx.x;
    __shared__ float ds[128 * 3];
    __shared__ float tile[256 * 3];
    __shared__ float red[4];
    __shared__ unsigned done;
    if (blockIdx.x < 64) {
        int b = blockIdx.x >> 4, chunk = blockIdx.x & 15;
        const float* pts = spts + (size_t)b * 384 * 3;
        if (t < 128) {
            int j = fidx[b * 128 + t];
            ds[t * 3] = pts[j * 3]; ds[t * 3 + 1] = pts[j * 3 + 1]; ds[t * 3 + 2] = pts[j * 3 + 2];
        }
        __syncthreads();
        int n = chunk * 256 + t;
        const float* xb = xyz + (size_t)b * NPTS * 3;
        float px = xb[n * 3], py = xb[n * 3 + 1], pz = xb[n * 3 + 2];
        float mn = 1e30f;
        #pragma unroll 4
        for (int jj = 0; jj < 128; ++jj) {
            float dx = ds[jj * 3] - px, dy = ds[jj * 3 + 1] - py, dz = ds[jj * 3 + 2] - pz;
            mn = fminf(mn, dx * dx + dy * dy + dz * dz);
        }
        float total = block_sum256(mn * (1.0f / 4096.0f), red);
        if (t == 0) atomicAdd(lacc, total);
    } else {
        int bid = blockIdx.x - 64;
        int b = bid >> 4, chunk = bid & 15;
        const float* xb = xyz + ((size_t)b * NPTS + chunk * 256) * 3;
        for (int i = t; i < 768; i += 256) tile[i] = xb[i];
        __syncthreads();
        if (t < 128) {
            int j = fidx[b * 128 + t];
            const float* pts = spts + (size_t)b * 384 * 3;
            float px = pts[j * 3], py = pts[j * 3 + 1], pz = pts[j * 3 + 2];
            float mn = 1e30f;
            #pragma unroll 4
            for (int i = 0; i < 256; ++i) {
                float dx = tile[i * 3] - px, dy = tile[i * 3 + 1] - py, dz = tile[i * 3 + 2] - pz;
                mn = fminf(mn, dx * dx + dy * dy + dz * dz);
            }
            atomicMin(&mnbuf[b * 128 + t], __float_as_uint(mn));
        }
    }
    __threadfence();
    __syncthreads();
    if (t == 0) done = atomicAdd(counter, 1u);
    __syncthreads();
    if (done == 127u) {
        unsigned a0 = atomicAdd(&mnbuf[t], 0u);
        unsigned a1 = atomicAdd(&mnbuf[t + 256], 0u);
        float v = (__uint_as_float(a0) + __uint_as_float(a1)) * (1.0f / 128.0f);
        __syncthreads();
        float tot = block_sum256(v, red);
        if (t == 0) {
            float l = atomicAdd(lacc, 0.0f);
            out[0] = (l + tot) * 0.25f;
        }
    }
}

// ---------------- launch ----------------

extern "C" void kernel_launch(void* const* d_in, const int* in_sizes, int n_in,
                              void* d_out, int out_size, void* d_ws, size_t ws_size,
                              hipStream_t stream) {
    (void)in_sizes; (void)n_in; (void)out_size; (void)ws_size;
    const float* x    = (const float*)d_in[0];
    const float* W1   = (const float*)d_in[2];
    const float* b1   = (const float*)d_in[3];
    const float* W2   = (const float*)d_in[4];
    const float* b2   = (const float*)d_in[5];
    const float* mu   = (const float*)d_in[6];
    const float* sg   = (const float*)d_in[7];
    const float* g_in = (const float*)d_in[8];
    const float* b_in = (const float*)d_in[9];
    const float* g_sl = (const float*)d_in[10];
    const float* b_sl = (const float*)d_in[11];
    const float* g_ff = (const float*)d_in[12];
    const float* b_ff = (const float*)d_in[13];
    const float* Wq   = (const float*)d_in[14];
    const float* Wk   = (const float*)d_in[15];
    const float* Wv   = (const float*)d_in[16];
    const float* W_ih = (const float*)d_in[17];
    const float* W_hh = (const float*)d_in[18];
    const float* b_ih = (const float*)d_in[19];
    const float* b_hh = (const float*)d_in[20];
    const float* Wm1  = (const float*)d_in[21];
    const float* bm1  = (const float*)d_in[22];
    const float* Wm2  = (const float*)d_in[23];
    const float* bm2  = (const float*)d_in[24];
    const float* Wr1  = (const float*)d_in[25];
    const float* br1  = (const float*)d_in[26];
    const float* g1   = (const float*)d_in[27];
    const float* be1  = (const float*)d_in[28];
    const float* Wr2  = (const float*)d_in[29];
    const float* br2  = (const float*)d_in[30];
    const float* g2   = (const float*)d_in[31];
    const float* be2  = (const float*)d_in[32];
    const float* Wr3  = (const float*)d_in[33];
    const float* br3  = (const float*)d_in[34];

    float* ws    = (float*)d_ws;
    float* xyz   = ws;                               // 49152 f
    float* xyzw  = xyz + 49152;                      // 65536 f
    int*   knn   = (int*)(xyzw + 65536);             // 524288 i
    _Float16* f1h = (_Float16*)(knn + 524288);       // -> 1048576 f
    _Float16* W2t = (_Float16*)((float*)f1h + 1048576);  // -> 20480 f
    _Float16* WkvT = (_Float16*)((float*)W2t + 20480);   // -> 65536 f
    _Float16* inph = (_Float16*)((float*)WkvT + 65536);  // -> 2097152 f
    float* kkb   = (float*)inph + 2097152;           // 4194304 f
    float* vvb   = kkb + 4194304;                    // 4194304 f
    float* slots = vvb + 4194304;                    // 4096 f
    float* qb    = slots + 4096;                     // 4096 f
    float* asum  = qb + 4096;                        // 16 f
    float* updp  = asum + 16;                        // 262144 f
    float* gi    = updp + 262144;                    // 24576 f
    float* gh    = gi + 24576;                       // 24576 f
    float* h1g   = gh + 24576;                       // 4096 f
    float* h2g   = h1g + 4096;                       // 4096 f
    float* spts  = h2g + 4096;                       // 4608 f
    int*   fidx  = (int*)(spts + 4608);              // 512 i
    float* lacc  = (float*)(fidx + 512);             // 1 f
    unsigned* mnbuf = (unsigned*)(lacc + 1);         // 512 u
    unsigned* counter = mnbuf + 512;                 // 1 u

    float* out = (float*)d_out;

    prep_kernel<<<832, 256, 0, stream>>>(x, xyz, (float4*)xyzw, mu, sg, slots, asum,
                                         W2, Wk, Wv, W2t, WkvT, counter);
    knn_kernel<<<NBATCH * NPTS / 4, 256, 0, stream>>>((const float4*)xyzw, knn);
    conv1_kernel<<<NBATCH * NPTS, 128, 0, stream>>>(xyz, knn, W1, b1, f1h);
    conv2_mfma_kernel<<<NBATCH * NPTS / 2, 256, 0, stream>>>(xyz, f1h, knn, W2t, b2, g_in, b_in, inph);
    kv_mfma_kernel<<<NBATCH * NPTS / 64 * 2 + 16, 256, 0, stream>>>(inph, WkvT, kkb, vvb,
                                                                    slots, g_sl, b_sl, Wq, qb);

    for (int it = 0; it < 3; ++it) {
        attn_updp_kernel<<<256, 256, 0, stream>>>(qb, kkb, vvb, asum, updp,
                                                  (it == 2) ? (out + 1) : (float*)nullptr);
        gru_gates_kernel<<<96, 256, 0, stream>>>(updp, asum, slots, W_ih, W_hh, b_ih, b_hh, gi, gh);
        gru_mlp_kernel<<<16, 256, 0, stream>>>(gi, gh, slots, g_ff, b_ff, Wm1, bm1, Wm2, bm2, asum,
                                               g_sl, b_sl, Wq, (it < 2) ? qb : (float*)nullptr);
    }

    recon_layer_kernel<<<16, 256, 0, stream>>>(slots, Wr1, br1, g1, be1, h1g);
    recon_layer_kernel<<<16, 256, 0, stream>>>(h1g, Wr2, br2, g2, be2, h2g);
    recon3_fps_kernel<<<4, 320, 0, stream>>>(h2g, Wr3, br3, spts, fidx, lacc, mnbuf);
    chamfer_kernel<<<128, 256, 0, stream>>>(spts, fidx, xyz, lacc, mnbuf, counter, out);
}